// Round 10
// baseline (662.542 us; speedup 1.0000x reference)
//
#include <hip/hip_runtime.h>

#define NN 6144
#define GG 32
#define NPGc 192
#define FINc 32
#define FEc 8
#define Hc 64
#define HMc 128
#define Kc 8
#define Ec 49152
#define NKc (NN*Kc)
#define RTOTc (GG*NPGc*NPGc)

typedef float f32x4 __attribute__((ext_vector_type(4)));
typedef short bf16x8 __attribute__((ext_vector_type(8)));
typedef unsigned long long u64;

__device__ __forceinline__ unsigned short f2bf(float f){
  unsigned u = __float_as_uint(f);
  unsigned r = u + 0x7fffu + ((u>>16)&1u);
  return (unsigned short)(r>>16);
}
__device__ __forceinline__ unsigned fenc(float f){
  unsigned u = __float_as_uint(f);
  return (u & 0x80000000u) ? ~u : (u | 0x80000000u);
}
__device__ __forceinline__ float fdec(unsigned e){
  unsigned u = (e & 0x80000000u) ? (e & 0x7fffffffu) : ~e;
  return __uint_as_float(u);
}
__device__ __forceinline__ void bub8(u64* t8, u64 k){
#pragma unroll
  for (int q=0;q<8;q++){ u64 cur=t8[q]; u64 lo=(k<cur)?k:cur; u64 hi=(k<cur)?cur:k; t8[q]=lo; k=hi; }
}

// ---------------- init: zero stats ----------------
__global__ void k_init(float* stats){
  int idx = blockIdx.x*256 + threadIdx.x;
  if (idx < 768) stats[idx] = 0.f;
}

// ---------------- x1a = x @ ef_wroot ----------------
__global__ __launch_bounds__(256) void k_root(const float* __restrict__ x, const float* __restrict__ wr, float* __restrict__ x1a){
  __shared__ float Ws[FINc*Hc];
  __shared__ float xr[4][FINc];
  int t = threadIdx.x;
  for (int q=t;q<FINc*Hc;q+=256) Ws[q] = wr[q];
  int rg = t>>6, j = t&63;
  int r = blockIdx.x*4 + rg;
  if (j < FINc) xr[rg][j] = x[r*FINc + j];
  __syncthreads();
  float a0=0.f, a1=0.f;
#pragma unroll
  for (int k=0;k<FINc;k+=2){
    a0 = fmaf(xr[rg][k],   Ws[k*Hc+j],     a0);
    a1 = fmaf(xr[rg][k+1], Ws[(k+1)*Hc+j], a1);
  }
  x1a[r*Hc + j] = a0 + a1;
}

// ---------------- edge1 precompute: EAc[e] = ea[e] @ W1c (rows 64..71) ----------------
__global__ __launch_bounds__(256) void k_eac(const float* __restrict__ ea, const float* __restrict__ w1, float* __restrict__ EAc){
  __shared__ float Wc[FEc*Hc];
  int t = threadIdx.x;
  for (int q=t; q<FEc*Hc; q+=256) Wc[q] = w1[64*Hc + q];
  __syncthreads();
  int idx = blockIdx.x*256 + t;
  int e = idx >> 4, c4 = (idx & 15)*4;
  float av[8];
#pragma unroll
  for (int q=0;q<8;q++) av[q] = ea[e*FEc + q];
  float4 o = {0.f,0.f,0.f,0.f};
#pragma unroll
  for (int q=0;q<8;q++){
    o.x = fmaf(av[q], Wc[q*Hc + c4+0], o.x);
    o.y = fmaf(av[q], Wc[q*Hc + c4+1], o.y);
    o.z = fmaf(av[q], Wc[q*Hc + c4+2], o.z);
    o.w = fmaf(av[q], Wc[q*Hc + c4+3], o.w);
  }
  *(float4*)(EAc + (size_t)e*Hc + c4) = o;
}

// ---------------- edge1 precompute: P1 = x@W1a + b1 (dst part), P2 = x@W1b (src part) ----------------
__global__ __launch_bounds__(256) void k_p12(const float* __restrict__ x, const float* __restrict__ w1, const float* __restrict__ b1,
                                             float* __restrict__ P1, float* __restrict__ P2){
  __shared__ float xs[16][32];
  int t = threadIdx.x;
  int j = t & 63, w = t >> 6;
  float wa[32], wb[32];
#pragma unroll
  for (int k=0;k<32;k++){
    wa[k] = w1[k*Hc + j];
    wb[k] = w1[(32+k)*Hc + j];
  }
  float b1j = b1[j];
  int nb = blockIdx.x * 16;
  for (int q=t; q<16*32; q+=256) xs[q>>5][q&31] = x[(size_t)(nb + (q>>5))*FINc + (q&31)];
  __syncthreads();
#pragma unroll
  for (int it=0; it<4; it++){
    int nl = it*4 + w;
    float a = b1j, b = 0.f;
#pragma unroll
    for (int k=0;k<32;k++){
      float xv = xs[nl][k];
      a = fmaf(xv, wa[k], a);
      b = fmaf(xv, wb[k], b);
    }
    int n = nb + nl;
    P1[(size_t)n*Hc + j] = a;
    P2[(size_t)n*Hc + j] = b;
  }
}

// ---------------- generic CSR build pieces ----------------
__global__ void k_zero_cnt(unsigned* rcnt){
  int idx = blockIdx.x*256 + threadIdx.x;
  if (idx < NN) rcnt[idx] = 0u;
}
__global__ void k_cnt_dst(const int* __restrict__ ei, unsigned* __restrict__ rcnt){
  int e = blockIdx.x*256 + threadIdx.x;
  atomicAdd(&rcnt[ei[Ec + e]], 1u);
}
__global__ __launch_bounds__(256) void k_scan(const unsigned* __restrict__ rcnt, unsigned* __restrict__ rptr, unsigned* __restrict__ rcur){
  __shared__ unsigned ps[256];
  int t = threadIdx.x;
  unsigned loc[24];
  unsigned s = 0;
#pragma unroll
  for (int q=0;q<24;q++){ loc[q] = s; s += rcnt[t*24+q]; }
  ps[t] = s;
  __syncthreads();
  for (int off=1; off<256; off<<=1){
    unsigned v = (t>=off)? ps[t-off] : 0u;
    __syncthreads();
    ps[t] += v;
    __syncthreads();
  }
  unsigned base = (t==0)? 0u : ps[t-1];
#pragma unroll
  for (int q=0;q<24;q++){ unsigned v = base + loc[q]; rptr[t*24+q]=v; rcur[t*24+q]=v; }
  if (t==255) rptr[NN] = ps[255];
}
__global__ void k_fill_dst(const int* __restrict__ ei, unsigned* __restrict__ rcur, unsigned* __restrict__ rlist){
  int e = blockIdx.x*256 + threadIdx.x;
  unsigned pos = atomicAdd(&rcur[ei[Ec + e]], 1u);
  rlist[pos] = (unsigned)e;
}
__global__ void k_rev_cnt(const unsigned* __restrict__ nbr, unsigned* __restrict__ rcnt){
  int e = blockIdx.x*256 + threadIdx.x;
  atomicAdd(&rcnt[nbr[e]], 1u);
}
__global__ void k_rev_fill(const unsigned* __restrict__ nbr, unsigned* __restrict__ rcur, unsigned* __restrict__ rlist){
  int e = blockIdx.x*256 + threadIdx.x;
  unsigned pos = atomicAdd(&rcur[nbr[e]], 1u);
  rlist[pos] = (unsigned)(e >> 3);
}

// ---------------- edge1 aggregate: x1a[n] += (Σ_in relu(P1[n]+P2[s]+EAc[e])) @ W2 + deg·b2 ----------------
__global__ __launch_bounds__(128) void k_node1(const float* __restrict__ P1, const float* __restrict__ P2, const float* __restrict__ EAc,
        const int* __restrict__ ei, const unsigned* __restrict__ rptr, const unsigned* __restrict__ rlist,
        const float* __restrict__ w2, const float* __restrict__ b2, float* __restrict__ x1a){
  __shared__ __align__(16) float accs[16][68];
  __shared__ __align__(16) float W2T[64][68];
  __shared__ unsigned rp_s[17];
  int t = threadIdx.x;
  int d0 = blockIdx.x * 16;
  for (int q=t; q<64*64; q+=128) W2T[q&63][q>>6] = w2[q];
  if (t < 17) rp_s[t] = rptr[d0 + t];
  __syncthreads();
  int slot = t>>3, cg = t&7, c0 = cg*8;
  int n = d0 + slot;
  float4 p1a = *(const float4*)(P1 + (size_t)n*Hc + c0);
  float4 p1b = *(const float4*)(P1 + (size_t)n*Hc + c0 + 4);
  float acc[8];
#pragma unroll
  for (int q=0;q<8;q++) acc[q] = 0.f;
  unsigned beg = rp_s[slot], end = rp_s[slot+1];
  for (unsigned pos=beg; pos<end; pos++){
    unsigned e = rlist[pos];
    int s = ei[e];
    float4 qa = *(const float4*)(P2 + (size_t)s*Hc + c0);
    float4 qb = *(const float4*)(P2 + (size_t)s*Hc + c0 + 4);
    float4 fa = *(const float4*)(EAc + (size_t)e*Hc + c0);
    float4 fb = *(const float4*)(EAc + (size_t)e*Hc + c0 + 4);
    acc[0] += fmaxf(p1a.x + qa.x + fa.x, 0.f);
    acc[1] += fmaxf(p1a.y + qa.y + fa.y, 0.f);
    acc[2] += fmaxf(p1a.z + qa.z + fa.z, 0.f);
    acc[3] += fmaxf(p1a.w + qa.w + fa.w, 0.f);
    acc[4] += fmaxf(p1b.x + qb.x + fb.x, 0.f);
    acc[5] += fmaxf(p1b.y + qb.y + fb.y, 0.f);
    acc[6] += fmaxf(p1b.z + qb.z + fb.z, 0.f);
    acc[7] += fmaxf(p1b.w + qb.w + fb.w, 0.f);
  }
  *(float4*)&accs[slot][c0]   = make_float4(acc[0],acc[1],acc[2],acc[3]);
  *(float4*)&accs[slot][c0+4] = make_float4(acc[4],acc[5],acc[6],acc[7]);
  __syncthreads();
  float out[8];
#pragma unroll
  for (int q=0;q<8;q++) out[q] = 0.f;
  for (int k4=0;k4<16;k4++){
    float4 hv = *(const float4*)&accs[slot][k4*4];
#pragma unroll
    for (int cc=0;cc<8;cc++){
      float4 wv = *(const float4*)&W2T[c0+cc][k4*4];
      out[cc] = fmaf(hv.x,wv.x, fmaf(hv.y,wv.y, fmaf(hv.z,wv.z, fmaf(hv.w,wv.w, out[cc]))));
    }
  }
  float deg = (float)(end - beg);
  float* px = x1a + (size_t)n*Hc + c0;
#pragma unroll
  for (int cc=0;cc<8;cc++) px[cc] += out[cc] + deg*b2[c0+cc];
}

// ---------------- BN stats over N rows x 64 cols ----------------
__global__ __launch_bounds__(256) void k_bn_stats(const float* __restrict__ src, float* __restrict__ gsum, float* __restrict__ gss){
  int t = threadIdx.x;
  int c = t & 63;
  int r0 = blockIdx.x*64 + (t>>6);
  float s=0.f, ss=0.f;
  for (int it=0; it<16; it++){
    int r = r0 + it*4;
    float v = src[r*Hc + c];
    s += v; ss += v*v;
  }
  __shared__ float S[64], SS[64];
  if (t < 64){ S[t]=0.f; SS[t]=0.f; }
  __syncthreads();
  atomicAdd(&S[c], s); atomicAdd(&SS[c], ss);
  __syncthreads();
  if (t < 64){ atomicAdd(&gsum[t], S[t]); atomicAdd(&gss[t], SS[t]); }
}

__global__ void k_bn_fin(const float* gsum, const float* gss, const float* gam, const float* bet, float* sc, float* sh){
  int c = threadIdx.x; // 64
  float mean = gsum[c] / (float)NN;
  float var  = gss[c] / (float)NN - mean*mean;
  float rs = rsqrtf(var + 1e-5f);
  float s = rs * gam[c];
  sc[c] = s; sh[c] = bet[c] - mean*s;
}

// ---------------- apply BN1 + per-row squared norm ----------------
__global__ __launch_bounds__(256) void k_apply_bn1_sq(const float* __restrict__ x1a, const float* __restrict__ sc, const float* __restrict__ sh,
                               float* __restrict__ x1bn, float* __restrict__ sqv){
  int t = threadIdx.x;
  int c = t & 63;
  int r = blockIdx.x*4 + (t>>6);
  float v = x1a[r*Hc + c]*sc[c] + sh[c];
  x1bn[r*Hc + c] = v;
  float s = v*v;
#pragma unroll
  for (int off=1; off<64; off<<=1) s += __shfl_xor(s, off, 64);
  if (c == 0) sqv[r] = s;
}

// ---------------- KNN: LDS-broadcast distances + online top-8 (round-6 proven kernel) ----------------
__global__ __launch_bounds__(128,2) void k_knn(const float* __restrict__ x1bn, const float* __restrict__ sqv, u64* __restrict__ parts, int CH){
  __shared__ __align__(16) float XJ[64][68];
  __shared__ float sqj[64];
  int t = threadIdx.x;
  int i1 = blockIdx.x*256 + t;
  int i2 = i1 + 128;
  float4 xa[16], xb[16];
#pragma unroll
  for (int q=0;q<16;q++){
    xa[q] = *(const float4*)(x1bn + (size_t)i1*Hc + q*4);
    xb[q] = *(const float4*)(x1bn + (size_t)i2*Hc + q*4);
  }
  float sqi1 = sqv[i1], sqi2 = sqv[i2];
  u64 t8a[8], t8b[8];
#pragma unroll
  for (int q=0;q<8;q++){ t8a[q] = ~0ull; t8b[q] = ~0ull; }
  float thra = __uint_as_float(0x7f800000u);
  float thrb = thra;
  int cpc = NN / CH;
  int nsub = cpc >> 6;
  int jbase0 = blockIdx.y * cpc;
  for (int sub=0; sub<nsub; sub++){
    int jb = jbase0 + sub*64;
    __syncthreads();
    {
      int c = t>>1, hh = t&1;
      const float4* srcp = (const float4*)(x1bn + (size_t)(jb + c)*Hc + hh*32);
#pragma unroll
      for (int q=0;q<8;q++) *(float4*)&XJ[c][hh*32 + q*4] = srcp[q];
      if (t < 64) sqj[t] = sqv[jb + t];
    }
    __syncthreads();
    for (int j=0;j<64;j++){
      float sqjc = sqj[j];
      float a0=0.f,a1=0.f,a2=0.f,a3=0.f,b0=0.f,b1=0.f,b2=0.f,b3=0.f;
#pragma unroll
      for (int q4=0;q4<4;q4++){
        float4 xj0 = *(const float4*)&XJ[j][q4*16];
        float4 xj1 = *(const float4*)&XJ[j][q4*16+4];
        float4 xj2 = *(const float4*)&XJ[j][q4*16+8];
        float4 xj3 = *(const float4*)&XJ[j][q4*16+12];
        float4 A0 = xa[q4*4+0], A1 = xa[q4*4+1], A2v = xa[q4*4+2], A3 = xa[q4*4+3];
        float4 B0 = xb[q4*4+0], B1 = xb[q4*4+1], B2v = xb[q4*4+2], B3 = xb[q4*4+3];
        a0=fmaf(A0.x,xj0.x,a0); a1=fmaf(A0.y,xj0.y,a1); a2=fmaf(A0.z,xj0.z,a2); a3=fmaf(A0.w,xj0.w,a3);
        b0=fmaf(B0.x,xj0.x,b0); b1=fmaf(B0.y,xj0.y,b1); b2=fmaf(B0.z,xj0.z,b2); b3=fmaf(B0.w,xj0.w,b3);
        a0=fmaf(A1.x,xj1.x,a0); a1=fmaf(A1.y,xj1.y,a1); a2=fmaf(A1.z,xj1.z,a2); a3=fmaf(A1.w,xj1.w,a3);
        b0=fmaf(B1.x,xj1.x,b0); b1=fmaf(B1.y,xj1.y,b1); b2=fmaf(B1.z,xj1.z,b2); b3=fmaf(B1.w,xj1.w,b3);
        a0=fmaf(A2v.x,xj2.x,a0); a1=fmaf(A2v.y,xj2.y,a1); a2=fmaf(A2v.z,xj2.z,a2); a3=fmaf(A2v.w,xj2.w,a3);
        b0=fmaf(B2v.x,xj2.x,b0); b1=fmaf(B2v.y,xj2.y,b1); b2=fmaf(B2v.z,xj2.z,b2); b3=fmaf(B2v.w,xj2.w,b3);
        a0=fmaf(A3.x,xj3.x,a0); a1=fmaf(A3.y,xj3.y,a1); a2=fmaf(A3.z,xj3.z,a2); a3=fmaf(A3.w,xj3.w,a3);
        b0=fmaf(B3.x,xj3.x,b0); b1=fmaf(B3.y,xj3.y,b1); b2=fmaf(B3.z,xj3.z,b2); b3=fmaf(B3.w,xj3.w,b3);
      }
      float dot1 = (a0+a1)+(a2+a3);
      float dot2 = (b0+b1)+(b2+b3);
      int jj = jb + j;
      float d2a = (sqi1 + sqjc) - 2.f*dot1;
      float d2b = (sqi2 + sqjc) - 2.f*dot2;
      bool ia = !(d2a > thra) && (jj != i1);
      bool ib = !(d2b > thrb) && (jj != i2);
      if (__builtin_expect(ia | ib, 0)){
        if (ia){
          u64 ka = (((u64)fenc(d2a))<<32) | (unsigned)jj;
          bub8(t8a, ka);
          thra = fdec((unsigned)(t8a[7]>>32));
        }
        if (ib){
          u64 kb = (((u64)fenc(d2b))<<32) | (unsigned)jj;
          bub8(t8b, kb);
          thrb = fdec((unsigned)(t8b[7]>>32));
        }
      }
    }
  }
  u64* pa = parts + ((size_t)blockIdx.y*NN + i1)*8;
  u64* pb = parts + ((size_t)blockIdx.y*NN + i2)*8;
#pragma unroll
  for (int q=0;q<8;q++){ pa[q] = t8a[q]; pb[q] = t8b[q]; }
}

__global__ __launch_bounds__(256) void k_knn_merge(const u64* __restrict__ parts, int CH, unsigned* __restrict__ nbr){
  int r = blockIdx.x*256 + threadIdx.x;
  u64 t8[8];
#pragma unroll
  for (int q=0;q<8;q++) t8[q] = ~0ull;
  for (int ch=0; ch<CH; ch++){
    const u64* p = parts + ((size_t)ch*NN + r)*8;
    u64 k[8];
#pragma unroll
    for (int q=0;q<8;q++) k[q] = p[q];
#pragma unroll
    for (int q=0;q<8;q++){
      if (k[q] >= t8[7]) break;
      bub8(t8, k[q]);
    }
  }
#pragma unroll
  for (int s=0;s<8;s++) nbr[r*Kc + s] = (unsigned)(t8[s] & 0xffffffffu);
}

// ---------------- edge2 precompute: A2 = x1bn@(W1t-W1b)+b1 ; Q = x1bn@W1b ----------------
__global__ __launch_bounds__(256) void k_pq(const float* __restrict__ x1bn, const float* __restrict__ w1, const float* __restrict__ b1,
                                            float* __restrict__ A2, float* __restrict__ Qm){
  __shared__ float xs[16][64];
  int t = threadIdx.x;
  int j = t & 63, w = t >> 6;
  float wa[64], wb[64];
#pragma unroll
  for (int k=0;k<64;k++){
    float wt  = w1[k*64 + j];
    float wbv = w1[(64+k)*64 + j];
    wa[k] = wt - wbv; wb[k] = wbv;
  }
  float b1j = b1[j];
  int nb = blockIdx.x * 16;
  for (int q=t; q<16*64; q+=256) xs[q>>6][q&63] = x1bn[(size_t)(nb + (q>>6))*64 + (q&63)];
  __syncthreads();
#pragma unroll
  for (int it=0; it<4; it++){
    int nl = it*4 + w;
    float a = b1j, qq = 0.f;
#pragma unroll
    for (int k=0;k<64;k++){
      float xv = xs[nl][k];
      a  = fmaf(xv, wa[k], a);
      qq = fmaf(xv, wb[k], qq);
    }
    int n = nb + nl;
    A2[(size_t)n*64 + j] = a;
    Qm[(size_t)n*64 + j] = qq;
  }
}

// ---------------- edge2: per-destination-block GEMM + LDS max, no global atomics ----------------
__global__ __launch_bounds__(128) void k_edge2max(const float* __restrict__ A2, const float* __restrict__ Qm,
        const unsigned* __restrict__ nbr, const unsigned* __restrict__ rptr, const unsigned* __restrict__ rlist,
        const float* __restrict__ w2, const float* __restrict__ b2, float* __restrict__ x2f){
  __shared__ __align__(16) float W2T[64][68];
  __shared__ __align__(16) float hidT[64][132];
  __shared__ unsigned x2s[17][64];
  __shared__ unsigned rp_s[17];
  __shared__ int wslot[128];
  int t = threadIdx.x;
  int d0 = blockIdx.x * 16;
  for (int q=t; q<64*64; q+=128) W2T[q&63][q>>6] = w2[q];
  for (int q=t; q<17*64; q+=128) ((unsigned*)x2s)[q] = 0x007FFFFFu;
  if (t < 17) rp_s[t] = rptr[d0 + t];
  __syncthreads();
  unsigned rp0 = rp_s[0];
  int total_rev = (int)(rp_s[16] - rp0);
  int eg = t & 15, cg = t >> 4;
  int r0 = eg*8, c0 = cg*8;
  float b2v[8];
#pragma unroll
  for (int cc=0;cc<8;cc++) b2v[cc] = b2[c0+cc];
  int ntile = 1 + ((total_rev + 127) >> 7);
  for (int tile=0; tile<ntile; tile++){
    int d, s, active;
    if (tile == 0){
      d = d0 + (t>>3); s = (int)nbr[(size_t)d*8 + (t&7)]; active = 1; wslot[t] = t>>3;
    } else {
      int idx = (tile-1)*128 + t;
      active = idx < total_rev;
      if (active){
        unsigned pos = rp0 + (unsigned)idx;
        int sl = 0;
#pragma unroll
        for (int m=1; m<16; m++) sl += (pos >= rp_s[m]) ? 1 : 0;
        s = (int)rlist[pos];
        d = d0 + sl;
        wslot[t] = sl;
      } else { d = d0; s = 0; wslot[t] = 16; }
    }
    if (active){
      const float* pa = A2 + (size_t)d*64;
      const float* pq = Qm + (size_t)s*64;
#pragma unroll
      for (int c4=0; c4<16; c4++){
        float4 va = *(const float4*)(pa + c4*4);
        float4 vq = *(const float4*)(pq + c4*4);
        hidT[c4*4+0][t] = fmaxf(va.x+vq.x, 0.f);
        hidT[c4*4+1][t] = fmaxf(va.y+vq.y, 0.f);
        hidT[c4*4+2][t] = fmaxf(va.z+vq.z, 0.f);
        hidT[c4*4+3][t] = fmaxf(va.w+vq.w, 0.f);
      }
    } else {
#pragma unroll
      for (int c4=0; c4<16; c4++){
        hidT[c4*4+0][t] = 0.f; hidT[c4*4+1][t] = 0.f;
        hidT[c4*4+2][t] = 0.f; hidT[c4*4+3][t] = 0.f;
      }
    }
    __syncthreads();
    float acc[8][8];
#pragma unroll
    for (int i=0;i<8;i++)
#pragma unroll
      for (int cc=0;cc<8;cc++) acc[i][cc] = 0.f;
    for (int k=0;k<64;k+=4){
      float4 wv[8];
#pragma unroll
      for (int cc=0;cc<8;cc++) wv[cc] = *(const float4*)&W2T[c0+cc][k];
#pragma unroll
      for (int kk=0;kk<4;kk++){
        float4 h0 = *(const float4*)&hidT[k+kk][r0];
        float4 h1 = *(const float4*)&hidT[k+kk][r0+4];
        float hh[8] = {h0.x,h0.y,h0.z,h0.w,h1.x,h1.y,h1.z,h1.w};
#pragma unroll
        for (int i=0;i<8;i++)
#pragma unroll
          for (int cc=0;cc<8;cc++)
            acc[i][cc] = fmaf(hh[i], ((const float*)&wv[cc])[kk], acc[i][cc]);
      }
    }
    int cur = wslot[r0];
    float mx[8];
#pragma unroll
    for (int cc=0;cc<8;cc++) mx[cc] = acc[0][cc];
    for (int i=1;i<8;i++){
      int sl = wslot[r0+i];
      if (sl != cur){
#pragma unroll
        for (int cc=0;cc<8;cc++) atomicMax(&x2s[cur][c0+cc], fenc(mx[cc] + b2v[cc]));
        cur = sl;
#pragma unroll
        for (int cc=0;cc<8;cc++) mx[cc] = acc[i][cc];
      } else {
#pragma unroll
        for (int cc=0;cc<8;cc++) mx[cc] = fmaxf(mx[cc], acc[i][cc]);
      }
    }
#pragma unroll
    for (int cc=0;cc<8;cc++) atomicMax(&x2s[cur][c0+cc], fenc(mx[cc] + b2v[cc]));
    __syncthreads();
  }
#pragma unroll
  for (int q=0;q<8;q++){
    int idx = t + q*128;
    int sl = idx >> 6, c = idx & 63;
    x2f[(size_t)(d0+sl)*64 + c] = fdec(x2s[sl][c]);
  }
}

__global__ __launch_bounds__(256) void k_apply_bn2f(const float* __restrict__ x2f, const float* __restrict__ sc, const float* __restrict__ sh, float* __restrict__ x2bn){
  int idx = blockIdx.x*256 + threadIdx.x;
  int c = idx & 63;
  x2bn[idx] = x2f[idx]*sc[c] + sh[c];
}

// ---------------- model2 stats via M-matrix: M = Σ D^T D (64x64), S = Σ rows |diff| ----------------
// grid 256 = 32 graphs x 8 z-chunks; per block: 24 z, accumulate M-tile in regs via MFMA.
__global__ __launch_bounds__(256) void k_d_M(const float* __restrict__ x2bn, float* __restrict__ Mpart, float* __restrict__ Spart){
  __shared__ __align__(16) float xgs[192*64];            // 48 KB
  __shared__ __align__(16) unsigned short Gs[64*200];    // 25 KB, row stride 200 bf16 (400B, 16B-aligned, 2-way banks)
  int t = threadIdx.x;
  int g = blockIdx.x >> 3, zc = blockIdx.x & 7;
  const float* xg = x2bn + (size_t)g*NPGc*Hc;
  for (int q=t; q<3072; q+=256)
    *(float4*)&xgs[q*4] = *(const float4*)(xg + (size_t)q*4);
  int w = t>>6, l = t&63, lr = l&15, lg = l>>4;
  int wr = w>>1, wc = w&1;
  f32x4 zero = {0.f,0.f,0.f,0.f};
  f32x4 acc[2][2];
  acc[0][0]=zero; acc[0][1]=zero; acc[1][0]=zero; acc[1][1]=zero;
  float sloc = 0.f;                 // per-thread rowsum partial for k = t&63
  for (int zi=0; zi<24; zi++){
    int z = zc*24 + zi;
    __syncthreads();                // xgs ready (first iter) / Gs reads done (later iters)
#pragma unroll
    for (int q=0;q<48;q++){
      int elem = t + 256*q;         // 12288 = 192 i x 64 k ; k = (t+256q)&63 = t&63 (const per thread)
      int i = elem >> 6, k = elem & 63;
      float d = fabsf(xgs[i*64 + k] - xgs[z*64 + k]);
      unsigned short hv = f2bf(d);
      sloc += __uint_as_float(((unsigned)hv)<<16);   // sum the bf16-quantized value (matches d_main's A)
      Gs[k*200 + i] = hv;
    }
    __syncthreads();
#pragma unroll
    for (int ks=0; ks<6; ks++){
      bf16x8 af[2], bg[2];
#pragma unroll
      for (int mi=0;mi<2;mi++){
        int row = wr*32 + mi*16 + lr;
        af[mi] = *(const bf16x8*)(Gs + row*200 + ks*32 + lg*8);
      }
#pragma unroll
      for (int ni=0;ni<2;ni++){
        int col = wc*32 + ni*16 + lr;
        bg[ni] = *(const bf16x8*)(Gs + col*200 + ks*32 + lg*8);
      }
#pragma unroll
      for (int mi=0;mi<2;mi++)
#pragma unroll
        for (int ni=0;ni<2;ni++)
          acc[mi][ni] = __builtin_amdgcn_mfma_f32_16x16x32_bf16(af[mi], bg[ni], acc[mi][ni], 0,0,0);
    }
  }
  float* mp = Mpart + (size_t)blockIdx.x*4096;
#pragma unroll
  for (int mi=0;mi<2;mi++)
#pragma unroll
    for (int ni=0;ni<2;ni++)
#pragma unroll
      for (int q=0;q<4;q++){
        int Mrow = wr*32 + mi*16 + lg*4 + q;     // verified C/D mapping: row=(lane>>4)*4+q, col=lane&15
        int Mcol = wc*32 + ni*16 + lr;
        mp[Mrow*64 + Mcol] = acc[mi][ni][q];
      }
  __syncthreads();
  xgs[t] = sloc;
  __syncthreads();
  if (t < 64) Spart[(size_t)blockIdx.x*64 + t] = (xgs[t] + xgs[64+t]) + (xgs[128+t] + xgs[192+t]);
}

__global__ __launch_bounds__(256) void k_d_red(const float* __restrict__ Mpart, const float* __restrict__ Spart,
                                               float* __restrict__ Msum, float* __restrict__ Ssum){
  int b = blockIdx.x, t = threadIdx.x;
  if (b < 16){
    int e = b*256 + t;
    float s = 0.f;
    for (int p=0;p<256;p++) s += Mpart[(size_t)p*4096 + e];
    Msum[e] = s;
  } else if (t < 64){
    float s = 0.f;
    for (int p=0;p<256;p++) s += Spart[(size_t)p*64 + t];
    Ssum[t] = s;
  }
}

// dsc/dsh from M,S: mean_c = (S.w_c)/R ; var_c = (w_c^T M w_c)/R - mean^2
__global__ void k_d_fin2(const float* __restrict__ Msum, const float* __restrict__ Ssum, const float* __restrict__ w1,
                         const float* gam, const float* bet, float* dsc, float* dsh){
  int c = threadIdx.x; // 128
  float wv[64];
#pragma unroll
  for (int k=0;k<64;k++) wv[k] = w1[k*HMc + c];
  float mean = 0.f;
#pragma unroll 8
  for (int k=0;k<64;k++) mean = fmaf(Ssum[k], wv[k], mean);
  mean /= (float)RTOTc;
  float msq = 0.f;
  for (int k=0;k<64;k++){
    const float* Mr = Msum + k*64;
    float mk = 0.f;
#pragma unroll 8
    for (int ll=0;ll<64;ll++) mk = fmaf(Mr[ll], wv[ll], mk);
    msq = fmaf(wv[k], mk, msq);
  }
  msq /= (float)RTOTc;
  float var = msq - mean*mean;
  float rs = rsqrtf(var + 1e-5f);
  float kk = rs * gam[c];
  dsc[c] = kk; dsh[c] = bet[c] - mean*kk;
}

// ---------------- model2 main: diff@W1 -> BN -> ReLU -> @W2 -> log_softmax ----------------
__global__ __launch_bounds__(256,2) void k_d_main(const float* __restrict__ x2bn, const float* __restrict__ w1,
                         const float* __restrict__ w2, const float* __restrict__ b2g,
                         const float* __restrict__ dsc, const float* __restrict__ dsh, float* __restrict__ out){
  __shared__ __align__(16) char sm[49152 + 4096 + 1024];
  unsigned char* A   = (unsigned char*)sm;
  unsigned char* W   = (unsigned char*)sm + 24576;
  unsigned char* W2T = (unsigned char*)sm + 49152;
  float* sS = (float*)(sm + 53248);
  int t = threadIdx.x;
  int gid = blockIdx.x; int g = gid / NPGc; int z = gid - g*NPGc;
  const float* xg = x2bn + (size_t)g*NPGc*Hc;
  const float* xz = xg + z*Hc;
  if (t < 128){ sS[t] = dsc[t]; sS[128+t] = dsh[t]; }
  {
    int c = t>>4, kc = t&15;
    ushort4 p0 = make_ushort4(0,0,0,0), p1 = make_ushort4(0,0,0,0);
    if (c < 2){
      p0.x = f2bf(w2[(kc*8+0)*2 + c]); p0.y = f2bf(w2[(kc*8+1)*2 + c]);
      p0.z = f2bf(w2[(kc*8+2)*2 + c]); p0.w = f2bf(w2[(kc*8+3)*2 + c]);
      p1.x = f2bf(w2[(kc*8+4)*2 + c]); p1.y = f2bf(w2[(kc*8+5)*2 + c]);
      p1.z = f2bf(w2[(kc*8+6)*2 + c]); p1.w = f2bf(w2[(kc*8+7)*2 + c]);
    }
    int byte = c*256 + ((kc*16) ^ ((c&7)<<4));
    *(ushort4*)(W2T + byte) = p0;
    *(ushort4*)(W2T + byte + 8) = p1;
  }
#pragma unroll
  for (int q=0;q<8;q++){
    int task = t + 256*q; int c = task & 127; int c4 = task >> 7;
    ushort4 p;
    p.x = f2bf(w1[(4*c4+0)*HMc + c]);
    p.y = f2bf(w1[(4*c4+1)*HMc + c]);
    p.z = f2bf(w1[(4*c4+2)*HMc + c]);
    p.w = f2bf(w1[(4*c4+3)*HMc + c]);
    *(ushort4*)(W + c*128 + ((c4*8) ^ ((c&7)<<4))) = p;
  }
#pragma unroll
  for (int q=0;q<12;q++){
    int task = t + 256*q; int i = task >> 4; int c = task & 15;
    float4 a = *(const float4*)(xg + i*Hc + c*4);
    float4 b = *(const float4*)(xz + c*4);
    ushort4 p;
    p.x = f2bf(fabsf(a.x-b.x)); p.y = f2bf(fabsf(a.y-b.y));
    p.z = f2bf(fabsf(a.z-b.z)); p.w = f2bf(fabsf(a.w-b.w));
    *(ushort4*)(A + i*128 + ((c*8) ^ ((i&7)<<4))) = p;
  }
  __syncthreads();
  int w = t>>6, l = t&63, lr = l&15, lg = l>>4;
  int sw = (lr&7)<<4;
  f32x4 zero = {0.f,0.f,0.f,0.f};
  f32x4 acc[3][8];
#pragma unroll
  for (int r=0;r<3;r++)
#pragma unroll
    for (int c=0;c<8;c++) acc[r][c] = zero;
#pragma unroll
  for (int kk=0;kk<2;kk++){
    bf16x8 af[3], bfr[8];
#pragma unroll
    for (int r=0;r<3;r++){
      int row = (w*3+r)*16 + lr;
      af[r] = *(const bf16x8*)(A + row*128 + ((lg*16 + 64*kk) ^ sw));
    }
#pragma unroll
    for (int c=0;c<8;c++){
      int col = c*16 + lr;
      bfr[c] = *(const bf16x8*)(W + col*128 + ((lg*16 + 64*kk) ^ sw));
    }
#pragma unroll
    for (int r=0;r<3;r++)
#pragma unroll
      for (int c=0;c<8;c++)
        acc[r][c] = __builtin_amdgcn_mfma_f32_16x16x32_bf16(af[r], bfr[c], acc[r][c], 0,0,0);
  }
  __syncthreads();
#pragma unroll
  for (int r=0;r<3;r++){
#pragma unroll
    for (int c=0;c<8;c++){
      int col = c*16 + lr;
      float scl = sS[col], shf = sS[128+col];
#pragma unroll
      for (int q=0;q<4;q++){
        int row = (w*3+r)*16 + lg*4 + q;
        float v = fmaxf(acc[r][c][q]*scl + shf, 0.f);
        *(unsigned short*)(A + row*256 + ((col*2) ^ ((row&7)<<4))) = f2bf(v);
      }
    }
  }
  __syncthreads();
  f32x4 acc2[3];
#pragma unroll
  for (int r=0;r<3;r++) acc2[r] = zero;
#pragma unroll
  for (int kk=0;kk<4;kk++){
    bf16x8 bw = *(const bf16x8*)(W2T + lr*256 + ((lg*16 + 64*kk) ^ sw));
#pragma unroll
    for (int r=0;r<3;r++){
      int row = (w*3+r)*16 + lr;
      bf16x8 ah = *(const bf16x8*)(A + row*256 + ((lg*16 + 64*kk) ^ sw));
      acc2[r] = __builtin_amdgcn_mfma_f32_16x16x32_bf16(ah, bw, acc2[r], 0,0,0);
    }
  }
  float b2a = b2g[0], b2b = b2g[1];
  size_t obase = (size_t)gid * NPGc;
#pragma unroll
  for (int r=0;r<3;r++){
#pragma unroll
    for (int q=0;q<4;q++){
      float o = acc2[r][q];
      float oo = __shfl_xor(o, 1, 64);
      if (lr < 2){
        int row = (w*3+r)*16 + lg*4 + q;
        float self = o + ((lr==0) ? b2a : b2b);
        float oth  = oo + ((lr==0) ? b2b : b2a);
        float mx = fmaxf(self, oth);
        float lse = mx + logf(expf(self-mx) + expf(oth-mx));
        out[(obase + row)*2 + lr] = self - lse;
      }
    }
  }
}

extern "C" void kernel_launch(void* const* d_in, const int* in_sizes, int n_in,
                              void* d_out, int out_size, void* d_ws, size_t ws_size,
                              hipStream_t stream){
  const float* x    = (const float*)d_in[0];
  const int*   ei   = (const int*)d_in[1];
  const float* ea   = (const float*)d_in[2];
  const float* efw1 = (const float*)d_in[4];
  const float* efb1 = (const float*)d_in[5];
  const float* efw2 = (const float*)d_in[6];
  const float* efb2 = (const float*)d_in[7];
  const float* efwr = (const float*)d_in[8];
  const float* bn1g = (const float*)d_in[9];
  const float* bn1b = (const float*)d_in[10];
  const float* ecw1 = (const float*)d_in[11];
  const float* ecb1 = (const float*)d_in[12];
  const float* ecw2 = (const float*)d_in[13];
  const float* ecb2 = (const float*)d_in[14];
  const float* bn2g = (const float*)d_in[15];
  const float* bn2b = (const float*)d_in[16];
  const float* m2w1 = (const float*)d_in[17];
  const float* m2bng = (const float*)d_in[19];
  const float* m2bnb = (const float*)d_in[20];
  const float* m2w2  = (const float*)d_in[21];
  const float* m2b2  = (const float*)d_in[22];

  char* ws = (char*)d_ws;
  float*    x1a   = (float*)(ws + 0);
  float*    x1bn  = (float*)(ws + 1572864);
  float*    x2bn  = (float*)(ws + 3145728);
  float*    x2f   = (float*)(ws + 4718592);
  float*    sqv   = (float*)(ws + 6291456);
  unsigned* nbr   = (unsigned*)(ws + 6316032);
  float*    stats = (float*)(ws + 6512640);
  // CSR scratch: 6581248 .. 6854656
  unsigned* rcnt  = (unsigned*)(ws + 6581248);
  unsigned* rptr  = rcnt + 6400;
  unsigned* rcur  = rptr + 6400;
  unsigned* rlist = rcur + 6400;
  // parts at 6974464 (CH*NN*64 B); EAc overlays it (dead before knn); Mpart/Spart/Msum overlay it (after knn_merge)
  u64*      parts = (u64*)(ws + 6974464);
  float*    EAc   = (float*)(ws + 6974464);
  float*    Mpart = (float*)(ws + 6974464);
  float*    Spart = (float*)(ws + 6974464 + 4194304);
  float*    Msum  = (float*)(ws + 6974464 + 4259840);
  float*    Ssum  = (float*)(ws + 6974464 + 4276224);
  // overlays (disjoint lifetimes):
  float*    A2    = (float*)(ws + 0);            // over x1a (dead after bn1 apply)
  float*    Qm    = (float*)(ws + 3145728);      // over x2bn slot (x2bn written later)
  float*    P1    = (float*)(ws + 3145728);      // edge1 phase only
  float*    P2    = (float*)(ws + 4718592);
  float *g1sum = stats,     *g1ss = stats+64,  *sc1 = stats+128, *sh1 = stats+192;
  float *g2sum = stats+256, *g2ss = stats+320, *sc2 = stats+384, *sh2 = stats+448;
  float *dsc = stats+512, *dsh = stats+640;
  float* outp = (float*)d_out;

  int CH = 96;
  if (ws_size < 6974464ull + (size_t)NN*96*64) CH = 48;
  if (ws_size < 6974464ull + (size_t)NN*48*64) CH = 24;

  k_init<<<3,256,0,stream>>>(stats);
  k_root<<<1536,256,0,stream>>>(x, efwr, x1a);
  k_eac<<<3072,256,0,stream>>>(ea, efw1, EAc);
  k_zero_cnt<<<24,256,0,stream>>>(rcnt);
  k_cnt_dst<<<192,256,0,stream>>>(ei, rcnt);
  k_scan<<<1,256,0,stream>>>(rcnt, rptr, rcur);
  k_fill_dst<<<192,256,0,stream>>>(ei, rcur, rlist);
  k_p12<<<384,256,0,stream>>>(x, efw1, efb1, P1, P2);
  k_node1<<<384,128,0,stream>>>(P1, P2, EAc, ei, rptr, rlist, efw2, efb2, x1a);
  k_bn_stats<<<96,256,0,stream>>>(x1a, g1sum, g1ss);
  k_bn_fin<<<1,64,0,stream>>>(g1sum, g1ss, bn1g, bn1b, sc1, sh1);
  k_apply_bn1_sq<<<1536,256,0,stream>>>(x1a, sc1, sh1, x1bn, sqv);
  dim3 kg(24, CH);
  k_knn<<<kg,128,0,stream>>>(x1bn, sqv, parts, CH);
  k_knn_merge<<<24,256,0,stream>>>(parts, CH, nbr);
  k_zero_cnt<<<24,256,0,stream>>>(rcnt);
  k_rev_cnt<<<192,256,0,stream>>>(nbr, rcnt);
  k_scan<<<1,256,0,stream>>>(rcnt, rptr, rcur);
  k_rev_fill<<<192,256,0,stream>>>(nbr, rcur, rlist);
  k_pq<<<384,256,0,stream>>>(x1bn, ecw1, ecb1, A2, Qm);
  k_edge2max<<<384,128,0,stream>>>(A2, Qm, nbr, rptr, rlist, ecw2, ecb2, x2f);
  k_bn_stats<<<96,256,0,stream>>>(x2f, g2sum, g2ss);
  k_bn_fin<<<1,64,0,stream>>>(g2sum, g2ss, bn2g, bn2b, sc2, sh2);
  k_apply_bn2f<<<1536,256,0,stream>>>(x2f, sc2, sh2, x2bn);
  k_d_M<<<256,256,0,stream>>>(x2bn, Mpart, Spart);
  k_d_red<<<17,256,0,stream>>>(Mpart, Spart, Msum, Ssum);
  k_d_fin2<<<1,128,0,stream>>>(Msum, Ssum, m2w1, m2bng, m2bnb, dsc, dsh);
  k_d_main<<<6144,256,0,stream>>>(x2bn, m2w1, m2w2, m2b2, dsc, dsh, outp);
}

// Round 11
// 560.010 us; speedup vs baseline: 1.1831x; 1.1831x over previous
//
#include <hip/hip_runtime.h>

#define NN 6144
#define GG 32
#define NPGc 192
#define FINc 32
#define FEc 8
#define Hc 64
#define HMc 128
#define Kc 8
#define Ec 49152
#define NKc (NN*Kc)
#define RTOTc (GG*NPGc*NPGc)

typedef float f32x4 __attribute__((ext_vector_type(4)));
typedef float f32x2 __attribute__((ext_vector_type(2)));
typedef short bf16x8 __attribute__((ext_vector_type(8)));
typedef unsigned long long u64;

__device__ __forceinline__ unsigned short f2bf(float f){
  unsigned u = __float_as_uint(f);
  unsigned r = u + 0x7fffu + ((u>>16)&1u);
  return (unsigned short)(r>>16);
}
__device__ __forceinline__ unsigned fenc(float f){
  unsigned u = __float_as_uint(f);
  return (u & 0x80000000u) ? ~u : (u | 0x80000000u);
}
__device__ __forceinline__ float fdec(unsigned e){
  unsigned u = (e & 0x80000000u) ? (e & 0x7fffffffu) : ~e;
  return __uint_as_float(u);
}
__device__ __forceinline__ void bub8(u64* t8, u64 k){
#pragma unroll
  for (int q=0;q<8;q++){ u64 cur=t8[q]; u64 lo=(k<cur)?k:cur; u64 hi=(k<cur)?cur:k; t8[q]=lo; k=hi; }
}

// ---------------- init: zero accumulators ----------------
__global__ void k_init(float* dbins, float* stats){
  int idx = blockIdx.x*256 + threadIdx.x;
  if (idx < 64*256) dbins[idx] = 0.f;
  if (idx < 768) stats[idx] = 0.f;
}

// ---------------- x1a = x @ ef_wroot ----------------
__global__ __launch_bounds__(256) void k_root(const float* __restrict__ x, const float* __restrict__ wr, float* __restrict__ x1a){
  __shared__ float Ws[FINc*Hc];
  __shared__ float xr[4][FINc];
  int t = threadIdx.x;
  for (int q=t;q<FINc*Hc;q+=256) Ws[q] = wr[q];
  int rg = t>>6, j = t&63;
  int r = blockIdx.x*4 + rg;
  if (j < FINc) xr[rg][j] = x[r*FINc + j];
  __syncthreads();
  float a0=0.f, a1=0.f;
#pragma unroll
  for (int k=0;k<FINc;k+=2){
    a0 = fmaf(xr[rg][k],   Ws[k*Hc+j],     a0);
    a1 = fmaf(xr[rg][k+1], Ws[(k+1)*Hc+j], a1);
  }
  x1a[r*Hc + j] = a0 + a1;
}

// ---------------- edge1 precompute: EAc[e] = ea[e] @ W1c (rows 64..71) ----------------
__global__ __launch_bounds__(256) void k_eac(const float* __restrict__ ea, const float* __restrict__ w1, float* __restrict__ EAc){
  __shared__ float Wc[FEc*Hc];
  int t = threadIdx.x;
  for (int q=t; q<FEc*Hc; q+=256) Wc[q] = w1[64*Hc + q];
  __syncthreads();
  int idx = blockIdx.x*256 + t;
  int e = idx >> 4, c4 = (idx & 15)*4;
  float av[8];
#pragma unroll
  for (int q=0;q<8;q++) av[q] = ea[e*FEc + q];
  float4 o = {0.f,0.f,0.f,0.f};
#pragma unroll
  for (int q=0;q<8;q++){
    o.x = fmaf(av[q], Wc[q*Hc + c4+0], o.x);
    o.y = fmaf(av[q], Wc[q*Hc + c4+1], o.y);
    o.z = fmaf(av[q], Wc[q*Hc + c4+2], o.z);
    o.w = fmaf(av[q], Wc[q*Hc + c4+3], o.w);
  }
  *(float4*)(EAc + (size_t)e*Hc + c4) = o;
}

// ---------------- edge1 precompute: P1 = x@W1a + b1 (dst part), P2 = x@W1b (src part) ----------------
__global__ __launch_bounds__(256) void k_p12(const float* __restrict__ x, const float* __restrict__ w1, const float* __restrict__ b1,
                                             float* __restrict__ P1, float* __restrict__ P2){
  __shared__ float xs[16][32];
  int t = threadIdx.x;
  int j = t & 63, w = t >> 6;
  float wa[32], wb[32];
#pragma unroll
  for (int k=0;k<32;k++){
    wa[k] = w1[k*Hc + j];
    wb[k] = w1[(32+k)*Hc + j];
  }
  float b1j = b1[j];
  int nb = blockIdx.x * 16;
  for (int q=t; q<16*32; q+=256) xs[q>>5][q&31] = x[(size_t)(nb + (q>>5))*FINc + (q&31)];
  __syncthreads();
#pragma unroll
  for (int it=0; it<4; it++){
    int nl = it*4 + w;
    float a = b1j, b = 0.f;
#pragma unroll
    for (int k=0;k<32;k++){
      float xv = xs[nl][k];
      a = fmaf(xv, wa[k], a);
      b = fmaf(xv, wb[k], b);
    }
    int n = nb + nl;
    P1[(size_t)n*Hc + j] = a;
    P2[(size_t)n*Hc + j] = b;
  }
}

// ---------------- generic CSR build pieces ----------------
__global__ void k_zero_cnt(unsigned* rcnt){
  int idx = blockIdx.x*256 + threadIdx.x;
  if (idx < NN) rcnt[idx] = 0u;
}
__global__ void k_cnt_dst(const int* __restrict__ ei, unsigned* __restrict__ rcnt){
  int e = blockIdx.x*256 + threadIdx.x;
  atomicAdd(&rcnt[ei[Ec + e]], 1u);
}
__global__ __launch_bounds__(256) void k_scan(const unsigned* __restrict__ rcnt, unsigned* __restrict__ rptr, unsigned* __restrict__ rcur){
  __shared__ unsigned ps[256];
  int t = threadIdx.x;
  unsigned loc[24];
  unsigned s = 0;
#pragma unroll
  for (int q=0;q<24;q++){ loc[q] = s; s += rcnt[t*24+q]; }
  ps[t] = s;
  __syncthreads();
  for (int off=1; off<256; off<<=1){
    unsigned v = (t>=off)? ps[t-off] : 0u;
    __syncthreads();
    ps[t] += v;
    __syncthreads();
  }
  unsigned base = (t==0)? 0u : ps[t-1];
#pragma unroll
  for (int q=0;q<24;q++){ unsigned v = base + loc[q]; rptr[t*24+q]=v; rcur[t*24+q]=v; }
  if (t==255) rptr[NN] = ps[255];
}
__global__ void k_fill_dst(const int* __restrict__ ei, unsigned* __restrict__ rcur, unsigned* __restrict__ rlist){
  int e = blockIdx.x*256 + threadIdx.x;
  unsigned pos = atomicAdd(&rcur[ei[Ec + e]], 1u);
  rlist[pos] = (unsigned)e;
}
__global__ void k_rev_cnt(const unsigned* __restrict__ nbr, unsigned* __restrict__ rcnt){
  int e = blockIdx.x*256 + threadIdx.x;
  atomicAdd(&rcnt[nbr[e]], 1u);
}
__global__ void k_rev_fill(const unsigned* __restrict__ nbr, unsigned* __restrict__ rcur, unsigned* __restrict__ rlist){
  int e = blockIdx.x*256 + threadIdx.x;
  unsigned pos = atomicAdd(&rcur[nbr[e]], 1u);
  rlist[pos] = (unsigned)(e >> 3);
}

// ---------------- edge1 aggregate: x1a[n] += (Σ_in relu(P1[n]+P2[s]+EAc[e])) @ W2 + deg·b2 ----------------
__global__ __launch_bounds__(128) void k_node1(const float* __restrict__ P1, const float* __restrict__ P2, const float* __restrict__ EAc,
        const int* __restrict__ ei, const unsigned* __restrict__ rptr, const unsigned* __restrict__ rlist,
        const float* __restrict__ w2, const float* __restrict__ b2, float* __restrict__ x1a){
  __shared__ __align__(16) float accs[16][68];
  __shared__ __align__(16) float W2T[64][68];
  __shared__ unsigned rp_s[17];
  int t = threadIdx.x;
  int d0 = blockIdx.x * 16;
  for (int q=t; q<64*64; q+=128) W2T[q&63][q>>6] = w2[q];
  if (t < 17) rp_s[t] = rptr[d0 + t];
  __syncthreads();
  int slot = t>>3, cg = t&7, c0 = cg*8;
  int n = d0 + slot;
  float4 p1a = *(const float4*)(P1 + (size_t)n*Hc + c0);
  float4 p1b = *(const float4*)(P1 + (size_t)n*Hc + c0 + 4);
  float acc[8];
#pragma unroll
  for (int q=0;q<8;q++) acc[q] = 0.f;
  unsigned beg = rp_s[slot], end = rp_s[slot+1];
  for (unsigned pos=beg; pos<end; pos++){
    unsigned e = rlist[pos];
    int s = ei[e];
    float4 qa = *(const float4*)(P2 + (size_t)s*Hc + c0);
    float4 qb = *(const float4*)(P2 + (size_t)s*Hc + c0 + 4);
    float4 fa = *(const float4*)(EAc + (size_t)e*Hc + c0);
    float4 fb = *(const float4*)(EAc + (size_t)e*Hc + c0 + 4);
    acc[0] += fmaxf(p1a.x + qa.x + fa.x, 0.f);
    acc[1] += fmaxf(p1a.y + qa.y + fa.y, 0.f);
    acc[2] += fmaxf(p1a.z + qa.z + fa.z, 0.f);
    acc[3] += fmaxf(p1a.w + qa.w + fa.w, 0.f);
    acc[4] += fmaxf(p1b.x + qb.x + fb.x, 0.f);
    acc[5] += fmaxf(p1b.y + qb.y + fb.y, 0.f);
    acc[6] += fmaxf(p1b.z + qb.z + fb.z, 0.f);
    acc[7] += fmaxf(p1b.w + qb.w + fb.w, 0.f);
  }
  *(float4*)&accs[slot][c0]   = make_float4(acc[0],acc[1],acc[2],acc[3]);
  *(float4*)&accs[slot][c0+4] = make_float4(acc[4],acc[5],acc[6],acc[7]);
  __syncthreads();
  float out[8];
#pragma unroll
  for (int q=0;q<8;q++) out[q] = 0.f;
  for (int k4=0;k4<16;k4++){
    float4 hv = *(const float4*)&accs[slot][k4*4];
#pragma unroll
    for (int cc=0;cc<8;cc++){
      float4 wv = *(const float4*)&W2T[c0+cc][k4*4];
      out[cc] = fmaf(hv.x,wv.x, fmaf(hv.y,wv.y, fmaf(hv.z,wv.z, fmaf(hv.w,wv.w, out[cc]))));
    }
  }
  float deg = (float)(end - beg);
  float* px = x1a + (size_t)n*Hc + c0;
#pragma unroll
  for (int cc=0;cc<8;cc++) px[cc] += out[cc] + deg*b2[c0+cc];
}

// ---------------- BN stats over N rows x 64 cols ----------------
__global__ __launch_bounds__(256) void k_bn_stats(const float* __restrict__ src, float* __restrict__ gsum, float* __restrict__ gss){
  int t = threadIdx.x;
  int c = t & 63;
  int r0 = blockIdx.x*64 + (t>>6);
  float s=0.f, ss=0.f;
  for (int it=0; it<16; it++){
    int r = r0 + it*4;
    float v = src[r*Hc + c];
    s += v; ss += v*v;
  }
  __shared__ float S[64], SS[64];
  if (t < 64){ S[t]=0.f; SS[t]=0.f; }
  __syncthreads();
  atomicAdd(&S[c], s); atomicAdd(&SS[c], ss);
  __syncthreads();
  if (t < 64){ atomicAdd(&gsum[t], S[t]); atomicAdd(&gss[t], SS[t]); }
}

__global__ void k_bn_fin(const float* gsum, const float* gss, const float* gam, const float* bet, float* sc, float* sh){
  int c = threadIdx.x; // 64
  float mean = gsum[c] / (float)NN;
  float var  = gss[c] / (float)NN - mean*mean;
  float rs = rsqrtf(var + 1e-5f);
  float s = rs * gam[c];
  sc[c] = s; sh[c] = bet[c] - mean*s;
}

// ---------------- apply BN1 + per-row squared norm ----------------
__global__ __launch_bounds__(256) void k_apply_bn1_sq(const float* __restrict__ x1a, const float* __restrict__ sc, const float* __restrict__ sh,
                               float* __restrict__ x1bn, float* __restrict__ sqv){
  int t = threadIdx.x;
  int c = t & 63;
  int r = blockIdx.x*4 + (t>>6);
  float v = x1a[r*Hc + c]*sc[c] + sh[c];
  x1bn[r*Hc + c] = v;
  float s = v*v;
#pragma unroll
  for (int off=1; off<64; off<<=1) s += __shfl_xor(s, off, 64);
  if (c == 0) sqv[r] = s;
}

// ---------------- KNN: LDS-broadcast distances + online top-8, packed v_pk_fma_f32 ----------------
// Pairing (a0,a1)<-(x,y), (a2,a3)<-(z,w) preserves per-component fma order exactly -> d2 bit-identical to r6.
__global__ __launch_bounds__(128,2) void k_knn(const float* __restrict__ x1bn, const float* __restrict__ sqv, u64* __restrict__ parts, int CH){
  __shared__ __align__(16) float XJ[64][68];
  __shared__ float sqj[64];
  int t = threadIdx.x;
  int i1 = blockIdx.x*256 + t;
  int i2 = i1 + 128;
  f32x2 xa2[32], xb2[32];
#pragma unroll
  for (int q=0;q<16;q++){
    float4 va = *(const float4*)(x1bn + (size_t)i1*Hc + q*4);
    float4 vb = *(const float4*)(x1bn + (size_t)i2*Hc + q*4);
    xa2[2*q]   = (f32x2){va.x, va.y};
    xa2[2*q+1] = (f32x2){va.z, va.w};
    xb2[2*q]   = (f32x2){vb.x, vb.y};
    xb2[2*q+1] = (f32x2){vb.z, vb.w};
  }
  float sqi1 = sqv[i1], sqi2 = sqv[i2];
  u64 t8a[8], t8b[8];
#pragma unroll
  for (int q=0;q<8;q++){ t8a[q] = ~0ull; t8b[q] = ~0ull; }
  float thra = __uint_as_float(0x7f800000u);
  float thrb = thra;
  int cpc = NN / CH;
  int nsub = cpc >> 6;
  int jbase0 = blockIdx.y * cpc;
  for (int sub=0; sub<nsub; sub++){
    int jb = jbase0 + sub*64;
    __syncthreads();
    {
      int c = t>>1, hh = t&1;
      const float4* srcp = (const float4*)(x1bn + (size_t)(jb + c)*Hc + hh*32);
#pragma unroll
      for (int q=0;q<8;q++) *(float4*)&XJ[c][hh*32 + q*4] = srcp[q];
      if (t < 64) sqj[t] = sqv[jb + t];
    }
    __syncthreads();
    for (int j=0;j<64;j++){
      float sqjc = sqj[j];
      f32x2 a01 = {0.f,0.f}, a23 = {0.f,0.f}, b01 = {0.f,0.f}, b23 = {0.f,0.f};
#pragma unroll
      for (int q=0;q<16;q++){
        float4 xjv = *(const float4*)&XJ[j][q*4];   // one ds_read_b128 (unchanged LDS pattern)
        f32x2 xlo = {xjv.x, xjv.y};
        f32x2 xhi = {xjv.z, xjv.w};
        a01 = __builtin_elementwise_fma(xa2[2*q],   xlo, a01);
        a23 = __builtin_elementwise_fma(xa2[2*q+1], xhi, a23);
        b01 = __builtin_elementwise_fma(xb2[2*q],   xlo, b01);
        b23 = __builtin_elementwise_fma(xb2[2*q+1], xhi, b23);
      }
      float dot1 = (a01.x + a01.y) + (a23.x + a23.y);
      float dot2 = (b01.x + b01.y) + (b23.x + b23.y);
      int jj = jb + j;
      float d2a = (sqi1 + sqjc) - 2.f*dot1;
      float d2b = (sqi2 + sqjc) - 2.f*dot2;
      bool ia = !(d2a > thra) && (jj != i1);
      bool ib = !(d2b > thrb) && (jj != i2);
      if (__builtin_expect(ia | ib, 0)){
        if (ia){
          u64 ka = (((u64)fenc(d2a))<<32) | (unsigned)jj;
          bub8(t8a, ka);
          thra = fdec((unsigned)(t8a[7]>>32));
        }
        if (ib){
          u64 kb = (((u64)fenc(d2b))<<32) | (unsigned)jj;
          bub8(t8b, kb);
          thrb = fdec((unsigned)(t8b[7]>>32));
        }
      }
    }
  }
  u64* pa = parts + ((size_t)blockIdx.y*NN + i1)*8;
  u64* pb = parts + ((size_t)blockIdx.y*NN + i2)*8;
#pragma unroll
  for (int q=0;q<8;q++){ pa[q] = t8a[q]; pb[q] = t8b[q]; }
}

__global__ __launch_bounds__(256) void k_knn_merge(const u64* __restrict__ parts, int CH, unsigned* __restrict__ nbr){
  int r = blockIdx.x*256 + threadIdx.x;
  u64 t8[8];
#pragma unroll
  for (int q=0;q<8;q++) t8[q] = ~0ull;
  for (int ch=0; ch<CH; ch++){
    const u64* p = parts + ((size_t)ch*NN + r)*8;
    u64 k[8];
#pragma unroll
    for (int q=0;q<8;q++) k[q] = p[q];
#pragma unroll
    for (int q=0;q<8;q++){
      if (k[q] >= t8[7]) break;
      bub8(t8, k[q]);
    }
  }
#pragma unroll
  for (int s=0;s<8;s++) nbr[r*Kc + s] = (unsigned)(t8[s] & 0xffffffffu);
}

// ---------------- edge2 precompute: A2 = x1bn@(W1t-W1b)+b1 ; Q = x1bn@W1b ----------------
__global__ __launch_bounds__(256) void k_pq(const float* __restrict__ x1bn, const float* __restrict__ w1, const float* __restrict__ b1,
                                            float* __restrict__ A2, float* __restrict__ Qm){
  __shared__ float xs[16][64];
  int t = threadIdx.x;
  int j = t & 63, w = t >> 6;
  float wa[64], wb[64];
#pragma unroll
  for (int k=0;k<64;k++){
    float wt  = w1[k*64 + j];
    float wbv = w1[(64+k)*64 + j];
    wa[k] = wt - wbv; wb[k] = wbv;
  }
  float b1j = b1[j];
  int nb = blockIdx.x * 16;
  for (int q=t; q<16*64; q+=256) xs[q>>6][q&63] = x1bn[(size_t)(nb + (q>>6))*64 + (q&63)];
  __syncthreads();
#pragma unroll
  for (int it=0; it<4; it++){
    int nl = it*4 + w;
    float a = b1j, qq = 0.f;
#pragma unroll
    for (int k=0;k<64;k++){
      float xv = xs[nl][k];
      a  = fmaf(xv, wa[k], a);
      qq = fmaf(xv, wb[k], qq);
    }
    int n = nb + nl;
    A2[(size_t)n*64 + j] = a;
    Qm[(size_t)n*64 + j] = qq;
  }
}

// ---------------- edge2: per-destination-block GEMM + LDS max, no global atomics ----------------
__global__ __launch_bounds__(128) void k_edge2max(const float* __restrict__ A2, const float* __restrict__ Qm,
        const unsigned* __restrict__ nbr, const unsigned* __restrict__ rptr, const unsigned* __restrict__ rlist,
        const float* __restrict__ w2, const float* __restrict__ b2, float* __restrict__ x2f){
  __shared__ __align__(16) float W2T[64][68];
  __shared__ __align__(16) float hidT[64][132];
  __shared__ unsigned x2s[17][64];
  __shared__ unsigned rp_s[17];
  __shared__ int wslot[128];
  int t = threadIdx.x;
  int d0 = blockIdx.x * 16;
  for (int q=t; q<64*64; q+=128) W2T[q&63][q>>6] = w2[q];
  for (int q=t; q<17*64; q+=128) ((unsigned*)x2s)[q] = 0x007FFFFFu;
  if (t < 17) rp_s[t] = rptr[d0 + t];
  __syncthreads();
  unsigned rp0 = rp_s[0];
  int total_rev = (int)(rp_s[16] - rp0);
  int eg = t & 15, cg = t >> 4;
  int r0 = eg*8, c0 = cg*8;
  float b2v[8];
#pragma unroll
  for (int cc=0;cc<8;cc++) b2v[cc] = b2[c0+cc];
  int ntile = 1 + ((total_rev + 127) >> 7);
  for (int tile=0; tile<ntile; tile++){
    int d, s, active;
    if (tile == 0){
      d = d0 + (t>>3); s = (int)nbr[(size_t)d*8 + (t&7)]; active = 1; wslot[t] = t>>3;
    } else {
      int idx = (tile-1)*128 + t;
      active = idx < total_rev;
      if (active){
        unsigned pos = rp0 + (unsigned)idx;
        int sl = 0;
#pragma unroll
        for (int m=1; m<16; m++) sl += (pos >= rp_s[m]) ? 1 : 0;
        s = (int)rlist[pos];
        d = d0 + sl;
        wslot[t] = sl;
      } else { d = d0; s = 0; wslot[t] = 16; }
    }
    if (active){
      const float* pa = A2 + (size_t)d*64;
      const float* pq = Qm + (size_t)s*64;
#pragma unroll
      for (int c4=0; c4<16; c4++){
        float4 va = *(const float4*)(pa + c4*4);
        float4 vq = *(const float4*)(pq + c4*4);
        hidT[c4*4+0][t] = fmaxf(va.x+vq.x, 0.f);
        hidT[c4*4+1][t] = fmaxf(va.y+vq.y, 0.f);
        hidT[c4*4+2][t] = fmaxf(va.z+vq.z, 0.f);
        hidT[c4*4+3][t] = fmaxf(va.w+vq.w, 0.f);
      }
    } else {
#pragma unroll
      for (int c4=0; c4<16; c4++){
        hidT[c4*4+0][t] = 0.f; hidT[c4*4+1][t] = 0.f;
        hidT[c4*4+2][t] = 0.f; hidT[c4*4+3][t] = 0.f;
      }
    }
    __syncthreads();
    float acc[8][8];
#pragma unroll
    for (int i=0;i<8;i++)
#pragma unroll
      for (int cc=0;cc<8;cc++) acc[i][cc] = 0.f;
    for (int k=0;k<64;k+=4){
      float4 wv[8];
#pragma unroll
      for (int cc=0;cc<8;cc++) wv[cc] = *(const float4*)&W2T[c0+cc][k];
#pragma unroll
      for (int kk=0;kk<4;kk++){
        float4 h0 = *(const float4*)&hidT[k+kk][r0];
        float4 h1 = *(const float4*)&hidT[k+kk][r0+4];
        float hh[8] = {h0.x,h0.y,h0.z,h0.w,h1.x,h1.y,h1.z,h1.w};
#pragma unroll
        for (int i=0;i<8;i++)
#pragma unroll
          for (int cc=0;cc<8;cc++)
            acc[i][cc] = fmaf(hh[i], ((const float*)&wv[cc])[kk], acc[i][cc]);
      }
    }
    int cur = wslot[r0];
    float mx[8];
#pragma unroll
    for (int cc=0;cc<8;cc++) mx[cc] = acc[0][cc];
    for (int i=1;i<8;i++){
      int sl = wslot[r0+i];
      if (sl != cur){
#pragma unroll
        for (int cc=0;cc<8;cc++) atomicMax(&x2s[cur][c0+cc], fenc(mx[cc] + b2v[cc]));
        cur = sl;
#pragma unroll
        for (int cc=0;cc<8;cc++) mx[cc] = acc[i][cc];
      } else {
#pragma unroll
        for (int cc=0;cc<8;cc++) mx[cc] = fmaxf(mx[cc], acc[i][cc]);
      }
    }
#pragma unroll
    for (int cc=0;cc<8;cc++) atomicMax(&x2s[cur][c0+cc], fenc(mx[cc] + b2v[cc]));
    __syncthreads();
  }
#pragma unroll
  for (int q=0;q<8;q++){
    int idx = t + q*128;
    int sl = idx >> 6, c = idx & 63;
    x2f[(size_t)(d0+sl)*64 + c] = fdec(x2s[sl][c]);
  }
}

__global__ __launch_bounds__(256) void k_apply_bn2f(const float* __restrict__ x2f, const float* __restrict__ sc, const float* __restrict__ sh, float* __restrict__ x2bn){
  int idx = blockIdx.x*256 + threadIdx.x;
  int c = idx & 63;
  x2bn[idx] = x2f[idx]*sc[c] + sh[c];
}

// ---------------- model2 pass 1: column sum/sumsq of diff@W1 via MFMA ----------------
__global__ __launch_bounds__(256,2) void k_d_stats(const float* __restrict__ x2bn, const float* __restrict__ w1, float* __restrict__ dbins){
  __shared__ __align__(16) char sm[24576 + 16384 + 1024];
  unsigned char* A = (unsigned char*)sm;
  unsigned char* W = (unsigned char*)sm + 24576;
  float* Ssum = (float*)(sm + 40960);
  int t = threadIdx.x;
  int gid = blockIdx.x; int g = gid / NPGc; int z = gid - g*NPGc;
  const float* xg = x2bn + (size_t)g*NPGc*Hc;
  const float* xz = xg + z*Hc;
  Ssum[t] = 0.f;
#pragma unroll
  for (int q=0;q<8;q++){
    int task = t + 256*q; int c = task & 127; int c4 = task >> 7;
    ushort4 p;
    p.x = f2bf(w1[(4*c4+0)*HMc + c]);
    p.y = f2bf(w1[(4*c4+1)*HMc + c]);
    p.z = f2bf(w1[(4*c4+2)*HMc + c]);
    p.w = f2bf(w1[(4*c4+3)*HMc + c]);
    *(ushort4*)(W + c*128 + ((c4*8) ^ ((c&7)<<4))) = p;
  }
#pragma unroll
  for (int q=0;q<12;q++){
    int task = t + 256*q; int i = task >> 4; int c = task & 15;
    float4 a = *(const float4*)(xg + i*Hc + c*4);
    float4 b = *(const float4*)(xz + c*4);
    ushort4 p;
    p.x = f2bf(fabsf(a.x-b.x)); p.y = f2bf(fabsf(a.y-b.y));
    p.z = f2bf(fabsf(a.z-b.z)); p.w = f2bf(fabsf(a.w-b.w));
    *(ushort4*)(A + i*128 + ((c*8) ^ ((i&7)<<4))) = p;
  }
  __syncthreads();
  int w = t>>6, l = t&63, lr = l&15, lg = l>>4;
  int sw = (lr&7)<<4;
  f32x4 zero = {0.f,0.f,0.f,0.f};
  f32x4 acc[3][8];
#pragma unroll
  for (int r=0;r<3;r++)
#pragma unroll
    for (int c=0;c<8;c++) acc[r][c] = zero;
#pragma unroll
  for (int kk=0;kk<2;kk++){
    bf16x8 af[3], bfr[8];
#pragma unroll
    for (int r=0;r<3;r++){
      int row = (w*3+r)*16 + lr;
      af[r] = *(const bf16x8*)(A + row*128 + ((lg*16 + 64*kk) ^ sw));
    }
#pragma unroll
    for (int c=0;c<8;c++){
      int col = c*16 + lr;
      bfr[c] = *(const bf16x8*)(W + col*128 + ((lg*16 + 64*kk) ^ sw));
    }
#pragma unroll
    for (int r=0;r<3;r++)
#pragma unroll
      for (int c=0;c<8;c++)
        acc[r][c] = __builtin_amdgcn_mfma_f32_16x16x32_bf16(af[r], bfr[c], acc[r][c], 0,0,0);
  }
#pragma unroll
  for (int c=0;c<8;c++){
    int col = c*16 + lr;
    float s=0.f, ss=0.f;
#pragma unroll
    for (int r=0;r<3;r++)
#pragma unroll
      for (int q=0;q<4;q++){ float v = acc[r][c][q]; s += v; ss = fmaf(v,v,ss); }
    s  += __shfl_xor(s, 16, 64);  ss += __shfl_xor(ss, 16, 64);
    s  += __shfl_xor(s, 32, 64);  ss += __shfl_xor(ss, 32, 64);
    if (lg == 0){
      atomicAdd(&Ssum[col], s);
      atomicAdd(&Ssum[128+col], ss);
    }
  }
  __syncthreads();
  if (t < 128){
    int bin = gid & 63;
    atomicAdd(&dbins[bin*256 + t], Ssum[t]);
    atomicAdd(&dbins[bin*256 + 128 + t], Ssum[128+t]);
  }
}

__global__ void k_d_fin(const float* __restrict__ dbins, const float* gam, const float* bet, float* dsc, float* dsh){
  int c = threadIdx.x; // 128
  float s=0.f, ss=0.f;
#pragma unroll 8
  for (int b=0;b<64;b++){ s += dbins[b*256 + c]; ss += dbins[b*256 + 128 + c]; }
  float mean = s / (float)RTOTc;
  float var  = ss / (float)RTOTc - mean*mean;
  float rs = rsqrtf(var + 1e-5f);
  float k = rs * gam[c];
  dsc[c] = k; dsh[c] = bet[c] - mean*k;
}

// ---------------- model2 main: diff@W1 -> BN -> ReLU -> @W2 -> log_softmax ----------------
__global__ __launch_bounds__(256,2) void k_d_main(const float* __restrict__ x2bn, const float* __restrict__ w1,
                         const float* __restrict__ w2, const float* __restrict__ b2g,
                         const float* __restrict__ dsc, const float* __restrict__ dsh, float* __restrict__ out){
  __shared__ __align__(16) char sm[49152 + 4096 + 1024];
  unsigned char* A   = (unsigned char*)sm;
  unsigned char* W   = (unsigned char*)sm + 24576;
  unsigned char* W2T = (unsigned char*)sm + 49152;
  float* sS = (float*)(sm + 53248);
  int t = threadIdx.x;
  int gid = blockIdx.x; int g = gid / NPGc; int z = gid - g*NPGc;
  const float* xg = x2bn + (size_t)g*NPGc*Hc;
  const float* xz = xg + z*Hc;
  if (t < 128){ sS[t] = dsc[t]; sS[128+t] = dsh[t]; }
  {
    int c = t>>4, kc = t&15;
    ushort4 p0 = make_ushort4(0,0,0,0), p1 = make_ushort4(0,0,0,0);
    if (c < 2){
      p0.x = f2bf(w2[(kc*8+0)*2 + c]); p0.y = f2bf(w2[(kc*8+1)*2 + c]);
      p0.z = f2bf(w2[(kc*8+2)*2 + c]); p0.w = f2bf(w2[(kc*8+3)*2 + c]);
      p1.x = f2bf(w2[(kc*8+4)*2 + c]); p1.y = f2bf(w2[(kc*8+5)*2 + c]);
      p1.z = f2bf(w2[(kc*8+6)*2 + c]); p1.w = f2bf(w2[(kc*8+7)*2 + c]);
    }
    int byte = c*256 + ((kc*16) ^ ((c&7)<<4));
    *(ushort4*)(W2T + byte) = p0;
    *(ushort4*)(W2T + byte + 8) = p1;
  }
#pragma unroll
  for (int q=0;q<8;q++){
    int task = t + 256*q; int c = task & 127; int c4 = task >> 7;
    ushort4 p;
    p.x = f2bf(w1[(4*c4+0)*HMc + c]);
    p.y = f2bf(w1[(4*c4+1)*HMc + c]);
    p.z = f2bf(w1[(4*c4+2)*HMc + c]);
    p.w = f2bf(w1[(4*c4+3)*HMc + c]);
    *(ushort4*)(W + c*128 + ((c4*8) ^ ((c&7)<<4))) = p;
  }
#pragma unroll
  for (int q=0;q<12;q++){
    int task = t + 256*q; int i = task >> 4; int c = task & 15;
    float4 a = *(const float4*)(xg + i*Hc + c*4);
    float4 b = *(const float4*)(xz + c*4);
    ushort4 p;
    p.x = f2bf(fabsf(a.x-b.x)); p.y = f2bf(fabsf(a.y-b.y));
    p.z = f2bf(fabsf(a.z-b.z)); p.w = f2bf(fabsf(a.w-b.w));
    *(ushort4*)(A + i*128 + ((c*8) ^ ((i&7)<<4))) = p;
  }
  __syncthreads();
  int w = t>>6, l = t&63, lr = l&15, lg = l>>4;
  int sw = (lr&7)<<4;
  f32x4 zero = {0.f,0.f,0.f,0.f};
  f32x4 acc[3][8];
#pragma unroll
  for (int r=0;r<3;r++)
#pragma unroll
    for (int c=0;c<8;c++) acc[r][c] = zero;
#pragma unroll
  for (int kk=0;kk<2;kk++){
    bf16x8 af[3], bfr[8];
#pragma unroll
    for (int r=0;r<3;r++){
      int row = (w*3+r)*16 + lr;
      af[r] = *(const bf16x8*)(A + row*128 + ((lg*16 + 64*kk) ^ sw));
    }
#pragma unroll
    for (int c=0;c<8;c++){
      int col = c*16 + lr;
      bfr[c] = *(const bf16x8*)(W + col*128 + ((lg*16 + 64*kk) ^ sw));
    }
#pragma unroll
    for (int r=0;r<3;r++)
#pragma unroll
      for (int c=0;c<8;c++)
        acc[r][c] = __builtin_amdgcn_mfma_f32_16x16x32_bf16(af[r], bfr[c], acc[r][c], 0,0,0);
  }
  __syncthreads();
#pragma unroll
  for (int r=0;r<3;r++){
#pragma unroll
    for (int c=0;c<8;c++){
      int col = c*16 + lr;
      float scl = sS[col], shf = sS[128+col];
#pragma unroll
      for (int q=0;q<4;q++){
        int row = (w*3+r)*16 + lg*4 + q;
        float v = fmaxf(acc[r][c][q]*scl + shf, 0.f);
        *(unsigned short*)(A + row*256 + ((col*2) ^ ((row&7)<<4))) = f2bf(v);
      }
    }
  }
  __syncthreads();
  f32x4 acc2[3];
#pragma unroll
  for (int r=0;r<3;r++) acc2[r] = zero;
#pragma unroll
  for (int kk=0;kk<4;kk++){
    bf16x8 bw = *(const bf16x8*)(W2T + lr*256 + ((lg*16 + 64*kk) ^ sw));
#pragma unroll
    for (int r=0;r<3;r++){
      int row = (w*3+r)*16 + lr;
      bf16x8 ah = *(const bf16x8*)(A + row*256 + ((lg*16 + 64*kk) ^ sw));
      acc2[r] = __builtin_amdgcn_mfma_f32_16x16x32_bf16(ah, bw, acc2[r], 0,0,0);
    }
  }
  float b2a = b2g[0], b2b = b2g[1];
  size_t obase = (size_t)gid * NPGc;
#pragma unroll
  for (int r=0;r<3;r++){
#pragma unroll
    for (int q=0;q<4;q++){
      float o = acc2[r][q];
      float oo = __shfl_xor(o, 1, 64);
      if (lr < 2){
        int row = (w*3+r)*16 + lg*4 + q;
        float self = o + ((lr==0) ? b2a : b2b);
        float oth  = oo + ((lr==0) ? b2b : b2a);
        float mx = fmaxf(self, oth);
        float lse = mx + logf(expf(self-mx) + expf(oth-mx));
        out[(obase + row)*2 + lr] = self - lse;
      }
    }
  }
}

extern "C" void kernel_launch(void* const* d_in, const int* in_sizes, int n_in,
                              void* d_out, int out_size, void* d_ws, size_t ws_size,
                              hipStream_t stream){
  const float* x    = (const float*)d_in[0];
  const int*   ei   = (const int*)d_in[1];
  const float* ea   = (const float*)d_in[2];
  const float* efw1 = (const float*)d_in[4];
  const float* efb1 = (const float*)d_in[5];
  const float* efw2 = (const float*)d_in[6];
  const float* efb2 = (const float*)d_in[7];
  const float* efwr = (const float*)d_in[8];
  const float* bn1g = (const float*)d_in[9];
  const float* bn1b = (const float*)d_in[10];
  const float* ecw1 = (const float*)d_in[11];
  const float* ecb1 = (const float*)d_in[12];
  const float* ecw2 = (const float*)d_in[13];
  const float* ecb2 = (const float*)d_in[14];
  const float* bn2g = (const float*)d_in[15];
  const float* bn2b = (const float*)d_in[16];
  const float* m2w1 = (const float*)d_in[17];
  const float* m2bng = (const float*)d_in[19];
  const float* m2bnb = (const float*)d_in[20];
  const float* m2w2  = (const float*)d_in[21];
  const float* m2b2  = (const float*)d_in[22];

  char* ws = (char*)d_ws;
  float*    x1a   = (float*)(ws + 0);
  float*    x1bn  = (float*)(ws + 1572864);
  float*    x2bn  = (float*)(ws + 3145728);
  float*    x2f   = (float*)(ws + 4718592);
  float*    sqv   = (float*)(ws + 6291456);
  unsigned* nbr   = (unsigned*)(ws + 6316032);
  float*    stats = (float*)(ws + 6512640);
  float*    dbins = (float*)(ws + 6515712);
  u64*      parts = (u64*)(ws + 6581248);
  // edge2 precompute reuse: A2 over x1a (dead after bn1), Qm over x2bn slot
  float*    A2    = (float*)(ws + 0);
  float*    Qm    = (float*)(ws + 3145728);
  // edge1 precompute: P1/P2 live only until k_node1 -> reuse x2bn/x2f slots (written later)
  float*    P1    = (float*)(ws + 3145728);
  float*    P2    = (float*)(ws + 4718592);
  // CSR scratch + EAc overlay the parts region (dead before k_knn writes parts)
  unsigned* rcnt  = (unsigned*)(ws + 6581248);
  unsigned* rptr  = rcnt + 6400;
  unsigned* rcur  = rptr + 6400;
  unsigned* rlist = rcur + 6400;
  float*    EAc   = (float*)(ws + 6581248 + 4194304);
  float *g1sum = stats,     *g1ss = stats+64,  *sc1 = stats+128, *sh1 = stats+192;
  float *g2sum = stats+256, *g2ss = stats+320, *sc2 = stats+384, *sh2 = stats+448;
  float *dsc = stats+512, *dsh = stats+640;
  float* outp = (float*)d_out;

  int CH = 96;
  if (ws_size < 6581248ull + (size_t)NN*96*64) CH = 48;
  if (ws_size < 6581248ull + (size_t)NN*48*64) CH = 24;

  k_init<<<64,256,0,stream>>>(dbins, stats);
  k_root<<<1536,256,0,stream>>>(x, efwr, x1a);
  k_eac<<<3072,256,0,stream>>>(ea, efw1, EAc);
  k_zero_cnt<<<24,256,0,stream>>>(rcnt);
  k_cnt_dst<<<192,256,0,stream>>>(ei, rcnt);
  k_scan<<<1,256,0,stream>>>(rcnt, rptr, rcur);
  k_fill_dst<<<192,256,0,stream>>>(ei, rcur, rlist);
  k_p12<<<384,256,0,stream>>>(x, efw1, efb1, P1, P2);
  k_node1<<<384,128,0,stream>>>(P1, P2, EAc, ei, rptr, rlist, efw2, efb2, x1a);
  k_bn_stats<<<96,256,0,stream>>>(x1a, g1sum, g1ss);
  k_bn_fin<<<1,64,0,stream>>>(g1sum, g1ss, bn1g, bn1b, sc1, sh1);
  k_apply_bn1_sq<<<1536,256,0,stream>>>(x1a, sc1, sh1, x1bn, sqv);
  dim3 kg(24, CH);
  k_knn<<<kg,128,0,stream>>>(x1bn, sqv, parts, CH);
  k_knn_merge<<<24,256,0,stream>>>(parts, CH, nbr);
  k_zero_cnt<<<24,256,0,stream>>>(rcnt);
  k_rev_cnt<<<192,256,0,stream>>>(nbr, rcnt);
  k_scan<<<1,256,0,stream>>>(rcnt, rptr, rcur);
  k_rev_fill<<<192,256,0,stream>>>(nbr, rcur, rlist);
  k_pq<<<384,256,0,stream>>>(x1bn, ecw1, ecb1, A2, Qm);
  k_edge2max<<<384,128,0,stream>>>(A2, Qm, nbr, rptr, rlist, ecw2, ecb2, x2f);
  k_bn_stats<<<96,256,0,stream>>>(x2f, g2sum, g2ss);
  k_bn_fin<<<1,64,0,stream>>>(g2sum, g2ss, bn2g, bn2b, sc2, sh2);
  k_apply_bn2f<<<1536,256,0,stream>>>(x2f, sc2, sh2, x2bn);
  k_d_stats<<<6144,256,0,stream>>>(x2bn, m2w1, dbins);
  k_d_fin<<<1,128,0,stream>>>(dbins, m2bng, m2bnb, dsc, dsh);
  k_d_main<<<6144,256,0,stream>>>(x2bn, m2w1, m2w2, m2b2, dsc, dsh, outp);
}

// Round 12
// 511.505 us; speedup vs baseline: 1.2953x; 1.0948x over previous
//
#include <hip/hip_runtime.h>

#define NN 6144
#define GG 32
#define NPGc 192
#define FINc 32
#define FEc 8
#define Hc 64
#define HMc 128
#define Kc 8
#define Ec 49152
#define NKc (NN*Kc)
#define RTOTc (GG*NPGc*NPGc)

typedef float f32x4 __attribute__((ext_vector_type(4)));
typedef short bf16x8 __attribute__((ext_vector_type(8)));
typedef unsigned long long u64;

__device__ __forceinline__ unsigned short f2bf(float f){
  unsigned u = __float_as_uint(f);
  unsigned r = u + 0x7fffu + ((u>>16)&1u);
  return (unsigned short)(r>>16);
}
__device__ __forceinline__ unsigned fenc(float f){
  unsigned u = __float_as_uint(f);
  return (u & 0x80000000u) ? ~u : (u | 0x80000000u);
}
__device__ __forceinline__ float fdec(unsigned e){
  unsigned u = (e & 0x80000000u) ? (e & 0x7fffffffu) : ~e;
  return __uint_as_float(u);
}
__device__ __forceinline__ void bub8(u64* t8, u64 k){
#pragma unroll
  for (int q=0;q<8;q++){ u64 cur=t8[q]; u64 lo=(k<cur)?k:cur; u64 hi=(k<cur)?cur:k; t8[q]=lo; k=hi; }
}

// ---------------- init: zero accumulators ----------------
__global__ void k_init(float* dbins, float* stats){
  int idx = blockIdx.x*256 + threadIdx.x;
  if (idx < 64*256) dbins[idx] = 0.f;
  if (idx < 768) stats[idx] = 0.f;
}

// ---------------- precompute bf16-swizzled W1 (16KB) and W2T (4KB) for d_stats/d_main ----------------
__global__ void k_prep_w(const float* __restrict__ w1, const float* __restrict__ w2,
                         unsigned short* __restrict__ Wpre, unsigned short* __restrict__ W2Tp){
  int idx = blockIdx.x*256 + threadIdx.x;   // 9 blocks = 2304 threads
  if (idx < 2048){
    int c = idx >> 4, c4 = idx & 15;
    ushort4 p;
    p.x = f2bf(w1[(4*c4+0)*HMc + c]);
    p.y = f2bf(w1[(4*c4+1)*HMc + c]);
    p.z = f2bf(w1[(4*c4+2)*HMc + c]);
    p.w = f2bf(w1[(4*c4+3)*HMc + c]);
    *(ushort4*)((char*)Wpre + c*128 + ((c4*8) ^ ((c&7)<<4))) = p;
  } else if (idx < 2304){
    int t2 = idx - 2048;
    int c = t2>>4, kc = t2&15;
    ushort4 p0 = make_ushort4(0,0,0,0), p1 = make_ushort4(0,0,0,0);
    if (c < 2){
      p0.x = f2bf(w2[(kc*8+0)*2 + c]); p0.y = f2bf(w2[(kc*8+1)*2 + c]);
      p0.z = f2bf(w2[(kc*8+2)*2 + c]); p0.w = f2bf(w2[(kc*8+3)*2 + c]);
      p1.x = f2bf(w2[(kc*8+4)*2 + c]); p1.y = f2bf(w2[(kc*8+5)*2 + c]);
      p1.z = f2bf(w2[(kc*8+6)*2 + c]); p1.w = f2bf(w2[(kc*8+7)*2 + c]);
    }
    int byte = c*256 + ((kc*16) ^ ((c&7)<<4));
    *(ushort4*)((char*)W2Tp + byte) = p0;
    *(ushort4*)((char*)W2Tp + byte + 8) = p1;
  }
}

// ---------------- x1a = x @ ef_wroot ----------------
__global__ __launch_bounds__(256) void k_root(const float* __restrict__ x, const float* __restrict__ wr, float* __restrict__ x1a){
  __shared__ float Ws[FINc*Hc];
  __shared__ float xr[4][FINc];
  int t = threadIdx.x;
  for (int q=t;q<FINc*Hc;q+=256) Ws[q] = wr[q];
  int rg = t>>6, j = t&63;
  int r = blockIdx.x*4 + rg;
  if (j < FINc) xr[rg][j] = x[r*FINc + j];
  __syncthreads();
  float a0=0.f, a1=0.f;
#pragma unroll
  for (int k=0;k<FINc;k+=2){
    a0 = fmaf(xr[rg][k],   Ws[k*Hc+j],     a0);
    a1 = fmaf(xr[rg][k+1], Ws[(k+1)*Hc+j], a1);
  }
  x1a[r*Hc + j] = a0 + a1;
}

// ---------------- edge1 precompute: EAc[e] = ea[e] @ W1c (rows 64..71) ----------------
__global__ __launch_bounds__(256) void k_eac(const float* __restrict__ ea, const float* __restrict__ w1, float* __restrict__ EAc){
  __shared__ float Wc[FEc*Hc];
  int t = threadIdx.x;
  for (int q=t; q<FEc*Hc; q+=256) Wc[q] = w1[64*Hc + q];
  __syncthreads();
  int idx = blockIdx.x*256 + t;
  int e = idx >> 4, c4 = (idx & 15)*4;
  float av[8];
#pragma unroll
  for (int q=0;q<8;q++) av[q] = ea[e*FEc + q];
  float4 o = {0.f,0.f,0.f,0.f};
#pragma unroll
  for (int q=0;q<8;q++){
    o.x = fmaf(av[q], Wc[q*Hc + c4+0], o.x);
    o.y = fmaf(av[q], Wc[q*Hc + c4+1], o.y);
    o.z = fmaf(av[q], Wc[q*Hc + c4+2], o.z);
    o.w = fmaf(av[q], Wc[q*Hc + c4+3], o.w);
  }
  *(float4*)(EAc + (size_t)e*Hc + c4) = o;
}

// ---------------- edge1 precompute: P1 = x@W1a + b1 (dst part), P2 = x@W1b (src part) ----------------
__global__ __launch_bounds__(256) void k_p12(const float* __restrict__ x, const float* __restrict__ w1, const float* __restrict__ b1,
                                             float* __restrict__ P1, float* __restrict__ P2){
  __shared__ float xs[16][32];
  int t = threadIdx.x;
  int j = t & 63, w = t >> 6;
  float wa[32], wb[32];
#pragma unroll
  for (int k=0;k<32;k++){
    wa[k] = w1[k*Hc + j];
    wb[k] = w1[(32+k)*Hc + j];
  }
  float b1j = b1[j];
  int nb = blockIdx.x * 16;
  for (int q=t; q<16*32; q+=256) xs[q>>5][q&31] = x[(size_t)(nb + (q>>5))*FINc + (q&31)];
  __syncthreads();
#pragma unroll
  for (int it=0; it<4; it++){
    int nl = it*4 + w;
    float a = b1j, b = 0.f;
#pragma unroll
    for (int k=0;k<32;k++){
      float xv = xs[nl][k];
      a = fmaf(xv, wa[k], a);
      b = fmaf(xv, wb[k], b);
    }
    int n = nb + nl;
    P1[(size_t)n*Hc + j] = a;
    P2[(size_t)n*Hc + j] = b;
  }
}

// ---------------- generic CSR build pieces ----------------
__global__ void k_zero_cnt(unsigned* rcnt){
  int idx = blockIdx.x*256 + threadIdx.x;
  if (idx < NN) rcnt[idx] = 0u;
}
__global__ void k_cnt_dst(const int* __restrict__ ei, unsigned* __restrict__ rcnt){
  int e = blockIdx.x*256 + threadIdx.x;
  atomicAdd(&rcnt[ei[Ec + e]], 1u);
}
__global__ __launch_bounds__(256) void k_scan(const unsigned* __restrict__ rcnt, unsigned* __restrict__ rptr, unsigned* __restrict__ rcur){
  __shared__ unsigned ps[256];
  int t = threadIdx.x;
  unsigned loc[24];
  unsigned s = 0;
#pragma unroll
  for (int q=0;q<24;q++){ loc[q] = s; s += rcnt[t*24+q]; }
  ps[t] = s;
  __syncthreads();
  for (int off=1; off<256; off<<=1){
    unsigned v = (t>=off)? ps[t-off] : 0u;
    __syncthreads();
    ps[t] += v;
    __syncthreads();
  }
  unsigned base = (t==0)? 0u : ps[t-1];
#pragma unroll
  for (int q=0;q<24;q++){ unsigned v = base + loc[q]; rptr[t*24+q]=v; rcur[t*24+q]=v; }
  if (t==255) rptr[NN] = ps[255];
}
__global__ void k_fill_dst(const int* __restrict__ ei, unsigned* __restrict__ rcur, unsigned* __restrict__ rlist){
  int e = blockIdx.x*256 + threadIdx.x;
  unsigned pos = atomicAdd(&rcur[ei[Ec + e]], 1u);
  rlist[pos] = (unsigned)e;
}
__global__ void k_rev_cnt(const unsigned* __restrict__ nbr, unsigned* __restrict__ rcnt){
  int e = blockIdx.x*256 + threadIdx.x;
  atomicAdd(&rcnt[nbr[e]], 1u);
}
__global__ void k_rev_fill(const unsigned* __restrict__ nbr, unsigned* __restrict__ rcur, unsigned* __restrict__ rlist){
  int e = blockIdx.x*256 + threadIdx.x;
  unsigned pos = atomicAdd(&rcur[nbr[e]], 1u);
  rlist[pos] = (unsigned)(e >> 3);
}

// ---------------- edge1 aggregate: x1a[n] += (Σ_in relu(P1[n]+P2[s]+EAc[e])) @ W2 + deg·b2 ----------------
__global__ __launch_bounds__(128) void k_node1(const float* __restrict__ P1, const float* __restrict__ P2, const float* __restrict__ EAc,
        const int* __restrict__ ei, const unsigned* __restrict__ rptr, const unsigned* __restrict__ rlist,
        const float* __restrict__ w2, const float* __restrict__ b2, float* __restrict__ x1a){
  __shared__ __align__(16) float accs[16][68];
  __shared__ __align__(16) float W2T[64][68];
  __shared__ unsigned rp_s[17];
  int t = threadIdx.x;
  int d0 = blockIdx.x * 16;
  for (int q=t; q<64*64; q+=128) W2T[q&63][q>>6] = w2[q];
  if (t < 17) rp_s[t] = rptr[d0 + t];
  __syncthreads();
  int slot = t>>3, cg = t&7, c0 = cg*8;
  int n = d0 + slot;
  float4 p1a = *(const float4*)(P1 + (size_t)n*Hc + c0);
  float4 p1b = *(const float4*)(P1 + (size_t)n*Hc + c0 + 4);
  float acc[8];
#pragma unroll
  for (int q=0;q<8;q++) acc[q] = 0.f;
  unsigned beg = rp_s[slot], end = rp_s[slot+1];
  for (unsigned pos=beg; pos<end; pos++){
    unsigned e = rlist[pos];
    int s = ei[e];
    float4 qa = *(const float4*)(P2 + (size_t)s*Hc + c0);
    float4 qb = *(const float4*)(P2 + (size_t)s*Hc + c0 + 4);
    float4 fa = *(const float4*)(EAc + (size_t)e*Hc + c0);
    float4 fb = *(const float4*)(EAc + (size_t)e*Hc + c0 + 4);
    acc[0] += fmaxf(p1a.x + qa.x + fa.x, 0.f);
    acc[1] += fmaxf(p1a.y + qa.y + fa.y, 0.f);
    acc[2] += fmaxf(p1a.z + qa.z + fa.z, 0.f);
    acc[3] += fmaxf(p1a.w + qa.w + fa.w, 0.f);
    acc[4] += fmaxf(p1b.x + qb.x + fb.x, 0.f);
    acc[5] += fmaxf(p1b.y + qb.y + fb.y, 0.f);
    acc[6] += fmaxf(p1b.z + qb.z + fb.z, 0.f);
    acc[7] += fmaxf(p1b.w + qb.w + fb.w, 0.f);
  }
  *(float4*)&accs[slot][c0]   = make_float4(acc[0],acc[1],acc[2],acc[3]);
  *(float4*)&accs[slot][c0+4] = make_float4(acc[4],acc[5],acc[6],acc[7]);
  __syncthreads();
  float out[8];
#pragma unroll
  for (int q=0;q<8;q++) out[q] = 0.f;
  for (int k4=0;k4<16;k4++){
    float4 hv = *(const float4*)&accs[slot][k4*4];
#pragma unroll
    for (int cc=0;cc<8;cc++){
      float4 wv = *(const float4*)&W2T[c0+cc][k4*4];
      out[cc] = fmaf(hv.x,wv.x, fmaf(hv.y,wv.y, fmaf(hv.z,wv.z, fmaf(hv.w,wv.w, out[cc]))));
    }
  }
  float deg = (float)(end - beg);
  float* px = x1a + (size_t)n*Hc + c0;
#pragma unroll
  for (int cc=0;cc<8;cc++) px[cc] += out[cc] + deg*b2[c0+cc];
}

// ---------------- BN stats over N rows x 64 cols ----------------
__global__ __launch_bounds__(256) void k_bn_stats(const float* __restrict__ src, float* __restrict__ gsum, float* __restrict__ gss){
  int t = threadIdx.x;
  int c = t & 63;
  int r0 = blockIdx.x*64 + (t>>6);
  float s=0.f, ss=0.f;
  for (int it=0; it<16; it++){
    int r = r0 + it*4;
    float v = src[r*Hc + c];
    s += v; ss += v*v;
  }
  __shared__ float S[64], SS[64];
  if (t < 64){ S[t]=0.f; SS[t]=0.f; }
  __syncthreads();
  atomicAdd(&S[c], s); atomicAdd(&SS[c], ss);
  __syncthreads();
  if (t < 64){ atomicAdd(&gsum[t], S[t]); atomicAdd(&gss[t], SS[t]); }
}

// ---------------- apply BN1 (fused finalize) + per-row squared norm ----------------
__global__ __launch_bounds__(256) void k_apply_bn1_sq(const float* __restrict__ x1a,
                               const float* __restrict__ gsum, const float* __restrict__ gss,
                               const float* __restrict__ gam, const float* __restrict__ bet,
                               float* __restrict__ x1bn, float* __restrict__ sqv){
  __shared__ float scs[64], shs[64];
  int t = threadIdx.x;
  if (t < 64){
    float mean = gsum[t] / (float)NN;
    float var  = gss[t] / (float)NN - mean*mean;
    float rs = rsqrtf(var + 1e-5f);
    float s = rs * gam[t];
    scs[t] = s; shs[t] = bet[t] - mean*s;
  }
  __syncthreads();
  int c = t & 63;
  int r = blockIdx.x*4 + (t>>6);
  float v = x1a[r*Hc + c]*scs[c] + shs[c];
  x1bn[r*Hc + c] = v;
  float s = v*v;
#pragma unroll
  for (int off=1; off<64; off<<=1) s += __shfl_xor(s, off, 64);
  if (c == 0) sqv[r] = s;
}

// ---------------- KNN: LDS-broadcast distances + online top-8 (round-6 proven body) ----------------
__global__ __launch_bounds__(128,2) void k_knn(const float* __restrict__ x1bn, const float* __restrict__ sqv, u64* __restrict__ parts, int CH){
  __shared__ __align__(16) float XJ[64][68];
  __shared__ float sqj[64];
  int t = threadIdx.x;
  int i1 = blockIdx.x*256 + t;
  int i2 = i1 + 128;
  float4 xa[16], xb[16];
#pragma unroll
  for (int q=0;q<16;q++){
    xa[q] = *(const float4*)(x1bn + (size_t)i1*Hc + q*4);
    xb[q] = *(const float4*)(x1bn + (size_t)i2*Hc + q*4);
  }
  float sqi1 = sqv[i1], sqi2 = sqv[i2];
  u64 t8a[8], t8b[8];
#pragma unroll
  for (int q=0;q<8;q++){ t8a[q] = ~0ull; t8b[q] = ~0ull; }
  float thra = __uint_as_float(0x7f800000u);
  float thrb = thra;
  int cpc = NN / CH;
  int nsub = cpc >> 6;
  int jbase0 = blockIdx.y * cpc;
  for (int sub=0; sub<nsub; sub++){
    int jb = jbase0 + sub*64;
    __syncthreads();
    {
      int c = t>>1, hh = t&1;
      const float4* srcp = (const float4*)(x1bn + (size_t)(jb + c)*Hc + hh*32);
#pragma unroll
      for (int q=0;q<8;q++) *(float4*)&XJ[c][hh*32 + q*4] = srcp[q];
      if (t < 64) sqj[t] = sqv[jb + t];
    }
    __syncthreads();
    for (int j=0;j<64;j++){
      float sqjc = sqj[j];
      float a0=0.f,a1=0.f,a2=0.f,a3=0.f,b0=0.f,b1=0.f,b2=0.f,b3=0.f;
#pragma unroll
      for (int q4=0;q4<4;q4++){
        float4 xj0 = *(const float4*)&XJ[j][q4*16];
        float4 xj1 = *(const float4*)&XJ[j][q4*16+4];
        float4 xj2 = *(const float4*)&XJ[j][q4*16+8];
        float4 xj3 = *(const float4*)&XJ[j][q4*16+12];
        float4 A0 = xa[q4*4+0], A1 = xa[q4*4+1], A2v = xa[q4*4+2], A3 = xa[q4*4+3];
        float4 B0 = xb[q4*4+0], B1 = xb[q4*4+1], B2v = xb[q4*4+2], B3 = xb[q4*4+3];
        a0=fmaf(A0.x,xj0.x,a0); a1=fmaf(A0.y,xj0.y,a1); a2=fmaf(A0.z,xj0.z,a2); a3=fmaf(A0.w,xj0.w,a3);
        b0=fmaf(B0.x,xj0.x,b0); b1=fmaf(B0.y,xj0.y,b1); b2=fmaf(B0.z,xj0.z,b2); b3=fmaf(B0.w,xj0.w,b3);
        a0=fmaf(A1.x,xj1.x,a0); a1=fmaf(A1.y,xj1.y,a1); a2=fmaf(A1.z,xj1.z,a2); a3=fmaf(A1.w,xj1.w,a3);
        b0=fmaf(B1.x,xj1.x,b0); b1=fmaf(B1.y,xj1.y,b1); b2=fmaf(B1.z,xj1.z,b2); b3=fmaf(B1.w,xj1.w,b3);
        a0=fmaf(A2v.x,xj2.x,a0); a1=fmaf(A2v.y,xj2.y,a1); a2=fmaf(A2v.z,xj2.z,a2); a3=fmaf(A2v.w,xj2.w,a3);
        b0=fmaf(B2v.x,xj2.x,b0); b1=fmaf(B2v.y,xj2.y,b1); b2=fmaf(B2v.z,xj2.z,b2); b3=fmaf(B2v.w,xj2.w,b3);
        a0=fmaf(A3.x,xj3.x,a0); a1=fmaf(A3.y,xj3.y,a1); a2=fmaf(A3.z,xj3.z,a2); a3=fmaf(A3.w,xj3.w,a3);
        b0=fmaf(B3.x,xj3.x,b0); b1=fmaf(B3.y,xj3.y,b1); b2=fmaf(B3.z,xj3.z,b2); b3=fmaf(B3.w,xj3.w,b3);
      }
      float dot1 = (a0+a1)+(a2+a3);
      float dot2 = (b0+b1)+(b2+b3);
      int jj = jb + j;
      float d2a = (sqi1 + sqjc) - 2.f*dot1;
      float d2b = (sqi2 + sqjc) - 2.f*dot2;
      bool ia = !(d2a > thra) && (jj != i1);
      bool ib = !(d2b > thrb) && (jj != i2);
      if (__builtin_expect(ia | ib, 0)){
        if (ia){
          u64 ka = (((u64)fenc(d2a))<<32) | (unsigned)jj;
          bub8(t8a, ka);
          thra = fdec((unsigned)(t8a[7]>>32));
        }
        if (ib){
          u64 kb = (((u64)fenc(d2b))<<32) | (unsigned)jj;
          bub8(t8b, kb);
          thrb = fdec((unsigned)(t8b[7]>>32));
        }
      }
    }
  }
  u64* pa = parts + ((size_t)blockIdx.y*NN + i1)*8;
  u64* pb = parts + ((size_t)blockIdx.y*NN + i2)*8;
#pragma unroll
  for (int q=0;q<8;q++){ pa[q] = t8a[q]; pb[q] = t8b[q]; }
}

// ---------------- two-stage parallel merge (top-8 of a set is partition-independent) ----------------
__global__ __launch_bounds__(256) void k_knn_merge1(const u64* __restrict__ parts, int CPG, u64* __restrict__ parts2){
  int g = blockIdx.x / 24;
  int r = (blockIdx.x % 24)*256 + threadIdx.x;
  u64 t8[8];
#pragma unroll
  for (int q=0;q<8;q++) t8[q] = ~0ull;
  for (int ch=g*CPG; ch<(g+1)*CPG; ch++){
    const u64* p = parts + ((size_t)ch*NN + r)*8;
    u64 k[8];
#pragma unroll
    for (int q=0;q<8;q++) k[q] = p[q];
#pragma unroll
    for (int q=0;q<8;q++){
      if (k[q] >= t8[7]) break;
      bub8(t8, k[q]);
    }
  }
  u64* o = parts2 + ((size_t)g*NN + r)*8;
#pragma unroll
  for (int q=0;q<8;q++) o[q] = t8[q];
}

__global__ __launch_bounds__(256) void k_knn_merge2(const u64* __restrict__ parts2, unsigned* __restrict__ nbr){
  int r = blockIdx.x*256 + threadIdx.x;
  u64 t8[8];
#pragma unroll
  for (int q=0;q<8;q++) t8[q] = ~0ull;
  for (int g=0; g<8; g++){
    const u64* p = parts2 + ((size_t)g*NN + r)*8;
    u64 k[8];
#pragma unroll
    for (int q=0;q<8;q++) k[q] = p[q];
#pragma unroll
    for (int q=0;q<8;q++){
      if (k[q] >= t8[7]) break;
      bub8(t8, k[q]);
    }
  }
#pragma unroll
  for (int s=0;s<8;s++) nbr[r*Kc + s] = (unsigned)(t8[s] & 0xffffffffu);
}

// ---------------- edge2 precompute: A2 = x1bn@(W1t-W1b)+b1 ; Q = x1bn@W1b ----------------
__global__ __launch_bounds__(256) void k_pq(const float* __restrict__ x1bn, const float* __restrict__ w1, const float* __restrict__ b1,
                                            float* __restrict__ A2, float* __restrict__ Qm){
  __shared__ float xs[16][64];
  int t = threadIdx.x;
  int j = t & 63, w = t >> 6;
  float wa[64], wb[64];
#pragma unroll
  for (int k=0;k<64;k++){
    float wt  = w1[k*64 + j];
    float wbv = w1[(64+k)*64 + j];
    wa[k] = wt - wbv; wb[k] = wbv;
  }
  float b1j = b1[j];
  int nb = blockIdx.x * 16;
  for (int q=t; q<16*64; q+=256) xs[q>>6][q&63] = x1bn[(size_t)(nb + (q>>6))*64 + (q&63)];
  __syncthreads();
#pragma unroll
  for (int it=0; it<4; it++){
    int nl = it*4 + w;
    float a = b1j, qq = 0.f;
#pragma unroll
    for (int k=0;k<64;k++){
      float xv = xs[nl][k];
      a  = fmaf(xv, wa[k], a);
      qq = fmaf(xv, wb[k], qq);
    }
    int n = nb + nl;
    A2[(size_t)n*64 + j] = a;
    Qm[(size_t)n*64 + j] = qq;
  }
}

// ---------------- edge2: per-destination-block GEMM + LDS max, no global atomics ----------------
__global__ __launch_bounds__(128) void k_edge2max(const float* __restrict__ A2, const float* __restrict__ Qm,
        const unsigned* __restrict__ nbr, const unsigned* __restrict__ rptr, const unsigned* __restrict__ rlist,
        const float* __restrict__ w2, const float* __restrict__ b2, float* __restrict__ x2f){
  __shared__ __align__(16) float W2T[64][68];
  __shared__ __align__(16) float hidT[64][132];
  __shared__ unsigned x2s[17][64];
  __shared__ unsigned rp_s[17];
  __shared__ int wslot[128];
  int t = threadIdx.x;
  int d0 = blockIdx.x * 16;
  for (int q=t; q<64*64; q+=128) W2T[q&63][q>>6] = w2[q];
  for (int q=t; q<17*64; q+=128) ((unsigned*)x2s)[q] = 0x007FFFFFu;
  if (t < 17) rp_s[t] = rptr[d0 + t];
  __syncthreads();
  unsigned rp0 = rp_s[0];
  int total_rev = (int)(rp_s[16] - rp0);
  int eg = t & 15, cg = t >> 4;
  int r0 = eg*8, c0 = cg*8;
  float b2v[8];
#pragma unroll
  for (int cc=0;cc<8;cc++) b2v[cc] = b2[c0+cc];
  int ntile = 1 + ((total_rev + 127) >> 7);
  for (int tile=0; tile<ntile; tile++){
    int d, s, active;
    if (tile == 0){
      d = d0 + (t>>3); s = (int)nbr[(size_t)d*8 + (t&7)]; active = 1; wslot[t] = t>>3;
    } else {
      int idx = (tile-1)*128 + t;
      active = idx < total_rev;
      if (active){
        unsigned pos = rp0 + (unsigned)idx;
        int sl = 0;
#pragma unroll
        for (int m=1; m<16; m++) sl += (pos >= rp_s[m]) ? 1 : 0;
        s = (int)rlist[pos];
        d = d0 + sl;
        wslot[t] = sl;
      } else { d = d0; s = 0; wslot[t] = 16; }
    }
    if (active){
      const float* pa = A2 + (size_t)d*64;
      const float* pq = Qm + (size_t)s*64;
#pragma unroll
      for (int c4=0; c4<16; c4++){
        float4 va = *(const float4*)(pa + c4*4);
        float4 vq = *(const float4*)(pq + c4*4);
        hidT[c4*4+0][t] = fmaxf(va.x+vq.x, 0.f);
        hidT[c4*4+1][t] = fmaxf(va.y+vq.y, 0.f);
        hidT[c4*4+2][t] = fmaxf(va.z+vq.z, 0.f);
        hidT[c4*4+3][t] = fmaxf(va.w+vq.w, 0.f);
      }
    } else {
#pragma unroll
      for (int c4=0; c4<16; c4++){
        hidT[c4*4+0][t] = 0.f; hidT[c4*4+1][t] = 0.f;
        hidT[c4*4+2][t] = 0.f; hidT[c4*4+3][t] = 0.f;
      }
    }
    __syncthreads();
    float acc[8][8];
#pragma unroll
    for (int i=0;i<8;i++)
#pragma unroll
      for (int cc=0;cc<8;cc++) acc[i][cc] = 0.f;
    for (int k=0;k<64;k+=4){
      float4 wv[8];
#pragma unroll
      for (int cc=0;cc<8;cc++) wv[cc] = *(const float4*)&W2T[c0+cc][k];
#pragma unroll
      for (int kk=0;kk<4;kk++){
        float4 h0 = *(const float4*)&hidT[k+kk][r0];
        float4 h1 = *(const float4*)&hidT[k+kk][r0+4];
        float hh[8] = {h0.x,h0.y,h0.z,h0.w,h1.x,h1.y,h1.z,h1.w};
#pragma unroll
        for (int i=0;i<8;i++)
#pragma unroll
          for (int cc=0;cc<8;cc++)
            acc[i][cc] = fmaf(hh[i], ((const float*)&wv[cc])[kk], acc[i][cc]);
      }
    }
    int cur = wslot[r0];
    float mx[8];
#pragma unroll
    for (int cc=0;cc<8;cc++) mx[cc] = acc[0][cc];
    for (int i=1;i<8;i++){
      int sl = wslot[r0+i];
      if (sl != cur){
#pragma unroll
        for (int cc=0;cc<8;cc++) atomicMax(&x2s[cur][c0+cc], fenc(mx[cc] + b2v[cc]));
        cur = sl;
#pragma unroll
        for (int cc=0;cc<8;cc++) mx[cc] = acc[i][cc];
      } else {
#pragma unroll
        for (int cc=0;cc<8;cc++) mx[cc] = fmaxf(mx[cc], acc[i][cc]);
      }
    }
#pragma unroll
    for (int cc=0;cc<8;cc++) atomicMax(&x2s[cur][c0+cc], fenc(mx[cc] + b2v[cc]));
    __syncthreads();
  }
#pragma unroll
  for (int q=0;q<8;q++){
    int idx = t + q*128;
    int sl = idx >> 6, c = idx & 63;
    x2f[(size_t)(d0+sl)*64 + c] = fdec(x2s[sl][c]);
  }
}

// ---------------- apply BN2 (fused finalize) ----------------
__global__ __launch_bounds__(256) void k_apply_bn2f(const float* __restrict__ x2f,
                               const float* __restrict__ gsum, const float* __restrict__ gss,
                               const float* __restrict__ gam, const float* __restrict__ bet,
                               float* __restrict__ x2bn){
  __shared__ float scs[64], shs[64];
  int t = threadIdx.x;
  if (t < 64){
    float mean = gsum[t] / (float)NN;
    float var  = gss[t] / (float)NN - mean*mean;
    float rs = rsqrtf(var + 1e-5f);
    float s = rs * gam[t];
    scs[t] = s; shs[t] = bet[t] - mean*s;
  }
  __syncthreads();
  int idx = blockIdx.x*256 + t;
  int c = idx & 63;
  x2bn[idx] = x2f[idx]*scs[c] + shs[c];
}

// ---------------- model2 pass 1: column sum/sumsq of diff@W1 via MFMA (pre-swizzled W) ----------------
__global__ __launch_bounds__(256,2) void k_d_stats(const float* __restrict__ x2bn, const unsigned short* __restrict__ Wpre, float* __restrict__ dbins){
  __shared__ __align__(16) char sm[24576 + 16384 + 1024];
  unsigned char* A = (unsigned char*)sm;
  unsigned char* W = (unsigned char*)sm + 24576;
  float* Ssum = (float*)(sm + 40960);
  int t = threadIdx.x;
  int gid = blockIdx.x; int g = gid / NPGc; int z = gid - g*NPGc;
  const float* xg = x2bn + (size_t)g*NPGc*Hc;
  const float* xz = xg + z*Hc;
  Ssum[t] = 0.f;
#pragma unroll
  for (int q=0;q<4;q++)
    *(float4*)(W + t*16 + q*4096) = *(const float4*)((const char*)Wpre + t*16 + q*4096);
#pragma unroll
  for (int q=0;q<12;q++){
    int task = t + 256*q; int i = task >> 4; int c = task & 15;
    float4 a = *(const float4*)(xg + i*Hc + c*4);
    float4 b = *(const float4*)(xz + c*4);
    ushort4 p;
    p.x = f2bf(fabsf(a.x-b.x)); p.y = f2bf(fabsf(a.y-b.y));
    p.z = f2bf(fabsf(a.z-b.z)); p.w = f2bf(fabsf(a.w-b.w));
    *(ushort4*)(A + i*128 + ((c*8) ^ ((i&7)<<4))) = p;
  }
  __syncthreads();
  int w = t>>6, l = t&63, lr = l&15, lg = l>>4;
  int sw = (lr&7)<<4;
  f32x4 zero = {0.f,0.f,0.f,0.f};
  f32x4 acc[3][8];
#pragma unroll
  for (int r=0;r<3;r++)
#pragma unroll
    for (int c=0;c<8;c++) acc[r][c] = zero;
#pragma unroll
  for (int kk=0;kk<2;kk++){
    bf16x8 af[3], bfr[8];
#pragma unroll
    for (int r=0;r<3;r++){
      int row = (w*3+r)*16 + lr;
      af[r] = *(const bf16x8*)(A + row*128 + ((lg*16 + 64*kk) ^ sw));
    }
#pragma unroll
    for (int c=0;c<8;c++){
      int col = c*16 + lr;
      bfr[c] = *(const bf16x8*)(W + col*128 + ((lg*16 + 64*kk) ^ sw));
    }
#pragma unroll
    for (int r=0;r<3;r++)
#pragma unroll
      for (int c=0;c<8;c++)
        acc[r][c] = __builtin_amdgcn_mfma_f32_16x16x32_bf16(af[r], bfr[c], acc[r][c], 0,0,0);
  }
#pragma unroll
  for (int c=0;c<8;c++){
    int col = c*16 + lr;
    float s=0.f, ss=0.f;
#pragma unroll
    for (int r=0;r<3;r++)
#pragma unroll
      for (int q=0;q<4;q++){ float v = acc[r][c][q]; s += v; ss = fmaf(v,v,ss); }
    s  += __shfl_xor(s, 16, 64);  ss += __shfl_xor(ss, 16, 64);
    s  += __shfl_xor(s, 32, 64);  ss += __shfl_xor(ss, 32, 64);
    if (lg == 0){
      atomicAdd(&Ssum[col], s);
      atomicAdd(&Ssum[128+col], ss);
    }
  }
  __syncthreads();
  if (t < 128){
    int bin = gid & 63;
    atomicAdd(&dbins[bin*256 + t], Ssum[t]);
    atomicAdd(&dbins[bin*256 + 128 + t], Ssum[128+t]);
  }
}

__global__ void k_d_fin(const float* __restrict__ dbins, const float* gam, const float* bet, float* dsc, float* dsh){
  int c = threadIdx.x; // 128
  float s=0.f, ss=0.f;
#pragma unroll 8
  for (int b=0;b<64;b++){ s += dbins[b*256 + c]; ss += dbins[b*256 + 128 + c]; }
  float mean = s / (float)RTOTc;
  float var  = ss / (float)RTOTc - mean*mean;
  float rs = rsqrtf(var + 1e-5f);
  float k = rs * gam[c];
  dsc[c] = k; dsh[c] = bet[c] - mean*k;
}

// ---------------- model2 main: diff@W1 -> BN -> ReLU -> @W2 -> log_softmax (pre-swizzled W) ----------------
__global__ __launch_bounds__(256,2) void k_d_main(const float* __restrict__ x2bn, const unsigned short* __restrict__ Wpre,
                         const unsigned short* __restrict__ W2Tp, const float* __restrict__ b2g,
                         const float* __restrict__ dsc, const float* __restrict__ dsh, float* __restrict__ out){
  __shared__ __align__(16) char sm[49152 + 4096 + 1024];
  unsigned char* A   = (unsigned char*)sm;
  unsigned char* W   = (unsigned char*)sm + 24576;
  unsigned char* W2T = (unsigned char*)sm + 49152;
  float* sS = (float*)(sm + 53248);
  int t = threadIdx.x;
  int gid = blockIdx.x; int g = gid / NPGc; int z = gid - g*NPGc;
  const float* xg = x2bn + (size_t)g*NPGc*Hc;
  const float* xz = xg + z*Hc;
  if (t < 128){ sS[t] = dsc[t]; sS[128+t] = dsh[t]; }
  *(float4*)(W2T + t*16) = *(const float4*)((const char*)W2Tp + t*16);
#pragma unroll
  for (int q=0;q<4;q++)
    *(float4*)(W + t*16 + q*4096) = *(const float4*)((const char*)Wpre + t*16 + q*4096);
#pragma unroll
  for (int q=0;q<12;q++){
    int task = t + 256*q; int i = task >> 4; int c = task & 15;
    float4 a = *(const float4*)(xg + i*Hc + c*4);
    float4 b = *(const float4*)(xz + c*4);
    ushort4 p;
    p.x = f2bf(fabsf(a.x-b.x)); p.y = f2bf(fabsf(a.y-b.y));
    p.z = f2bf(fabsf(a.z-b.z)); p.w = f2bf(fabsf(a.w-b.w));
    *(ushort4*)(A + i*128 + ((c*8) ^ ((i&7)<<4))) = p;
  }
  __syncthreads();
  int w = t>>6, l = t&63, lr = l&15, lg = l>>4;
  int sw = (lr&7)<<4;
  f32x4 zero = {0.f,0.f,0.f,0.f};
  f32x4 acc[3][8];
#pragma unroll
  for (int r=0;r<3;r++)
#pragma unroll
    for (int c=0;c<8;c++) acc[r][c] = zero;
#pragma unroll
  for (int kk=0;kk<2;kk++){
    bf16x8 af[3], bfr[8];
#pragma unroll
    for (int r=0;r<3;r++){
      int row = (w*3+r)*16 + lr;
      af[r] = *(const bf16x8*)(A + row*128 + ((lg*16 + 64*kk) ^ sw));
    }
#pragma unroll
    for (int c=0;c<8;c++){
      int col = c*16 + lr;
      bfr[c] = *(const bf16x8*)(W + col*128 + ((lg*16 + 64*kk) ^ sw));
    }
#pragma unroll
    for (int r=0;r<3;r++)
#pragma unroll
      for (int c=0;c<8;c++)
        acc[r][c] = __builtin_amdgcn_mfma_f32_16x16x32_bf16(af[r], bfr[c], acc[r][c], 0,0,0);
  }
  __syncthreads();
#pragma unroll
  for (int r=0;r<3;r++){
#pragma unroll
    for (int c=0;c<8;c++){
      int col = c*16 + lr;
      float scl = sS[col], shf = sS[128+col];
#pragma unroll
      for (int q=0;q<4;q++){
        int row = (w*3+r)*16 + lg*4 + q;
        float v = fmaxf(acc[r][c][q]*scl + shf, 0.f);
        *(unsigned short*)(A + row*256 + ((col*2) ^ ((row&7)<<4))) = f2bf(v);
      }
    }
  }
  __syncthreads();
  f32x4 acc2[3];
#pragma unroll
  for (int r=0;r<3;r++) acc2[r] = zero;
#pragma unroll
  for (int kk=0;kk<4;kk++){
    bf16x8 bw = *(const bf16x8*)(W2T + lr*256 + ((lg*16 + 64*kk) ^ sw));
#pragma unroll
    for (int r=0;r<3;r++){
      int row = (w*3+r)*16 + lr;
      bf16x8 ah = *(const bf16x8*)(A + row*256 + ((lg*16 + 64*kk) ^ sw));
      acc2[r] = __builtin_amdgcn_mfma_f32_16x16x32_bf16(ah, bw, acc2[r], 0,0,0);
    }
  }
  float b2a = b2g[0], b2b = b2g[1];
  size_t obase = (size_t)gid * NPGc;
#pragma unroll
  for (int r=0;r<3;r++){
#pragma unroll
    for (int q=0;q<4;q++){
      float o = acc2[r][q];
      float oo = __shfl_xor(o, 1, 64);
      if (lr < 2){
        int row = (w*3+r)*16 + lg*4 + q;
        float self = o + ((lr==0) ? b2a : b2b);
        float oth  = oo + ((lr==0) ? b2b : b2a);
        float mx = fmaxf(self, oth);
        float lse = mx + logf(expf(self-mx) + expf(oth-mx));
        out[(obase + row)*2 + lr] = self - lse;
      }
    }
  }
}

extern "C" void kernel_launch(void* const* d_in, const int* in_sizes, int n_in,
                              void* d_out, int out_size, void* d_ws, size_t ws_size,
                              hipStream_t stream){
  const float* x    = (const float*)d_in[0];
  const int*   ei   = (const int*)d_in[1];
  const float* ea   = (const float*)d_in[2];
  const float* efw1 = (const float*)d_in[4];
  const float* efb1 = (const float*)d_in[5];
  const float* efw2 = (const float*)d_in[6];
  const float* efb2 = (const float*)d_in[7];
  const float* efwr = (const float*)d_in[8];
  const float* bn1g = (const float*)d_in[9];
  const float* bn1b = (const float*)d_in[10];
  const float* ecw1 = (const float*)d_in[11];
  const float* ecb1 = (const float*)d_in[12];
  const float* ecw2 = (const float*)d_in[13];
  const float* ecb2 = (const float*)d_in[14];
  const float* bn2g = (const float*)d_in[15];
  const float* bn2b = (const float*)d_in[16];
  const float* m2w1 = (const float*)d_in[17];
  const float* m2bng = (const float*)d_in[19];
  const float* m2bnb = (const float*)d_in[20];
  const float* m2w2  = (const float*)d_in[21];
  const float* m2b2  = (const float*)d_in[22];

  char* ws = (char*)d_ws;
  float*    x1a   = (float*)(ws + 0);
  float*    x1bn  = (float*)(ws + 1572864);
  float*    x2bn  = (float*)(ws + 3145728);
  float*    x2f   = (float*)(ws + 4718592);
  float*    sqv   = (float*)(ws + 6291456);
  unsigned* nbr   = (unsigned*)(ws + 6316032);
  float*    stats = (float*)(ws + 6512640);
  float*    dbins = (float*)(ws + 6515712);
  u64*      parts = (u64*)(ws + 6581248);
  // overlays (disjoint lifetimes):
  float*    A2    = (float*)(ws + 0);            // over x1a (dead after bn1 apply)
  float*    Qm    = (float*)(ws + 3145728);      // over x2bn slot (written later)
  float*    P1    = (float*)(ws + 3145728);      // edge1 phase only
  float*    P2    = (float*)(ws + 4718592);
  // CSR scratch + EAc overlay the parts region (dead before k_knn writes parts)
  unsigned* rcnt  = (unsigned*)(ws + 6581248);
  unsigned* rptr  = rcnt + 6400;
  unsigned* rcur  = rptr + 6400;
  unsigned* rlist = rcur + 6400;
  float*    EAc   = (float*)(ws + 6581248 + 4194304);   // ends at ws+23358464
  float *g1sum = stats,     *g1ss = stats+64;
  float *g2sum = stats+256, *g2ss = stats+320;
  float *dsc = stats+512, *dsh = stats+640;
  float* outp = (float*)d_out;

  int CH = 48;
  if (ws_size < 6581248ull + (size_t)NN*48*64 + 3145728ull + 20480ull) CH = 24;
  if (ws_size < 6581248ull + (size_t)NN*24*64 + 3145728ull + 20480ull) CH = 16;
  size_t parts2_off = 6581248ull + (size_t)CH*NN*64;
  size_t wpre_off = parts2_off + 3145728ull;
  if (wpre_off < 23358464ull) wpre_off = 23358464ull;   // keep clear of EAc
  u64* parts2 = (u64*)(ws + parts2_off);
  unsigned short* Wpre  = (unsigned short*)(ws + wpre_off);
  unsigned short* W2Tp  = (unsigned short*)(ws + wpre_off + 16384);

  k_init<<<64,256,0,stream>>>(dbins, stats);
  k_prep_w<<<9,256,0,stream>>>(m2w1, m2w2, Wpre, W2Tp);
  k_root<<<1536,256,0,stream>>>(x, efwr, x1a);
  k_eac<<<3072,256,0,stream>>>(ea, efw1, EAc);
  k_zero_cnt<<<24,256,0,stream>>>(rcnt);
  k_cnt_dst<<<192,256,0,stream>>>(ei, rcnt);
  k_scan<<<1,256,0,stream>>>(rcnt, rptr, rcur);
  k_fill_dst<<<192,256,0,stream>>>(ei, rcur, rlist);
  k_p12<<<384,256,0,stream>>>(x, efw1, efb1, P1, P2);
  k_node1<<<384,128,0,stream>>>(P1, P2, EAc, ei, rptr, rlist, efw2, efb2, x1a);
  k_bn_stats<<<96,256,0,stream>>>(x1a, g1sum, g1ss);
  k_apply_bn1_sq<<<1536,256,0,stream>>>(x1a, g1sum, g1ss, bn1g, bn1b, x1bn, sqv);
  dim3 kg(24, CH);
  k_knn<<<kg,128,0,stream>>>(x1bn, sqv, parts, CH);
  k_knn_merge1<<<192,256,0,stream>>>(parts, CH/8, parts2);
  k_knn_merge2<<<24,256,0,stream>>>(parts2, nbr);
  k_zero_cnt<<<24,256,0,stream>>>(rcnt);
  k_rev_cnt<<<192,256,0,stream>>>(nbr, rcnt);
  k_scan<<<1,256,0,stream>>>(rcnt, rptr, rcur);
  k_rev_fill<<<192,256,0,stream>>>(nbr, rcur, rlist);
  k_pq<<<384,256,0,stream>>>(x1bn, ecw1, ecb1, A2, Qm);
  k_edge2max<<<384,128,0,stream>>>(A2, Qm, nbr, rptr, rlist, ecw2, ecb2, x2f);
  k_bn_stats<<<96,256,0,stream>>>(x2f, g2sum, g2ss);
  k_apply_bn2f<<<1536,256,0,stream>>>(x2f, g2sum, g2ss, bn2g, bn2b, x2bn);
  k_d_stats<<<6144,256,0,stream>>>(x2bn, Wpre, dbins);
  k_d_fin<<<1,128,0,stream>>>(dbins, m2bng, m2bnb, dsc, dsh);
  k_d_main<<<6144,256,0,stream>>>(x2bn, Wpre, W2Tp, m2b2, dsc, dsh, outp);
}

// Round 13
// 490.071 us; speedup vs baseline: 1.3519x; 1.0437x over previous
//
#include <hip/hip_runtime.h>

#define NN 6144
#define GG 32
#define NPGc 192
#define FINc 32
#define FEc 8
#define Hc 64
#define HMc 128
#define Kc 8
#define Ec 49152
#define NKc (NN*Kc)
#define RTOTc (GG*NPGc*NPGc)

typedef float f32x4 __attribute__((ext_vector_type(4)));
typedef short bf16x8 __attribute__((ext_vector_type(8)));
typedef unsigned long long u64;

__device__ __forceinline__ unsigned short f2bf(float f){
  unsigned u = __float_as_uint(f);
  unsigned r = u + 0x7fffu + ((u>>16)&1u);
  return (unsigned short)(r>>16);
}
__device__ __forceinline__ unsigned fenc(float f){
  unsigned u = __float_as_uint(f);
  return (u & 0x80000000u) ? ~u : (u | 0x80000000u);
}
__device__ __forceinline__ float fdec(unsigned e){
  unsigned u = (e & 0x80000000u) ? (e & 0x7fffffffu) : ~e;
  return __uint_as_float(u);
}
__device__ __forceinline__ void bub8(u64* t8, u64 k){
#pragma unroll
  for (int q=0;q<8;q++){ u64 cur=t8[q]; u64 lo=(k<cur)?k:cur; u64 hi=(k<cur)?cur:k; t8[q]=lo; k=hi; }
}

// ---------------- init: zero accumulators ----------------
__global__ void k_init(float* dbins, float* stats){
  int idx = blockIdx.x*256 + threadIdx.x;
  if (idx < 64*256) dbins[idx] = 0.f;
  if (idx < 768) stats[idx] = 0.f;
}

// ---------------- precompute bf16-swizzled W1 (16KB) and W2T (4KB) for d_stats/d_main ----------------
__global__ void k_prep_w(const float* __restrict__ w1, const float* __restrict__ w2,
                         unsigned short* __restrict__ Wpre, unsigned short* __restrict__ W2Tp){
  int idx = blockIdx.x*256 + threadIdx.x;   // 9 blocks = 2304 threads
  if (idx < 2048){
    int c = idx >> 4, c4 = idx & 15;
    ushort4 p;
    p.x = f2bf(w1[(4*c4+0)*HMc + c]);
    p.y = f2bf(w1[(4*c4+1)*HMc + c]);
    p.z = f2bf(w1[(4*c4+2)*HMc + c]);
    p.w = f2bf(w1[(4*c4+3)*HMc + c]);
    *(ushort4*)((char*)Wpre + c*128 + ((c4*8) ^ ((c&7)<<4))) = p;
  } else if (idx < 2304){
    int t2 = idx - 2048;
    int c = t2>>4, kc = t2&15;
    ushort4 p0 = make_ushort4(0,0,0,0), p1 = make_ushort4(0,0,0,0);
    if (c < 2){
      p0.x = f2bf(w2[(kc*8+0)*2 + c]); p0.y = f2bf(w2[(kc*8+1)*2 + c]);
      p0.z = f2bf(w2[(kc*8+2)*2 + c]); p0.w = f2bf(w2[(kc*8+3)*2 + c]);
      p1.x = f2bf(w2[(kc*8+4)*2 + c]); p1.y = f2bf(w2[(kc*8+5)*2 + c]);
      p1.z = f2bf(w2[(kc*8+6)*2 + c]); p1.w = f2bf(w2[(kc*8+7)*2 + c]);
    }
    int byte = c*256 + ((kc*16) ^ ((c&7)<<4));
    *(ushort4*)((char*)W2Tp + byte) = p0;
    *(ushort4*)((char*)W2Tp + byte + 8) = p1;
  }
}

// ---------------- x1a = x @ ef_wroot ----------------
__global__ __launch_bounds__(256) void k_root(const float* __restrict__ x, const float* __restrict__ wr, float* __restrict__ x1a){
  __shared__ float Ws[FINc*Hc];
  __shared__ float xr[4][FINc];
  int t = threadIdx.x;
  for (int q=t;q<FINc*Hc;q+=256) Ws[q] = wr[q];
  int rg = t>>6, j = t&63;
  int r = blockIdx.x*4 + rg;
  if (j < FINc) xr[rg][j] = x[r*FINc + j];
  __syncthreads();
  float a0=0.f, a1=0.f;
#pragma unroll
  for (int k=0;k<FINc;k+=2){
    a0 = fmaf(xr[rg][k],   Ws[k*Hc+j],     a0);
    a1 = fmaf(xr[rg][k+1], Ws[(k+1)*Hc+j], a1);
  }
  x1a[r*Hc + j] = a0 + a1;
}

// ---------------- edge1 precompute: EAc[e] = ea[e] @ W1c (rows 64..71) ----------------
__global__ __launch_bounds__(256) void k_eac(const float* __restrict__ ea, const float* __restrict__ w1, float* __restrict__ EAc){
  __shared__ float Wc[FEc*Hc];
  int t = threadIdx.x;
  for (int q=t; q<FEc*Hc; q+=256) Wc[q] = w1[64*Hc + q];
  __syncthreads();
  int idx = blockIdx.x*256 + t;
  int e = idx >> 4, c4 = (idx & 15)*4;
  float av[8];
#pragma unroll
  for (int q=0;q<8;q++) av[q] = ea[e*FEc + q];
  float4 o = {0.f,0.f,0.f,0.f};
#pragma unroll
  for (int q=0;q<8;q++){
    o.x = fmaf(av[q], Wc[q*Hc + c4+0], o.x);
    o.y = fmaf(av[q], Wc[q*Hc + c4+1], o.y);
    o.z = fmaf(av[q], Wc[q*Hc + c4+2], o.z);
    o.w = fmaf(av[q], Wc[q*Hc + c4+3], o.w);
  }
  *(float4*)(EAc + (size_t)e*Hc + c4) = o;
}

// ---------------- edge1 precompute: P1 = x@W1a + b1 (dst part), P2 = x@W1b (src part) ----------------
__global__ __launch_bounds__(256) void k_p12(const float* __restrict__ x, const float* __restrict__ w1, const float* __restrict__ b1,
                                             float* __restrict__ P1, float* __restrict__ P2){
  __shared__ float xs[16][32];
  int t = threadIdx.x;
  int j = t & 63, w = t >> 6;
  float wa[32], wb[32];
#pragma unroll
  for (int k=0;k<32;k++){
    wa[k] = w1[k*Hc + j];
    wb[k] = w1[(32+k)*Hc + j];
  }
  float b1j = b1[j];
  int nb = blockIdx.x * 16;
  for (int q=t; q<16*32; q+=256) xs[q>>5][q&31] = x[(size_t)(nb + (q>>5))*FINc + (q&31)];
  __syncthreads();
#pragma unroll
  for (int it=0; it<4; it++){
    int nl = it*4 + w;
    float a = b1j, b = 0.f;
#pragma unroll
    for (int k=0;k<32;k++){
      float xv = xs[nl][k];
      a = fmaf(xv, wa[k], a);
      b = fmaf(xv, wb[k], b);
    }
    int n = nb + nl;
    P1[(size_t)n*Hc + j] = a;
    P2[(size_t)n*Hc + j] = b;
  }
}

// ---------------- generic CSR build pieces ----------------
__global__ void k_zero_cnt(unsigned* rcnt){
  int idx = blockIdx.x*256 + threadIdx.x;
  if (idx < NN) rcnt[idx] = 0u;
}
__global__ void k_cnt_dst(const int* __restrict__ ei, unsigned* __restrict__ rcnt){
  int e = blockIdx.x*256 + threadIdx.x;
  atomicAdd(&rcnt[ei[Ec + e]], 1u);
}
__global__ __launch_bounds__(256) void k_scan(const unsigned* __restrict__ rcnt, unsigned* __restrict__ rptr, unsigned* __restrict__ rcur){
  __shared__ unsigned ps[256];
  int t = threadIdx.x;
  unsigned loc[24];
  unsigned s = 0;
#pragma unroll
  for (int q=0;q<24;q++){ loc[q] = s; s += rcnt[t*24+q]; }
  ps[t] = s;
  __syncthreads();
  for (int off=1; off<256; off<<=1){
    unsigned v = (t>=off)? ps[t-off] : 0u;
    __syncthreads();
    ps[t] += v;
    __syncthreads();
  }
  unsigned base = (t==0)? 0u : ps[t-1];
#pragma unroll
  for (int q=0;q<24;q++){ unsigned v = base + loc[q]; rptr[t*24+q]=v; rcur[t*24+q]=v; }
  if (t==255) rptr[NN] = ps[255];
}
__global__ void k_fill_dst(const int* __restrict__ ei, unsigned* __restrict__ rcur, unsigned* __restrict__ rlist){
  int e = blockIdx.x*256 + threadIdx.x;
  unsigned pos = atomicAdd(&rcur[ei[Ec + e]], 1u);
  rlist[pos] = (unsigned)e;
}
__global__ void k_rev_cnt(const unsigned* __restrict__ nbr, unsigned* __restrict__ rcnt){
  int e = blockIdx.x*256 + threadIdx.x;
  atomicAdd(&rcnt[nbr[e]], 1u);
}
__global__ void k_rev_fill(const unsigned* __restrict__ nbr, unsigned* __restrict__ rcur, unsigned* __restrict__ rlist){
  int e = blockIdx.x*256 + threadIdx.x;
  unsigned pos = atomicAdd(&rcur[nbr[e]], 1u);
  rlist[pos] = (unsigned)(e >> 3);
}

// ---------------- edge1 aggregate: x1a[n] += (Σ_in relu(P1[n]+P2[s]+EAc[e])) @ W2 + deg·b2 ----------------
__global__ __launch_bounds__(128) void k_node1(const float* __restrict__ P1, const float* __restrict__ P2, const float* __restrict__ EAc,
        const int* __restrict__ ei, const unsigned* __restrict__ rptr, const unsigned* __restrict__ rlist,
        const float* __restrict__ w2, const float* __restrict__ b2, float* __restrict__ x1a){
  __shared__ __align__(16) float accs[16][68];
  __shared__ __align__(16) float W2T[64][68];
  __shared__ unsigned rp_s[17];
  int t = threadIdx.x;
  int d0 = blockIdx.x * 16;
  for (int q=t; q<64*64; q+=128) W2T[q&63][q>>6] = w2[q];
  if (t < 17) rp_s[t] = rptr[d0 + t];
  __syncthreads();
  int slot = t>>3, cg = t&7, c0 = cg*8;
  int n = d0 + slot;
  float4 p1a = *(const float4*)(P1 + (size_t)n*Hc + c0);
  float4 p1b = *(const float4*)(P1 + (size_t)n*Hc + c0 + 4);
  float acc[8];
#pragma unroll
  for (int q=0;q<8;q++) acc[q] = 0.f;
  unsigned beg = rp_s[slot], end = rp_s[slot+1];
  for (unsigned pos=beg; pos<end; pos++){
    unsigned e = rlist[pos];
    int s = ei[e];
    float4 qa = *(const float4*)(P2 + (size_t)s*Hc + c0);
    float4 qb = *(const float4*)(P2 + (size_t)s*Hc + c0 + 4);
    float4 fa = *(const float4*)(EAc + (size_t)e*Hc + c0);
    float4 fb = *(const float4*)(EAc + (size_t)e*Hc + c0 + 4);
    acc[0] += fmaxf(p1a.x + qa.x + fa.x, 0.f);
    acc[1] += fmaxf(p1a.y + qa.y + fa.y, 0.f);
    acc[2] += fmaxf(p1a.z + qa.z + fa.z, 0.f);
    acc[3] += fmaxf(p1a.w + qa.w + fa.w, 0.f);
    acc[4] += fmaxf(p1b.x + qb.x + fb.x, 0.f);
    acc[5] += fmaxf(p1b.y + qb.y + fb.y, 0.f);
    acc[6] += fmaxf(p1b.z + qb.z + fb.z, 0.f);
    acc[7] += fmaxf(p1b.w + qb.w + fb.w, 0.f);
  }
  *(float4*)&accs[slot][c0]   = make_float4(acc[0],acc[1],acc[2],acc[3]);
  *(float4*)&accs[slot][c0+4] = make_float4(acc[4],acc[5],acc[6],acc[7]);
  __syncthreads();
  float out[8];
#pragma unroll
  for (int q=0;q<8;q++) out[q] = 0.f;
  for (int k4=0;k4<16;k4++){
    float4 hv = *(const float4*)&accs[slot][k4*4];
#pragma unroll
    for (int cc=0;cc<8;cc++){
      float4 wv = *(const float4*)&W2T[c0+cc][k4*4];
      out[cc] = fmaf(hv.x,wv.x, fmaf(hv.y,wv.y, fmaf(hv.z,wv.z, fmaf(hv.w,wv.w, out[cc]))));
    }
  }
  float deg = (float)(end - beg);
  float* px = x1a + (size_t)n*Hc + c0;
#pragma unroll
  for (int cc=0;cc<8;cc++) px[cc] += out[cc] + deg*b2[c0+cc];
}

// ---------------- BN stats over N rows x 64 cols ----------------
__global__ __launch_bounds__(256) void k_bn_stats(const float* __restrict__ src, float* __restrict__ gsum, float* __restrict__ gss){
  int t = threadIdx.x;
  int c = t & 63;
  int r0 = blockIdx.x*64 + (t>>6);
  float s=0.f, ss=0.f;
  for (int it=0; it<16; it++){
    int r = r0 + it*4;
    float v = src[r*Hc + c];
    s += v; ss += v*v;
  }
  __shared__ float S[64], SS[64];
  if (t < 64){ S[t]=0.f; SS[t]=0.f; }
  __syncthreads();
  atomicAdd(&S[c], s); atomicAdd(&SS[c], ss);
  __syncthreads();
  if (t < 64){ atomicAdd(&gsum[t], S[t]); atomicAdd(&gss[t], SS[t]); }
}

// ---------------- apply BN1 (fused finalize) + per-row squared norm ----------------
__global__ __launch_bounds__(256) void k_apply_bn1_sq(const float* __restrict__ x1a,
                               const float* __restrict__ gsum, const float* __restrict__ gss,
                               const float* __restrict__ gam, const float* __restrict__ bet,
                               float* __restrict__ x1bn, float* __restrict__ sqv){
  __shared__ float scs[64], shs[64];
  int t = threadIdx.x;
  if (t < 64){
    float mean = gsum[t] / (float)NN;
    float var  = gss[t] / (float)NN - mean*mean;
    float rs = rsqrtf(var + 1e-5f);
    float s = rs * gam[t];
    scs[t] = s; shs[t] = bet[t] - mean*s;
  }
  __syncthreads();
  int c = t & 63;
  int r = blockIdx.x*4 + (t>>6);
  float v = x1a[r*Hc + c]*scs[c] + shs[c];
  x1bn[r*Hc + c] = v;
  float s = v*v;
#pragma unroll
  for (int off=1; off<64; off<<=1) s += __shfl_xor(s, off, 64);
  if (c == 0) sqv[r] = s;
}

// ---------------- KNN: LDS-broadcast distances + online top-8 (round-6 proven body, CH=96) ----------------
__global__ __launch_bounds__(128,2) void k_knn(const float* __restrict__ x1bn, const float* __restrict__ sqv, u64* __restrict__ parts, int CH){
  __shared__ __align__(16) float XJ[64][68];
  __shared__ float sqj[64];
  int t = threadIdx.x;
  int i1 = blockIdx.x*256 + t;
  int i2 = i1 + 128;
  float4 xa[16], xb[16];
#pragma unroll
  for (int q=0;q<16;q++){
    xa[q] = *(const float4*)(x1bn + (size_t)i1*Hc + q*4);
    xb[q] = *(const float4*)(x1bn + (size_t)i2*Hc + q*4);
  }
  float sqi1 = sqv[i1], sqi2 = sqv[i2];
  u64 t8a[8], t8b[8];
#pragma unroll
  for (int q=0;q<8;q++){ t8a[q] = ~0ull; t8b[q] = ~0ull; }
  float thra = __uint_as_float(0x7f800000u);
  float thrb = thra;
  int cpc = NN / CH;
  int nsub = cpc >> 6;
  int jbase0 = blockIdx.y * cpc;
  for (int sub=0; sub<nsub; sub++){
    int jb = jbase0 + sub*64;
    __syncthreads();
    {
      int c = t>>1, hh = t&1;
      const float4* srcp = (const float4*)(x1bn + (size_t)(jb + c)*Hc + hh*32);
#pragma unroll
      for (int q=0;q<8;q++) *(float4*)&XJ[c][hh*32 + q*4] = srcp[q];
      if (t < 64) sqj[t] = sqv[jb + t];
    }
    __syncthreads();
    for (int j=0;j<64;j++){
      float sqjc = sqj[j];
      float a0=0.f,a1=0.f,a2=0.f,a3=0.f,b0=0.f,b1=0.f,b2=0.f,b3=0.f;
#pragma unroll
      for (int q4=0;q4<4;q4++){
        float4 xj0 = *(const float4*)&XJ[j][q4*16];
        float4 xj1 = *(const float4*)&XJ[j][q4*16+4];
        float4 xj2 = *(const float4*)&XJ[j][q4*16+8];
        float4 xj3 = *(const float4*)&XJ[j][q4*16+12];
        float4 A0 = xa[q4*4+0], A1 = xa[q4*4+1], A2v = xa[q4*4+2], A3 = xa[q4*4+3];
        float4 B0 = xb[q4*4+0], B1 = xb[q4*4+1], B2v = xb[q4*4+2], B3 = xb[q4*4+3];
        a0=fmaf(A0.x,xj0.x,a0); a1=fmaf(A0.y,xj0.y,a1); a2=fmaf(A0.z,xj0.z,a2); a3=fmaf(A0.w,xj0.w,a3);
        b0=fmaf(B0.x,xj0.x,b0); b1=fmaf(B0.y,xj0.y,b1); b2=fmaf(B0.z,xj0.z,b2); b3=fmaf(B0.w,xj0.w,b3);
        a0=fmaf(A1.x,xj1.x,a0); a1=fmaf(A1.y,xj1.y,a1); a2=fmaf(A1.z,xj1.z,a2); a3=fmaf(A1.w,xj1.w,a3);
        b0=fmaf(B1.x,xj1.x,b0); b1=fmaf(B1.y,xj1.y,b1); b2=fmaf(B1.z,xj1.z,b2); b3=fmaf(B1.w,xj1.w,b3);
        a0=fmaf(A2v.x,xj2.x,a0); a1=fmaf(A2v.y,xj2.y,a1); a2=fmaf(A2v.z,xj2.z,a2); a3=fmaf(A2v.w,xj2.w,a3);
        b0=fmaf(B2v.x,xj2.x,b0); b1=fmaf(B2v.y,xj2.y,b1); b2=fmaf(B2v.z,xj2.z,b2); b3=fmaf(B2v.w,xj2.w,b3);
        a0=fmaf(A3.x,xj3.x,a0); a1=fmaf(A3.y,xj3.y,a1); a2=fmaf(A3.z,xj3.z,a2); a3=fmaf(A3.w,xj3.w,a3);
        b0=fmaf(B3.x,xj3.x,b0); b1=fmaf(B3.y,xj3.y,b1); b2=fmaf(B3.z,xj3.z,b2); b3=fmaf(B3.w,xj3.w,b3);
      }
      float dot1 = (a0+a1)+(a2+a3);
      float dot2 = (b0+b1)+(b2+b3);
      int jj = jb + j;
      float d2a = (sqi1 + sqjc) - 2.f*dot1;
      float d2b = (sqi2 + sqjc) - 2.f*dot2;
      bool ia = !(d2a > thra) && (jj != i1);
      bool ib = !(d2b > thrb) && (jj != i2);
      if (__builtin_expect(ia | ib, 0)){
        if (ia){
          u64 ka = (((u64)fenc(d2a))<<32) | (unsigned)jj;
          bub8(t8a, ka);
          thra = fdec((unsigned)(t8a[7]>>32));
        }
        if (ib){
          u64 kb = (((u64)fenc(d2b))<<32) | (unsigned)jj;
          bub8(t8b, kb);
          thrb = fdec((unsigned)(t8b[7]>>32));
        }
      }
    }
  }
  u64* pa = parts + ((size_t)blockIdx.y*NN + i1)*8;
  u64* pb = parts + ((size_t)blockIdx.y*NN + i2)*8;
#pragma unroll
  for (int q=0;q<8;q++){ pa[q] = t8a[q]; pb[q] = t8b[q]; }
}

// ---------------- two-stage parallel merge (top-8 of a set is partition-independent) ----------------
__global__ __launch_bounds__(256) void k_knn_merge1(const u64* __restrict__ parts, int CPG, u64* __restrict__ parts2){
  int g = blockIdx.x / 24;
  int r = (blockIdx.x % 24)*256 + threadIdx.x;
  u64 t8[8];
#pragma unroll
  for (int q=0;q<8;q++) t8[q] = ~0ull;
  for (int ch=g*CPG; ch<(g+1)*CPG; ch++){
    const u64* p = parts + ((size_t)ch*NN + r)*8;
    u64 k[8];
#pragma unroll
    for (int q=0;q<8;q++) k[q] = p[q];
#pragma unroll
    for (int q=0;q<8;q++){
      if (k[q] >= t8[7]) break;
      bub8(t8, k[q]);
    }
  }
  u64* o = parts2 + ((size_t)g*NN + r)*8;
#pragma unroll
  for (int q=0;q<8;q++) o[q] = t8[q];
}

__global__ __launch_bounds__(256) void k_knn_merge2(const u64* __restrict__ parts2, unsigned* __restrict__ nbr){
  int r = blockIdx.x*256 + threadIdx.x;
  u64 t8[8];
#pragma unroll
  for (int q=0;q<8;q++) t8[q] = ~0ull;
  for (int g=0; g<8; g++){
    const u64* p = parts2 + ((size_t)g*NN + r)*8;
    u64 k[8];
#pragma unroll
    for (int q=0;q<8;q++) k[q] = p[q];
#pragma unroll
    for (int q=0;q<8;q++){
      if (k[q] >= t8[7]) break;
      bub8(t8, k[q]);
    }
  }
#pragma unroll
  for (int s=0;s<8;s++) nbr[r*Kc + s] = (unsigned)(t8[s] & 0xffffffffu);
}

// ---------------- edge2 precompute: A2 = x1bn@(W1t-W1b)+b1 ; Q = x1bn@W1b ----------------
__global__ __launch_bounds__(256) void k_pq(const float* __restrict__ x1bn, const float* __restrict__ w1, const float* __restrict__ b1,
                                            float* __restrict__ A2, float* __restrict__ Qm){
  __shared__ float xs[16][64];
  int t = threadIdx.x;
  int j = t & 63, w = t >> 6;
  float wa[64], wb[64];
#pragma unroll
  for (int k=0;k<64;k++){
    float wt  = w1[k*64 + j];
    float wbv = w1[(64+k)*64 + j];
    wa[k] = wt - wbv; wb[k] = wbv;
  }
  float b1j = b1[j];
  int nb = blockIdx.x * 16;
  for (int q=t; q<16*64; q+=256) xs[q>>6][q&63] = x1bn[(size_t)(nb + (q>>6))*64 + (q&63)];
  __syncthreads();
#pragma unroll
  for (int it=0; it<4; it++){
    int nl = it*4 + w;
    float a = b1j, qq = 0.f;
#pragma unroll
    for (int k=0;k<64;k++){
      float xv = xs[nl][k];
      a  = fmaf(xv, wa[k], a);
      qq = fmaf(xv, wb[k], qq);
    }
    int n = nb + nl;
    A2[(size_t)n*64 + j] = a;
    Qm[(size_t)n*64 + j] = qq;
  }
}

// ---------------- edge2: per-destination-block GEMM + LDS max, no global atomics ----------------
__global__ __launch_bounds__(128) void k_edge2max(const float* __restrict__ A2, const float* __restrict__ Qm,
        const unsigned* __restrict__ nbr, const unsigned* __restrict__ rptr, const unsigned* __restrict__ rlist,
        const float* __restrict__ w2, const float* __restrict__ b2, float* __restrict__ x2f){
  __shared__ __align__(16) float W2T[64][68];
  __shared__ __align__(16) float hidT[64][132];
  __shared__ unsigned x2s[17][64];
  __shared__ unsigned rp_s[17];
  __shared__ int wslot[128];
  int t = threadIdx.x;
  int d0 = blockIdx.x * 16;
  for (int q=t; q<64*64; q+=128) W2T[q&63][q>>6] = w2[q];
  for (int q=t; q<17*64; q+=128) ((unsigned*)x2s)[q] = 0x007FFFFFu;
  if (t < 17) rp_s[t] = rptr[d0 + t];
  __syncthreads();
  unsigned rp0 = rp_s[0];
  int total_rev = (int)(rp_s[16] - rp0);
  int eg = t & 15, cg = t >> 4;
  int r0 = eg*8, c0 = cg*8;
  float b2v[8];
#pragma unroll
  for (int cc=0;cc<8;cc++) b2v[cc] = b2[c0+cc];
  int ntile = 1 + ((total_rev + 127) >> 7);
  for (int tile=0; tile<ntile; tile++){
    int d, s, active;
    if (tile == 0){
      d = d0 + (t>>3); s = (int)nbr[(size_t)d*8 + (t&7)]; active = 1; wslot[t] = t>>3;
    } else {
      int idx = (tile-1)*128 + t;
      active = idx < total_rev;
      if (active){
        unsigned pos = rp0 + (unsigned)idx;
        int sl = 0;
#pragma unroll
        for (int m=1; m<16; m++) sl += (pos >= rp_s[m]) ? 1 : 0;
        s = (int)rlist[pos];
        d = d0 + sl;
        wslot[t] = sl;
      } else { d = d0; s = 0; wslot[t] = 16; }
    }
    if (active){
      const float* pa = A2 + (size_t)d*64;
      const float* pq = Qm + (size_t)s*64;
#pragma unroll
      for (int c4=0; c4<16; c4++){
        float4 va = *(const float4*)(pa + c4*4);
        float4 vq = *(const float4*)(pq + c4*4);
        hidT[c4*4+0][t] = fmaxf(va.x+vq.x, 0.f);
        hidT[c4*4+1][t] = fmaxf(va.y+vq.y, 0.f);
        hidT[c4*4+2][t] = fmaxf(va.z+vq.z, 0.f);
        hidT[c4*4+3][t] = fmaxf(va.w+vq.w, 0.f);
      }
    } else {
#pragma unroll
      for (int c4=0; c4<16; c4++){
        hidT[c4*4+0][t] = 0.f; hidT[c4*4+1][t] = 0.f;
        hidT[c4*4+2][t] = 0.f; hidT[c4*4+3][t] = 0.f;
      }
    }
    __syncthreads();
    float acc[8][8];
#pragma unroll
    for (int i=0;i<8;i++)
#pragma unroll
      for (int cc=0;cc<8;cc++) acc[i][cc] = 0.f;
    for (int k=0;k<64;k+=4){
      float4 wv[8];
#pragma unroll
      for (int cc=0;cc<8;cc++) wv[cc] = *(const float4*)&W2T[c0+cc][k];
#pragma unroll
      for (int kk=0;kk<4;kk++){
        float4 h0 = *(const float4*)&hidT[k+kk][r0];
        float4 h1 = *(const float4*)&hidT[k+kk][r0+4];
        float hh[8] = {h0.x,h0.y,h0.z,h0.w,h1.x,h1.y,h1.z,h1.w};
#pragma unroll
        for (int i=0;i<8;i++)
#pragma unroll
          for (int cc=0;cc<8;cc++)
            acc[i][cc] = fmaf(hh[i], ((const float*)&wv[cc])[kk], acc[i][cc]);
      }
    }
    int cur = wslot[r0];
    float mx[8];
#pragma unroll
    for (int cc=0;cc<8;cc++) mx[cc] = acc[0][cc];
    for (int i=1;i<8;i++){
      int sl = wslot[r0+i];
      if (sl != cur){
#pragma unroll
        for (int cc=0;cc<8;cc++) atomicMax(&x2s[cur][c0+cc], fenc(mx[cc] + b2v[cc]));
        cur = sl;
#pragma unroll
        for (int cc=0;cc<8;cc++) mx[cc] = acc[i][cc];
      } else {
#pragma unroll
        for (int cc=0;cc<8;cc++) mx[cc] = fmaxf(mx[cc], acc[i][cc]);
      }
    }
#pragma unroll
    for (int cc=0;cc<8;cc++) atomicMax(&x2s[cur][c0+cc], fenc(mx[cc] + b2v[cc]));
    __syncthreads();
  }
#pragma unroll
  for (int q=0;q<8;q++){
    int idx = t + q*128;
    int sl = idx >> 6, c = idx & 63;
    x2f[(size_t)(d0+sl)*64 + c] = fdec(x2s[sl][c]);
  }
}

// ---------------- apply BN2 (fused finalize) ----------------
__global__ __launch_bounds__(256) void k_apply_bn2f(const float* __restrict__ x2f,
                               const float* __restrict__ gsum, const float* __restrict__ gss,
                               const float* __restrict__ gam, const float* __restrict__ bet,
                               float* __restrict__ x2bn){
  __shared__ float scs[64], shs[64];
  int t = threadIdx.x;
  if (t < 64){
    float mean = gsum[t] / (float)NN;
    float var  = gss[t] / (float)NN - mean*mean;
    float rs = rsqrtf(var + 1e-5f);
    float s = rs * gam[t];
    scs[t] = s; shs[t] = bet[t] - mean*s;
  }
  __syncthreads();
  int idx = blockIdx.x*256 + t;
  int c = idx & 63;
  x2bn[idx] = x2f[idx]*scs[c] + shs[c];
}

// ---------------- model2 pass 1: column sum/sumsq of diff@W1 via MFMA (pre-swizzled W) ----------------
__global__ __launch_bounds__(256,2) void k_d_stats(const float* __restrict__ x2bn, const unsigned short* __restrict__ Wpre, float* __restrict__ dbins){
  __shared__ __align__(16) char sm[24576 + 16384 + 1024];
  unsigned char* A = (unsigned char*)sm;
  unsigned char* W = (unsigned char*)sm + 24576;
  float* Ssum = (float*)(sm + 40960);
  int t = threadIdx.x;
  int gid = blockIdx.x; int g = gid / NPGc; int z = gid - g*NPGc;
  const float* xg = x2bn + (size_t)g*NPGc*Hc;
  const float* xz = xg + z*Hc;
  Ssum[t] = 0.f;
#pragma unroll
  for (int q=0;q<4;q++)
    *(float4*)(W + t*16 + q*4096) = *(const float4*)((const char*)Wpre + t*16 + q*4096);
#pragma unroll
  for (int q=0;q<12;q++){
    int task = t + 256*q; int i = task >> 4; int c = task & 15;
    float4 a = *(const float4*)(xg + i*Hc + c*4);
    float4 b = *(const float4*)(xz + c*4);
    ushort4 p;
    p.x = f2bf(fabsf(a.x-b.x)); p.y = f2bf(fabsf(a.y-b.y));
    p.z = f2bf(fabsf(a.z-b.z)); p.w = f2bf(fabsf(a.w-b.w));
    *(ushort4*)(A + i*128 + ((c*8) ^ ((i&7)<<4))) = p;
  }
  __syncthreads();
  int w = t>>6, l = t&63, lr = l&15, lg = l>>4;
  int sw = (lr&7)<<4;
  f32x4 zero = {0.f,0.f,0.f,0.f};
  f32x4 acc[3][8];
#pragma unroll
  for (int r=0;r<3;r++)
#pragma unroll
    for (int c=0;c<8;c++) acc[r][c] = zero;
#pragma unroll
  for (int kk=0;kk<2;kk++){
    bf16x8 af[3], bfr[8];
#pragma unroll
    for (int r=0;r<3;r++){
      int row = (w*3+r)*16 + lr;
      af[r] = *(const bf16x8*)(A + row*128 + ((lg*16 + 64*kk) ^ sw));
    }
#pragma unroll
    for (int c=0;c<8;c++){
      int col = c*16 + lr;
      bfr[c] = *(const bf16x8*)(W + col*128 + ((lg*16 + 64*kk) ^ sw));
    }
#pragma unroll
    for (int r=0;r<3;r++)
#pragma unroll
      for (int c=0;c<8;c++)
        acc[r][c] = __builtin_amdgcn_mfma_f32_16x16x32_bf16(af[r], bfr[c], acc[r][c], 0,0,0);
  }
#pragma unroll
  for (int c=0;c<8;c++){
    int col = c*16 + lr;
    float s=0.f, ss=0.f;
#pragma unroll
    for (int r=0;r<3;r++)
#pragma unroll
      for (int q=0;q<4;q++){ float v = acc[r][c][q]; s += v; ss = fmaf(v,v,ss); }
    s  += __shfl_xor(s, 16, 64);  ss += __shfl_xor(ss, 16, 64);
    s  += __shfl_xor(s, 32, 64);  ss += __shfl_xor(ss, 32, 64);
    if (lg == 0){
      atomicAdd(&Ssum[col], s);
      atomicAdd(&Ssum[128+col], ss);
    }
  }
  __syncthreads();
  if (t < 128){
    int bin = gid & 63;
    atomicAdd(&dbins[bin*256 + t], Ssum[t]);
    atomicAdd(&dbins[bin*256 + 128 + t], Ssum[128+t]);
  }
}

__global__ void k_d_fin(const float* __restrict__ dbins, const float* gam, const float* bet, float* dsc, float* dsh){
  int c = threadIdx.x; // 128
  float s=0.f, ss=0.f;
#pragma unroll 8
  for (int b=0;b<64;b++){ s += dbins[b*256 + c]; ss += dbins[b*256 + 128 + c]; }
  float mean = s / (float)RTOTc;
  float var  = ss / (float)RTOTc - mean*mean;
  float rs = rsqrtf(var + 1e-5f);
  float k = rs * gam[c];
  dsc[c] = k; dsh[c] = bet[c] - mean*k;
}

// ---------------- model2 main: diff@W1 -> BN -> ReLU -> @W2 -> log_softmax (pre-swizzled W) ----------------
__global__ __launch_bounds__(256,2) void k_d_main(const float* __restrict__ x2bn, const unsigned short* __restrict__ Wpre,
                         const unsigned short* __restrict__ W2Tp, const float* __restrict__ b2g,
                         const float* __restrict__ dsc, const float* __restrict__ dsh, float* __restrict__ out){
  __shared__ __align__(16) char sm[49152 + 4096 + 1024];
  unsigned char* A   = (unsigned char*)sm;
  unsigned char* W   = (unsigned char*)sm + 24576;
  unsigned char* W2T = (unsigned char*)sm + 49152;
  float* sS = (float*)(sm + 53248);
  int t = threadIdx.x;
  int gid = blockIdx.x; int g = gid / NPGc; int z = gid - g*NPGc;
  const float* xg = x2bn + (size_t)g*NPGc*Hc;
  const float* xz = xg + z*Hc;
  if (t < 128){ sS[t] = dsc[t]; sS[128+t] = dsh[t]; }
  *(float4*)(W2T + t*16) = *(const float4*)((const char*)W2Tp + t*16);
#pragma unroll
  for (int q=0;q<4;q++)
    *(float4*)(W + t*16 + q*4096) = *(const float4*)((const char*)Wpre + t*16 + q*4096);
#pragma unroll
  for (int q=0;q<12;q++){
    int task = t + 256*q; int i = task >> 4; int c = task & 15;
    float4 a = *(const float4*)(xg + i*Hc + c*4);
    float4 b = *(const float4*)(xz + c*4);
    ushort4 p;
    p.x = f2bf(fabsf(a.x-b.x)); p.y = f2bf(fabsf(a.y-b.y));
    p.z = f2bf(fabsf(a.z-b.z)); p.w = f2bf(fabsf(a.w-b.w));
    *(ushort4*)(A + i*128 + ((c*8) ^ ((i&7)<<4))) = p;
  }
  __syncthreads();
  int w = t>>6, l = t&63, lr = l&15, lg = l>>4;
  int sw = (lr&7)<<4;
  f32x4 zero = {0.f,0.f,0.f,0.f};
  f32x4 acc[3][8];
#pragma unroll
  for (int r=0;r<3;r++)
#pragma unroll
    for (int c=0;c<8;c++) acc[r][c] = zero;
#pragma unroll
  for (int kk=0;kk<2;kk++){
    bf16x8 af[3], bfr[8];
#pragma unroll
    for (int r=0;r<3;r++){
      int row = (w*3+r)*16 + lr;
      af[r] = *(const bf16x8*)(A + row*128 + ((lg*16 + 64*kk) ^ sw));
    }
#pragma unroll
    for (int c=0;c<8;c++){
      int col = c*16 + lr;
      bfr[c] = *(const bf16x8*)(W + col*128 + ((lg*16 + 64*kk) ^ sw));
    }
#pragma unroll
    for (int r=0;r<3;r++)
#pragma unroll
      for (int c=0;c<8;c++)
        acc[r][c] = __builtin_amdgcn_mfma_f32_16x16x32_bf16(af[r], bfr[c], acc[r][c], 0,0,0);
  }
  __syncthreads();
#pragma unroll
  for (int r=0;r<3;r++){
#pragma unroll
    for (int c=0;c<8;c++){
      int col = c*16 + lr;
      float scl = sS[col], shf = sS[128+col];
#pragma unroll
      for (int q=0;q<4;q++){
        int row = (w*3+r)*16 + lg*4 + q;
        float v = fmaxf(acc[r][c][q]*scl + shf, 0.f);
        *(unsigned short*)(A + row*256 + ((col*2) ^ ((row&7)<<4))) = f2bf(v);
      }
    }
  }
  __syncthreads();
  f32x4 acc2[3];
#pragma unroll
  for (int r=0;r<3;r++) acc2[r] = zero;
#pragma unroll
  for (int kk=0;kk<4;kk++){
    bf16x8 bw = *(const bf16x8*)(W2T + lr*256 + ((lg*16 + 64*kk) ^ sw));
#pragma unroll
    for (int r=0;r<3;r++){
      int row = (w*3+r)*16 + lr;
      bf16x8 ah = *(const bf16x8*)(A + row*256 + ((lg*16 + 64*kk) ^ sw));
      acc2[r] = __builtin_amdgcn_mfma_f32_16x16x32_bf16(ah, bw, acc2[r], 0,0,0);
    }
  }
  float b2a = b2g[0], b2b = b2g[1];
  size_t obase = (size_t)gid * NPGc;
#pragma unroll
  for (int r=0;r<3;r++){
#pragma unroll
    for (int q=0;q<4;q++){
      float o = acc2[r][q];
      float oo = __shfl_xor(o, 1, 64);
      if (lr < 2){
        int row = (w*3+r)*16 + lg*4 + q;
        float self = o + ((lr==0) ? b2a : b2b);
        float oth  = oo + ((lr==0) ? b2b : b2a);
        float mx = fmaxf(self, oth);
        float lse = mx + logf(expf(self-mx) + expf(oth-mx));
        out[(obase + row)*2 + lr] = self - lse;
      }
    }
  }
}

extern "C" void kernel_launch(void* const* d_in, const int* in_sizes, int n_in,
                              void* d_out, int out_size, void* d_ws, size_t ws_size,
                              hipStream_t stream){
  const float* x    = (const float*)d_in[0];
  const int*   ei   = (const int*)d_in[1];
  const float* ea   = (const float*)d_in[2];
  const float* efw1 = (const float*)d_in[4];
  const float* efb1 = (const float*)d_in[5];
  const float* efw2 = (const float*)d_in[6];
  const float* efb2 = (const float*)d_in[7];
  const float* efwr = (const float*)d_in[8];
  const float* bn1g = (const float*)d_in[9];
  const float* bn1b = (const float*)d_in[10];
  const float* ecw1 = (const float*)d_in[11];
  const float* ecb1 = (const float*)d_in[12];
  const float* ecw2 = (const float*)d_in[13];
  const float* ecb2 = (const float*)d_in[14];
  const float* bn2g = (const float*)d_in[15];
  const float* bn2b = (const float*)d_in[16];
  const float* m2w1 = (const float*)d_in[17];
  const float* m2bng = (const float*)d_in[19];
  const float* m2bnb = (const float*)d_in[20];
  const float* m2w2  = (const float*)d_in[21];
  const float* m2b2  = (const float*)d_in[22];

  char* ws = (char*)d_ws;
  float*    x1a   = (float*)(ws + 0);
  float*    x1bn  = (float*)(ws + 1572864);
  float*    x2bn  = (float*)(ws + 3145728);
  float*    x2f   = (float*)(ws + 4718592);
  float*    sqv   = (float*)(ws + 6291456);
  unsigned* nbr   = (unsigned*)(ws + 6316032);
  float*    stats = (float*)(ws + 6512640);
  float*    dbins = (float*)(ws + 6515712);
  u64*      parts = (u64*)(ws + 6581248);
  // overlays (disjoint lifetimes):
  float*    A2    = (float*)(ws + 0);            // over x1a (dead after bn1 apply)
  float*    Qm    = (float*)(ws + 3145728);      // over x2bn slot (written later)
  float*    P1    = (float*)(ws + 3145728);      // edge1 phase only
  float*    P2    = (float*)(ws + 4718592);
  // CSR scratch + EAc overlay the parts region (dead before k_knn writes parts)
  unsigned* rcnt  = (unsigned*)(ws + 6581248);
  unsigned* rptr  = rcnt + 6400;
  unsigned* rcur  = rptr + 6400;
  unsigned* rlist = rcur + 6400;
  float*    EAc   = (float*)(ws + 6581248 + 4194304);   // ends at ws+23358464
  float *g1sum = stats,     *g1ss = stats+64;
  float *g2sum = stats+256, *g2ss = stats+320;
  float *dsc = stats+512, *dsh = stats+640;
  float* outp = (float*)d_out;

  int CH = 96;   // 24x96 = 2304 blocks: the measured-best knn occupancy (r6/r10: 174us)
  if (ws_size < 6581248ull + (size_t)NN*96*64 + 3145728ull + 20480ull) CH = 48;
  if (ws_size < 6581248ull + (size_t)NN*48*64 + 3145728ull + 20480ull) CH = 24;
  size_t parts2_off = 6581248ull + (size_t)CH*NN*64;
  size_t wpre_off = parts2_off + 3145728ull;
  if (wpre_off < 23358464ull) wpre_off = 23358464ull;   // keep clear of EAc
  u64* parts2 = (u64*)(ws + parts2_off);
  unsigned short* Wpre  = (unsigned short*)(ws + wpre_off);
  unsigned short* W2Tp  = (unsigned short*)(ws + wpre_off + 16384);

  k_init<<<64,256,0,stream>>>(dbins, stats);
  k_prep_w<<<9,256,0,stream>>>(m2w1, m2w2, Wpre, W2Tp);
  k_root<<<1536,256,0,stream>>>(x, efwr, x1a);
  k_eac<<<3072,256,0,stream>>>(ea, efw1, EAc);
  k_zero_cnt<<<24,256,0,stream>>>(rcnt);
  k_cnt_dst<<<192,256,0,stream>>>(ei, rcnt);
  k_scan<<<1,256,0,stream>>>(rcnt, rptr, rcur);
  k_fill_dst<<<192,256,0,stream>>>(ei, rcur, rlist);
  k_p12<<<384,256,0,stream>>>(x, efw1, efb1, P1, P2);
  k_node1<<<384,128,0,stream>>>(P1, P2, EAc, ei, rptr, rlist, efw2, efb2, x1a);
  k_bn_stats<<<96,256,0,stream>>>(x1a, g1sum, g1ss);
  k_apply_bn1_sq<<<1536,256,0,stream>>>(x1a, g1sum, g1ss, bn1g, bn1b, x1bn, sqv);
  dim3 kg(24, CH);
  k_knn<<<kg,128,0,stream>>>(x1bn, sqv, parts, CH);
  k_knn_merge1<<<192,256,0,stream>>>(parts, CH/8, parts2);
  k_knn_merge2<<<24,256,0,stream>>>(parts2, nbr);
  k_zero_cnt<<<24,256,0,stream>>>(rcnt);
  k_rev_cnt<<<192,256,0,stream>>>(nbr, rcnt);
  k_scan<<<1,256,0,stream>>>(rcnt, rptr, rcur);
  k_rev_fill<<<192,256,0,stream>>>(nbr, rcur, rlist);
  k_pq<<<384,256,0,stream>>>(x1bn, ecw1, ecb1, A2, Qm);
  k_edge2max<<<384,128,0,stream>>>(A2, Qm, nbr, rptr, rlist, ecw2, ecb2, x2f);
  k_bn_stats<<<96,256,0,stream>>>(x2f, g2sum, g2ss);
  k_apply_bn2f<<<1536,256,0,stream>>>(x2f, g2sum, g2ss, bn2g, bn2b, x2bn);
  k_d_stats<<<6144,256,0,stream>>>(x2bn, Wpre, dbins);
  k_d_fin<<<1,128,0,stream>>>(dbins, m2bng, m2bnb, dsc, dsh);
  k_d_main<<<6144,256,0,stream>>>(x2bn, Wpre, W2Tp, m2b2, dsc, dsh, outp);
}

// Round 14
// 480.371 us; speedup vs baseline: 1.3792x; 1.0202x over previous
//
#include <hip/hip_runtime.h>

#define NN 6144
#define GG 32
#define NPGc 192
#define FINc 32
#define FEc 8
#define Hc 64
#define HMc 128
#define Kc 8
#define Ec 49152
#define NKc (NN*Kc)
#define RTOTc (GG*NPGc*NPGc)

typedef float f32x4 __attribute__((ext_vector_type(4)));
typedef short bf16x8 __attribute__((ext_vector_type(8)));
typedef unsigned long long u64;

__device__ __forceinline__ unsigned short f2bf(float f){
  unsigned u = __float_as_uint(f);
  unsigned r = u + 0x7fffu + ((u>>16)&1u);
  return (unsigned short)(r>>16);
}
__device__ __forceinline__ unsigned fenc(float f){
  unsigned u = __float_as_uint(f);
  return (u & 0x80000000u) ? ~u : (u | 0x80000000u);
}
__device__ __forceinline__ float fdec(unsigned e){
  unsigned u = (e & 0x80000000u) ? (e & 0x7fffffffu) : ~e;
  return __uint_as_float(u);
}
__device__ __forceinline__ void bub8(u64* t8, u64 k){
#pragma unroll
  for (int q=0;q<8;q++){ u64 cur=t8[q]; u64 lo=(k<cur)?k:cur; u64 hi=(k<cur)?cur:k; t8[q]=lo; k=hi; }
}

// ---------------- init: zero accumulators ----------------
__global__ void k_init(float* dbins, float* stats){
  int idx = blockIdx.x*256 + threadIdx.x;
  if (idx < 64*256) dbins[idx] = 0.f;
  if (idx < 768) stats[idx] = 0.f;
}

// ---------------- precompute bf16-swizzled W1 (16KB) and W2T (4KB) for d_stats/d_main ----------------
__global__ void k_prep_w(const float* __restrict__ w1, const float* __restrict__ w2,
                         unsigned short* __restrict__ Wpre, unsigned short* __restrict__ W2Tp){
  int idx = blockIdx.x*256 + threadIdx.x;   // 9 blocks = 2304 threads
  if (idx < 2048){
    int c = idx >> 4, c4 = idx & 15;
    ushort4 p;
    p.x = f2bf(w1[(4*c4+0)*HMc + c]);
    p.y = f2bf(w1[(4*c4+1)*HMc + c]);
    p.z = f2bf(w1[(4*c4+2)*HMc + c]);
    p.w = f2bf(w1[(4*c4+3)*HMc + c]);
    *(ushort4*)((char*)Wpre + c*128 + ((c4*8) ^ ((c&7)<<4))) = p;
  } else if (idx < 2304){
    int t2 = idx - 2048;
    int c = t2>>4, kc = t2&15;
    ushort4 p0 = make_ushort4(0,0,0,0), p1 = make_ushort4(0,0,0,0);
    if (c < 2){
      p0.x = f2bf(w2[(kc*8+0)*2 + c]); p0.y = f2bf(w2[(kc*8+1)*2 + c]);
      p0.z = f2bf(w2[(kc*8+2)*2 + c]); p0.w = f2bf(w2[(kc*8+3)*2 + c]);
      p1.x = f2bf(w2[(kc*8+4)*2 + c]); p1.y = f2bf(w2[(kc*8+5)*2 + c]);
      p1.z = f2bf(w2[(kc*8+6)*2 + c]); p1.w = f2bf(w2[(kc*8+7)*2 + c]);
    }
    int byte = c*256 + ((kc*16) ^ ((c&7)<<4));
    *(ushort4*)((char*)W2Tp + byte) = p0;
    *(ushort4*)((char*)W2Tp + byte + 8) = p1;
  }
}

// ---------------- x1a = x @ ef_wroot ----------------
__global__ __launch_bounds__(256) void k_root(const float* __restrict__ x, const float* __restrict__ wr, float* __restrict__ x1a){
  __shared__ float Ws[FINc*Hc];
  __shared__ float xr[4][FINc];
  int t = threadIdx.x;
  for (int q=t;q<FINc*Hc;q+=256) Ws[q] = wr[q];
  int rg = t>>6, j = t&63;
  int r = blockIdx.x*4 + rg;
  if (j < FINc) xr[rg][j] = x[r*FINc + j];
  __syncthreads();
  float a0=0.f, a1=0.f;
#pragma unroll
  for (int k=0;k<FINc;k+=2){
    a0 = fmaf(xr[rg][k],   Ws[k*Hc+j],     a0);
    a1 = fmaf(xr[rg][k+1], Ws[(k+1)*Hc+j], a1);
  }
  x1a[r*Hc + j] = a0 + a1;
}

// ---------------- edge1 precompute: EAc[e] = ea[e] @ W1c (rows 64..71) ----------------
__global__ __launch_bounds__(256) void k_eac(const float* __restrict__ ea, const float* __restrict__ w1, float* __restrict__ EAc){
  __shared__ float Wc[FEc*Hc];
  int t = threadIdx.x;
  for (int q=t; q<FEc*Hc; q+=256) Wc[q] = w1[64*Hc + q];
  __syncthreads();
  int idx = blockIdx.x*256 + t;
  int e = idx >> 4, c4 = (idx & 15)*4;
  float av[8];
#pragma unroll
  for (int q=0;q<8;q++) av[q] = ea[e*FEc + q];
  float4 o = {0.f,0.f,0.f,0.f};
#pragma unroll
  for (int q=0;q<8;q++){
    o.x = fmaf(av[q], Wc[q*Hc + c4+0], o.x);
    o.y = fmaf(av[q], Wc[q*Hc + c4+1], o.y);
    o.z = fmaf(av[q], Wc[q*Hc + c4+2], o.z);
    o.w = fmaf(av[q], Wc[q*Hc + c4+3], o.w);
  }
  *(float4*)(EAc + (size_t)e*Hc + c4) = o;
}

// ---------------- edge1 precompute: P1 = x@W1a + b1 (dst part), P2 = x@W1b (src part) ----------------
__global__ __launch_bounds__(256) void k_p12(const float* __restrict__ x, const float* __restrict__ w1, const float* __restrict__ b1,
                                             float* __restrict__ P1, float* __restrict__ P2){
  __shared__ float xs[16][32];
  int t = threadIdx.x;
  int j = t & 63, w = t >> 6;
  float wa[32], wb[32];
#pragma unroll
  for (int k=0;k<32;k++){
    wa[k] = w1[k*Hc + j];
    wb[k] = w1[(32+k)*Hc + j];
  }
  float b1j = b1[j];
  int nb = blockIdx.x * 16;
  for (int q=t; q<16*32; q+=256) xs[q>>5][q&31] = x[(size_t)(nb + (q>>5))*FINc + (q&31)];
  __syncthreads();
#pragma unroll
  for (int it=0; it<4; it++){
    int nl = it*4 + w;
    float a = b1j, b = 0.f;
#pragma unroll
    for (int k=0;k<32;k++){
      float xv = xs[nl][k];
      a = fmaf(xv, wa[k], a);
      b = fmaf(xv, wb[k], b);
    }
    int n = nb + nl;
    P1[(size_t)n*Hc + j] = a;
    P2[(size_t)n*Hc + j] = b;
  }
}

// ---------------- generic CSR build pieces ----------------
__global__ void k_zero_cnt(unsigned* rcnt){
  int idx = blockIdx.x*256 + threadIdx.x;
  if (idx < NN) rcnt[idx] = 0u;
}
__global__ void k_cnt_dst(const int* __restrict__ ei, unsigned* __restrict__ rcnt){
  int e = blockIdx.x*256 + threadIdx.x;
  atomicAdd(&rcnt[ei[Ec + e]], 1u);
}
__global__ __launch_bounds__(256) void k_scan(const unsigned* __restrict__ rcnt, unsigned* __restrict__ rptr, unsigned* __restrict__ rcur){
  __shared__ unsigned ps[256];
  int t = threadIdx.x;
  unsigned loc[24];
  unsigned s = 0;
#pragma unroll
  for (int q=0;q<24;q++){ loc[q] = s; s += rcnt[t*24+q]; }
  ps[t] = s;
  __syncthreads();
  for (int off=1; off<256; off<<=1){
    unsigned v = (t>=off)? ps[t-off] : 0u;
    __syncthreads();
    ps[t] += v;
    __syncthreads();
  }
  unsigned base = (t==0)? 0u : ps[t-1];
#pragma unroll
  for (int q=0;q<24;q++){ unsigned v = base + loc[q]; rptr[t*24+q]=v; rcur[t*24+q]=v; }
  if (t==255) rptr[NN] = ps[255];
}
__global__ void k_fill_dst(const int* __restrict__ ei, unsigned* __restrict__ rcur, unsigned* __restrict__ rlist){
  int e = blockIdx.x*256 + threadIdx.x;
  unsigned pos = atomicAdd(&rcur[ei[Ec + e]], 1u);
  rlist[pos] = (unsigned)e;
}
__global__ void k_rev_cnt(const unsigned* __restrict__ nbr, unsigned* __restrict__ rcnt){
  int e = blockIdx.x*256 + threadIdx.x;
  atomicAdd(&rcnt[nbr[e]], 1u);
}
__global__ void k_rev_fill(const unsigned* __restrict__ nbr, unsigned* __restrict__ rcur, unsigned* __restrict__ rlist){
  int e = blockIdx.x*256 + threadIdx.x;
  unsigned pos = atomicAdd(&rcur[nbr[e]], 1u);
  rlist[pos] = (unsigned)(e >> 3);
}

// ---------------- edge1 aggregate (256 thr: 16 nodes x 16 col-groups of 4) ----------------
__global__ __launch_bounds__(256) void k_node1(const float* __restrict__ P1, const float* __restrict__ P2, const float* __restrict__ EAc,
        const int* __restrict__ ei, const unsigned* __restrict__ rptr, const unsigned* __restrict__ rlist,
        const float* __restrict__ w2, const float* __restrict__ b2, float* __restrict__ x1a){
  __shared__ __align__(16) float accs[16][68];
  __shared__ __align__(16) float W2T[64][68];
  __shared__ unsigned rp_s[17];
  int t = threadIdx.x;
  int d0 = blockIdx.x * 16;
  for (int q=t; q<64*64; q+=256) W2T[q&63][q>>6] = w2[q];
  if (t < 17) rp_s[t] = rptr[d0 + t];
  __syncthreads();
  int slot = t>>4, cg = t&15, c0 = cg*4;
  int n = d0 + slot;
  float4 p1 = *(const float4*)(P1 + (size_t)n*Hc + c0);
  float acc[4];
#pragma unroll
  for (int q=0;q<4;q++) acc[q] = 0.f;
  unsigned beg = rp_s[slot], end = rp_s[slot+1];
  for (unsigned pos=beg; pos<end; pos++){
    unsigned e = rlist[pos];
    int s = ei[e];
    float4 q4 = *(const float4*)(P2 + (size_t)s*Hc + c0);
    float4 f4 = *(const float4*)(EAc + (size_t)e*Hc + c0);
    acc[0] += fmaxf(p1.x + q4.x + f4.x, 0.f);
    acc[1] += fmaxf(p1.y + q4.y + f4.y, 0.f);
    acc[2] += fmaxf(p1.z + q4.z + f4.z, 0.f);
    acc[3] += fmaxf(p1.w + q4.w + f4.w, 0.f);
  }
  *(float4*)&accs[slot][c0] = make_float4(acc[0],acc[1],acc[2],acc[3]);
  __syncthreads();
  float out[4];
#pragma unroll
  for (int q=0;q<4;q++) out[q] = 0.f;
  for (int k4=0;k4<16;k4++){
    float4 hv = *(const float4*)&accs[slot][k4*4];
#pragma unroll
    for (int cc=0;cc<4;cc++){
      float4 wv = *(const float4*)&W2T[c0+cc][k4*4];
      out[cc] = fmaf(hv.x,wv.x, fmaf(hv.y,wv.y, fmaf(hv.z,wv.z, fmaf(hv.w,wv.w, out[cc]))));
    }
  }
  float deg = (float)(end - beg);
  float* px = x1a + (size_t)n*Hc + c0;
#pragma unroll
  for (int cc=0;cc<4;cc++) px[cc] += out[cc] + deg*b2[c0+cc];
}

// ---------------- BN stats over N rows x 64 cols ----------------
__global__ __launch_bounds__(256) void k_bn_stats(const float* __restrict__ src, float* __restrict__ gsum, float* __restrict__ gss){
  int t = threadIdx.x;
  int c = t & 63;
  int r0 = blockIdx.x*64 + (t>>6);
  float s=0.f, ss=0.f;
  for (int it=0; it<16; it++){
    int r = r0 + it*4;
    float v = src[r*Hc + c];
    s += v; ss += v*v;
  }
  __shared__ float S[64], SS[64];
  if (t < 64){ S[t]=0.f; SS[t]=0.f; }
  __syncthreads();
  atomicAdd(&S[c], s); atomicAdd(&SS[c], ss);
  __syncthreads();
  if (t < 64){ atomicAdd(&gsum[t], S[t]); atomicAdd(&gss[t], SS[t]); }
}

// ---------------- apply BN1 (fused finalize) + per-row squared norm ----------------
__global__ __launch_bounds__(256) void k_apply_bn1_sq(const float* __restrict__ x1a,
                               const float* __restrict__ gsum, const float* __restrict__ gss,
                               const float* __restrict__ gam, const float* __restrict__ bet,
                               float* __restrict__ x1bn, float* __restrict__ sqv){
  __shared__ float scs[64], shs[64];
  int t = threadIdx.x;
  if (t < 64){
    float mean = gsum[t] / (float)NN;
    float var  = gss[t] / (float)NN - mean*mean;
    float rs = rsqrtf(var + 1e-5f);
    float s = rs * gam[t];
    scs[t] = s; shs[t] = bet[t] - mean*s;
  }
  __syncthreads();
  int c = t & 63;
  int r = blockIdx.x*4 + (t>>6);
  float v = x1a[r*Hc + c]*scs[c] + shs[c];
  x1bn[r*Hc + c] = v;
  float s = v*v;
#pragma unroll
  for (int off=1; off<64; off<<=1) s += __shfl_xor(s, off, 64);
  if (c == 0) sqv[r] = s;
}

// ---------------- KNN: LDS-broadcast distances + online top-8 (proven body, CH=96) ----------------
__global__ __launch_bounds__(128,2) void k_knn(const float* __restrict__ x1bn, const float* __restrict__ sqv, u64* __restrict__ parts, int CH){
  __shared__ __align__(16) float XJ[64][68];
  __shared__ float sqj[64];
  int t = threadIdx.x;
  int i1 = blockIdx.x*256 + t;
  int i2 = i1 + 128;
  float4 xa[16], xb[16];
#pragma unroll
  for (int q=0;q<16;q++){
    xa[q] = *(const float4*)(x1bn + (size_t)i1*Hc + q*4);
    xb[q] = *(const float4*)(x1bn + (size_t)i2*Hc + q*4);
  }
  float sqi1 = sqv[i1], sqi2 = sqv[i2];
  u64 t8a[8], t8b[8];
#pragma unroll
  for (int q=0;q<8;q++){ t8a[q] = ~0ull; t8b[q] = ~0ull; }
  float thra = __uint_as_float(0x7f800000u);
  float thrb = thra;
  int cpc = NN / CH;
  int nsub = cpc >> 6;
  int jbase0 = blockIdx.y * cpc;
  for (int sub=0; sub<nsub; sub++){
    int jb = jbase0 + sub*64;
    __syncthreads();
    {
      int c = t>>1, hh = t&1;
      const float4* srcp = (const float4*)(x1bn + (size_t)(jb + c)*Hc + hh*32);
#pragma unroll
      for (int q=0;q<8;q++) *(float4*)&XJ[c][hh*32 + q*4] = srcp[q];
      if (t < 64) sqj[t] = sqv[jb + t];
    }
    __syncthreads();
    for (int j=0;j<64;j++){
      float sqjc = sqj[j];
      float a0=0.f,a1=0.f,a2=0.f,a3=0.f,b0=0.f,b1=0.f,b2=0.f,b3=0.f;
#pragma unroll
      for (int q4=0;q4<4;q4++){
        float4 xj0 = *(const float4*)&XJ[j][q4*16];
        float4 xj1 = *(const float4*)&XJ[j][q4*16+4];
        float4 xj2 = *(const float4*)&XJ[j][q4*16+8];
        float4 xj3 = *(const float4*)&XJ[j][q4*16+12];
        float4 A0 = xa[q4*4+0], A1 = xa[q4*4+1], A2v = xa[q4*4+2], A3 = xa[q4*4+3];
        float4 B0 = xb[q4*4+0], B1 = xb[q4*4+1], B2v = xb[q4*4+2], B3 = xb[q4*4+3];
        a0=fmaf(A0.x,xj0.x,a0); a1=fmaf(A0.y,xj0.y,a1); a2=fmaf(A0.z,xj0.z,a2); a3=fmaf(A0.w,xj0.w,a3);
        b0=fmaf(B0.x,xj0.x,b0); b1=fmaf(B0.y,xj0.y,b1); b2=fmaf(B0.z,xj0.z,b2); b3=fmaf(B0.w,xj0.w,b3);
        a0=fmaf(A1.x,xj1.x,a0); a1=fmaf(A1.y,xj1.y,a1); a2=fmaf(A1.z,xj1.z,a2); a3=fmaf(A1.w,xj1.w,a3);
        b0=fmaf(B1.x,xj1.x,b0); b1=fmaf(B1.y,xj1.y,b1); b2=fmaf(B1.z,xj1.z,b2); b3=fmaf(B1.w,xj1.w,b3);
        a0=fmaf(A2v.x,xj2.x,a0); a1=fmaf(A2v.y,xj2.y,a1); a2=fmaf(A2v.z,xj2.z,a2); a3=fmaf(A2v.w,xj2.w,a3);
        b0=fmaf(B2v.x,xj2.x,b0); b1=fmaf(B2v.y,xj2.y,b1); b2=fmaf(B2v.z,xj2.z,b2); b3=fmaf(B2v.w,xj2.w,b3);
        a0=fmaf(A3.x,xj3.x,a0); a1=fmaf(A3.y,xj3.y,a1); a2=fmaf(A3.z,xj3.z,a2); a3=fmaf(A3.w,xj3.w,a3);
        b0=fmaf(B3.x,xj3.x,b0); b1=fmaf(B3.y,xj3.y,b1); b2=fmaf(B3.z,xj3.z,b2); b3=fmaf(B3.w,xj3.w,b3);
      }
      float dot1 = (a0+a1)+(a2+a3);
      float dot2 = (b0+b1)+(b2+b3);
      int jj = jb + j;
      float d2a = (sqi1 + sqjc) - 2.f*dot1;
      float d2b = (sqi2 + sqjc) - 2.f*dot2;
      bool ia = !(d2a > thra) && (jj != i1);
      bool ib = !(d2b > thrb) && (jj != i2);
      if (__builtin_expect(ia | ib, 0)){
        if (ia){
          u64 ka = (((u64)fenc(d2a))<<32) | (unsigned)jj;
          bub8(t8a, ka);
          thra = fdec((unsigned)(t8a[7]>>32));
        }
        if (ib){
          u64 kb = (((u64)fenc(d2b))<<32) | (unsigned)jj;
          bub8(t8b, kb);
          thrb = fdec((unsigned)(t8b[7]>>32));
        }
      }
    }
  }
  u64* pa = parts + ((size_t)blockIdx.y*NN + i1)*8;
  u64* pb = parts + ((size_t)blockIdx.y*NN + i2)*8;
#pragma unroll
  for (int q=0;q<8;q++){ pa[q] = t8a[q]; pb[q] = t8b[q]; }
}

// ---------------- two-stage parallel merge ----------------
__global__ __launch_bounds__(256) void k_knn_merge1(const u64* __restrict__ parts, int CPG, u64* __restrict__ parts2){
  int g = blockIdx.x / 24;
  int r = (blockIdx.x % 24)*256 + threadIdx.x;
  u64 t8[8];
#pragma unroll
  for (int q=0;q<8;q++) t8[q] = ~0ull;
  for (int ch=g*CPG; ch<(g+1)*CPG; ch++){
    const u64* p = parts + ((size_t)ch*NN + r)*8;
    u64 k[8];
#pragma unroll
    for (int q=0;q<8;q++) k[q] = p[q];
#pragma unroll
    for (int q=0;q<8;q++){
      if (k[q] >= t8[7]) break;
      bub8(t8, k[q]);
    }
  }
  u64* o = parts2 + ((size_t)g*NN + r)*8;
#pragma unroll
  for (int q=0;q<8;q++) o[q] = t8[q];
}

__global__ __launch_bounds__(256) void k_knn_merge2(const u64* __restrict__ parts2, unsigned* __restrict__ nbr){
  int r = blockIdx.x*256 + threadIdx.x;
  u64 t8[8];
#pragma unroll
  for (int q=0;q<8;q++) t8[q] = ~0ull;
  for (int g=0; g<8; g++){
    const u64* p = parts2 + ((size_t)g*NN + r)*8;
    u64 k[8];
#pragma unroll
    for (int q=0;q<8;q++) k[q] = p[q];
#pragma unroll
    for (int q=0;q<8;q++){
      if (k[q] >= t8[7]) break;
      bub8(t8, k[q]);
    }
  }
#pragma unroll
  for (int s=0;s<8;s++) nbr[r*Kc + s] = (unsigned)(t8[s] & 0xffffffffu);
}

// ---------------- edge2 precompute: A2 = x1bn@(W1t-W1b)+b1 ; Q = x1bn@W1b ----------------
__global__ __launch_bounds__(256) void k_pq(const float* __restrict__ x1bn, const float* __restrict__ w1, const float* __restrict__ b1,
                                            float* __restrict__ A2, float* __restrict__ Qm){
  __shared__ float xs[16][64];
  int t = threadIdx.x;
  int j = t & 63, w = t >> 6;
  float wa[64], wb[64];
#pragma unroll
  for (int k=0;k<64;k++){
    float wt  = w1[k*64 + j];
    float wbv = w1[(64+k)*64 + j];
    wa[k] = wt - wbv; wb[k] = wbv;
  }
  float b1j = b1[j];
  int nb = blockIdx.x * 16;
  for (int q=t; q<16*64; q+=256) xs[q>>6][q&63] = x1bn[(size_t)(nb + (q>>6))*64 + (q&63)];
  __syncthreads();
#pragma unroll
  for (int it=0; it<4; it++){
    int nl = it*4 + w;
    float a = b1j, qq = 0.f;
#pragma unroll
    for (int k=0;k<64;k++){
      float xv = xs[nl][k];
      a  = fmaf(xv, wa[k], a);
      qq = fmaf(xv, wb[k], qq);
    }
    int n = nb + nl;
    A2[(size_t)n*64 + j] = a;
    Qm[(size_t)n*64 + j] = qq;
  }
}

// ---------------- edge2 (256 thr): per-dst-block GEMM 8 edges x 4 cols/thread + LDS max ----------------
__global__ __launch_bounds__(256) void k_edge2max(const float* __restrict__ A2, const float* __restrict__ Qm,
        const unsigned* __restrict__ nbr, const unsigned* __restrict__ rptr, const unsigned* __restrict__ rlist,
        const float* __restrict__ w2, const float* __restrict__ b2, float* __restrict__ x2f){
  __shared__ __align__(16) float W2T[64][68];
  __shared__ __align__(16) float hidT[64][132];
  __shared__ unsigned x2s[17][64];
  __shared__ unsigned rp_s[17];
  __shared__ int wslot[128];
  int t = threadIdx.x;
  int d0 = blockIdx.x * 16;
  for (int q=t; q<64*64; q+=256) W2T[q&63][q>>6] = w2[q];
  for (int q=t; q<17*64; q+=256) ((unsigned*)x2s)[q] = 0x007FFFFFu;
  if (t < 17) rp_s[t] = rptr[d0 + t];
  __syncthreads();
  unsigned rp0 = rp_s[0];
  int total_rev = (int)(rp_s[16] - rp0);
  int e2 = t & 127, kh = t >> 7;          // staging split: edge + k-half
  int eg = t & 15, cg = t >> 4;           // GEMM: 8 edges x 4 cols
  int r0 = eg*8, c0 = cg*4;
  float b2v[4];
#pragma unroll
  for (int cc=0;cc<4;cc++) b2v[cc] = b2[c0+cc];
  int ntile = 1 + ((total_rev + 127) >> 7);
  for (int tile=0; tile<ntile; tile++){
    int d, s, active;
    if (tile == 0){
      d = d0 + (e2>>3); s = (int)nbr[(size_t)d*8 + (e2&7)]; active = 1; wslot[e2] = e2>>3;
    } else {
      int idx = (tile-1)*128 + e2;
      active = idx < total_rev;
      if (active){
        unsigned pos = rp0 + (unsigned)idx;
        int sl = 0;
#pragma unroll
        for (int m=1; m<16; m++) sl += (pos >= rp_s[m]) ? 1 : 0;
        s = (int)rlist[pos];
        d = d0 + sl;
        wslot[e2] = sl;
      } else { d = d0; s = 0; wslot[e2] = 16; }
    }
    if (active){
      const float* pa = A2 + (size_t)d*64;
      const float* pq = Qm + (size_t)s*64;
#pragma unroll
      for (int c4i=0; c4i<8; c4i++){
        int c4 = kh*8 + c4i;
        float4 va = *(const float4*)(pa + c4*4);
        float4 vq = *(const float4*)(pq + c4*4);
        hidT[c4*4+0][e2] = fmaxf(va.x+vq.x, 0.f);
        hidT[c4*4+1][e2] = fmaxf(va.y+vq.y, 0.f);
        hidT[c4*4+2][e2] = fmaxf(va.z+vq.z, 0.f);
        hidT[c4*4+3][e2] = fmaxf(va.w+vq.w, 0.f);
      }
    } else {
#pragma unroll
      for (int c4i=0; c4i<8; c4i++){
        int c4 = kh*8 + c4i;
        hidT[c4*4+0][e2] = 0.f; hidT[c4*4+1][e2] = 0.f;
        hidT[c4*4+2][e2] = 0.f; hidT[c4*4+3][e2] = 0.f;
      }
    }
    __syncthreads();
    float acc[8][4];
#pragma unroll
    for (int i=0;i<8;i++)
#pragma unroll
      for (int cc=0;cc<4;cc++) acc[i][cc] = 0.f;
    for (int k=0;k<64;k+=4){
      float4 wv[4];
#pragma unroll
      for (int cc=0;cc<4;cc++) wv[cc] = *(const float4*)&W2T[c0+cc][k];
#pragma unroll
      for (int kk=0;kk<4;kk++){
        float4 h0 = *(const float4*)&hidT[k+kk][r0];
        float4 h1 = *(const float4*)&hidT[k+kk][r0+4];
        float hh[8] = {h0.x,h0.y,h0.z,h0.w,h1.x,h1.y,h1.z,h1.w};
#pragma unroll
        for (int i=0;i<8;i++)
#pragma unroll
          for (int cc=0;cc<4;cc++)
            acc[i][cc] = fmaf(hh[i], ((const float*)&wv[cc])[kk], acc[i][cc]);
      }
    }
    int cur = wslot[r0];
    float mx[4];
#pragma unroll
    for (int cc=0;cc<4;cc++) mx[cc] = acc[0][cc];
    for (int i=1;i<8;i++){
      int sl = wslot[r0+i];
      if (sl != cur){
#pragma unroll
        for (int cc=0;cc<4;cc++) atomicMax(&x2s[cur][c0+cc], fenc(mx[cc] + b2v[cc]));
        cur = sl;
#pragma unroll
        for (int cc=0;cc<4;cc++) mx[cc] = acc[i][cc];
      } else {
#pragma unroll
        for (int cc=0;cc<4;cc++) mx[cc] = fmaxf(mx[cc], acc[i][cc]);
      }
    }
#pragma unroll
    for (int cc=0;cc<4;cc++) atomicMax(&x2s[cur][c0+cc], fenc(mx[cc] + b2v[cc]));
    __syncthreads();
  }
#pragma unroll
  for (int q=0;q<4;q++){
    int idx = t + q*256;
    int sl = idx >> 6, c = idx & 63;
    x2f[(size_t)(d0+sl)*64 + c] = fdec(x2s[sl][c]);
  }
}

// ---------------- apply BN2 (fused finalize) ----------------
__global__ __launch_bounds__(256) void k_apply_bn2f(const float* __restrict__ x2f,
                               const float* __restrict__ gsum, const float* __restrict__ gss,
                               const float* __restrict__ gam, const float* __restrict__ bet,
                               float* __restrict__ x2bn){
  __shared__ float scs[64], shs[64];
  int t = threadIdx.x;
  if (t < 64){
    float mean = gsum[t] / (float)NN;
    float var  = gss[t] / (float)NN - mean*mean;
    float rs = rsqrtf(var + 1e-5f);
    float s = rs * gam[t];
    scs[t] = s; shs[t] = bet[t] - mean*s;
  }
  __syncthreads();
  int idx = blockIdx.x*256 + t;
  int c = idx & 63;
  x2bn[idx] = x2f[idx]*scs[c] + shs[c];
}

// ---------------- model2 pass 1: Ssum aliases A (LDS 40960 -> 4 blocks/CU) ----------------
__global__ __launch_bounds__(256,2) void k_d_stats(const float* __restrict__ x2bn, const unsigned short* __restrict__ Wpre, float* __restrict__ dbins){
  __shared__ __align__(16) char sm[24576 + 16384];
  unsigned char* A = (unsigned char*)sm;
  unsigned char* W = (unsigned char*)sm + 24576;
  float* Ssum = (float*)sm;                 // overlays A; used only after MFMA reads complete
  int t = threadIdx.x;
  int gid = blockIdx.x; int g = gid / NPGc; int z = gid - g*NPGc;
  const float* xg = x2bn + (size_t)g*NPGc*Hc;
  const float* xz = xg + z*Hc;
#pragma unroll
  for (int q=0;q<4;q++)
    *(float4*)(W + t*16 + q*4096) = *(const float4*)((const char*)Wpre + t*16 + q*4096);
#pragma unroll
  for (int q=0;q<12;q++){
    int task = t + 256*q; int i = task >> 4; int c = task & 15;
    float4 a = *(const float4*)(xg + i*Hc + c*4);
    float4 b = *(const float4*)(xz + c*4);
    ushort4 p;
    p.x = f2bf(fabsf(a.x-b.x)); p.y = f2bf(fabsf(a.y-b.y));
    p.z = f2bf(fabsf(a.z-b.z)); p.w = f2bf(fabsf(a.w-b.w));
    *(ushort4*)(A + i*128 + ((c*8) ^ ((i&7)<<4))) = p;
  }
  __syncthreads();
  int w = t>>6, l = t&63, lr = l&15, lg = l>>4;
  int sw = (lr&7)<<4;
  f32x4 zero = {0.f,0.f,0.f,0.f};
  f32x4 acc[3][8];
#pragma unroll
  for (int r=0;r<3;r++)
#pragma unroll
    for (int c=0;c<8;c++) acc[r][c] = zero;
#pragma unroll
  for (int kk=0;kk<2;kk++){
    bf16x8 af[3], bfr[8];
#pragma unroll
    for (int r=0;r<3;r++){
      int row = (w*3+r)*16 + lr;
      af[r] = *(const bf16x8*)(A + row*128 + ((lg*16 + 64*kk) ^ sw));
    }
#pragma unroll
    for (int c=0;c<8;c++){
      int col = c*16 + lr;
      bfr[c] = *(const bf16x8*)(W + col*128 + ((lg*16 + 64*kk) ^ sw));
    }
#pragma unroll
    for (int r=0;r<3;r++)
#pragma unroll
      for (int c=0;c<8;c++)
        acc[r][c] = __builtin_amdgcn_mfma_f32_16x16x32_bf16(af[r], bfr[c], acc[r][c], 0,0,0);
  }
  __syncthreads();            // all A reads done; reuse as Ssum
  Ssum[t] = 0.f;
  __syncthreads();
#pragma unroll
  for (int c=0;c<8;c++){
    int col = c*16 + lr;
    float s=0.f, ss=0.f;
#pragma unroll
    for (int r=0;r<3;r++)
#pragma unroll
      for (int q=0;q<4;q++){ float v = acc[r][c][q]; s += v; ss = fmaf(v,v,ss); }
    s  += __shfl_xor(s, 16, 64);  ss += __shfl_xor(ss, 16, 64);
    s  += __shfl_xor(s, 32, 64);  ss += __shfl_xor(ss, 32, 64);
    if (lg == 0){
      atomicAdd(&Ssum[col], s);
      atomicAdd(&Ssum[128+col], ss);
    }
  }
  __syncthreads();
  if (t < 128){
    int bin = gid & 63;
    atomicAdd(&dbins[bin*256 + t], Ssum[t]);
    atomicAdd(&dbins[bin*256 + 128 + t], Ssum[128+t]);
  }
}

__global__ void k_d_fin(const float* __restrict__ dbins, const float* gam, const float* bet, float* dsc, float* dsh){
  int c = threadIdx.x; // 128
  float s=0.f, ss=0.f;
#pragma unroll 8
  for (int b=0;b<64;b++){ s += dbins[b*256 + c]; ss += dbins[b*256 + 128 + c]; }
  float mean = s / (float)RTOTc;
  float var  = ss / (float)RTOTc - mean*mean;
  float rs = rsqrtf(var + 1e-5f);
  float k = rs * gam[c];
  dsc[c] = k; dsh[c] = bet[c] - mean*k;
}

// ---------------- model2 main: diff@W1 -> BN -> ReLU -> @W2 -> log_softmax (pre-swizzled W) ----------------
__global__ __launch_bounds__(256,2) void k_d_main(const float* __restrict__ x2bn, const unsigned short* __restrict__ Wpre,
                         const unsigned short* __restrict__ W2Tp, const float* __restrict__ b2g,
                         const float* __restrict__ dsc, const float* __restrict__ dsh, float* __restrict__ out){
  __shared__ __align__(16) char sm[49152 + 4096 + 1024];
  unsigned char* A   = (unsigned char*)sm;
  unsigned char* W   = (unsigned char*)sm + 24576;
  unsigned char* W2T = (unsigned char*)sm + 49152;
  float* sS = (float*)(sm + 53248);
  int t = threadIdx.x;
  int gid = blockIdx.x; int g = gid / NPGc; int z = gid - g*NPGc;
  const float* xg = x2bn + (size_t)g*NPGc*Hc;
  const float* xz = xg + z*Hc;
  if (t < 128){ sS[t] = dsc[t]; sS[128+t] = dsh[t]; }
  *(float4*)(W2T + t*16) = *(const float4*)((const char*)W2Tp + t*16);
#pragma unroll
  for (int q=0;q<4;q++)
    *(float4*)(W + t*16 + q*4096) = *(const float4*)((const char*)Wpre + t*16 + q*4096);
#pragma unroll
  for (int q=0;q<12;q++){
    int task = t + 256*q; int i = task >> 4; int c = task & 15;
    float4 a = *(const float4*)(xg + i*Hc + c*4);
    float4 b = *(const float4*)(xz + c*4);
    ushort4 p;
    p.x = f2bf(fabsf(a.x-b.x)); p.y = f2bf(fabsf(a.y-b.y));
    p.z = f2bf(fabsf(a.z-b.z)); p.w = f2bf(fabsf(a.w-b.w));
    *(ushort4*)(A + i*128 + ((c*8) ^ ((i&7)<<4))) = p;
  }
  __syncthreads();
  int w = t>>6, l = t&63, lr = l&15, lg = l>>4;
  int sw = (lr&7)<<4;
  f32x4 zero = {0.f,0.f,0.f,0.f};
  f32x4 acc[3][8];
#pragma unroll
  for (int r=0;r<3;r++)
#pragma unroll
    for (int c=0;c<8;c++) acc[r][c] = zero;
#pragma unroll
  for (int kk=0;kk<2;kk++){
    bf16x8 af[3], bfr[8];
#pragma unroll
    for (int r=0;r<3;r++){
      int row = (w*3+r)*16 + lr;
      af[r] = *(const bf16x8*)(A + row*128 + ((lg*16 + 64*kk) ^ sw));
    }
#pragma unroll
    for (int c=0;c<8;c++){
      int col = c*16 + lr;
      bfr[c] = *(const bf16x8*)(W + col*128 + ((lg*16 + 64*kk) ^ sw));
    }
#pragma unroll
    for (int r=0;r<3;r++)
#pragma unroll
      for (int c=0;c<8;c++)
        acc[r][c] = __builtin_amdgcn_mfma_f32_16x16x32_bf16(af[r], bfr[c], acc[r][c], 0,0,0);
  }
  __syncthreads();
#pragma unroll
  for (int r=0;r<3;r++){
#pragma unroll
    for (int c=0;c<8;c++){
      int col = c*16 + lr;
      float scl = sS[col], shf = sS[128+col];
#pragma unroll
      for (int q=0;q<4;q++){
        int row = (w*3+r)*16 + lg*4 + q;
        float v = fmaxf(acc[r][c][q]*scl + shf, 0.f);
        *(unsigned short*)(A + row*256 + ((col*2) ^ ((row&7)<<4))) = f2bf(v);
      }
    }
  }
  __syncthreads();
  f32x4 acc2[3];
#pragma unroll
  for (int r=0;r<3;r++) acc2[r] = zero;
#pragma unroll
  for (int kk=0;kk<4;kk++){
    bf16x8 bw = *(const bf16x8*)(W2T + lr*256 + ((lg*16 + 64*kk) ^ sw));
#pragma unroll
    for (int r=0;r<3;r++){
      int row = (w*3+r)*16 + lr;
      bf16x8 ah = *(const bf16x8*)(A + row*256 + ((lg*16 + 64*kk) ^ sw));
      acc2[r] = __builtin_amdgcn_mfma_f32_16x16x32_bf16(ah, bw, acc2[r], 0,0,0);
    }
  }
  float b2a = b2g[0], b2b = b2g[1];
  size_t obase = (size_t)gid * NPGc;
#pragma unroll
  for (int r=0;r<3;r++){
#pragma unroll
    for (int q=0;q<4;q++){
      float o = acc2[r][q];
      float oo = __shfl_xor(o, 1, 64);
      if (lr < 2){
        int row = (w*3+r)*16 + lg*4 + q;
        float self = o + ((lr==0) ? b2a : b2b);
        float oth  = oo + ((lr==0) ? b2b : b2a);
        float mx = fmaxf(self, oth);
        float lse = mx + logf(expf(self-mx) + expf(oth-mx));
        out[(obase + row)*2 + lr] = self - lse;
      }
    }
  }
}

extern "C" void kernel_launch(void* const* d_in, const int* in_sizes, int n_in,
                              void* d_out, int out_size, void* d_ws, size_t ws_size,
                              hipStream_t stream){
  const float* x    = (const float*)d_in[0];
  const int*   ei   = (const int*)d_in[1];
  const float* ea   = (const float*)d_in[2];
  const float* efw1 = (const float*)d_in[4];
  const float* efb1 = (const float*)d_in[5];
  const float* efw2 = (const float*)d_in[6];
  const float* efb2 = (const float*)d_in[7];
  const float* efwr = (const float*)d_in[8];
  const float* bn1g = (const float*)d_in[9];
  const float* bn1b = (const float*)d_in[10];
  const float* ecw1 = (const float*)d_in[11];
  const float* ecb1 = (const float*)d_in[12];
  const float* ecw2 = (const float*)d_in[13];
  const float* ecb2 = (const float*)d_in[14];
  const float* bn2g = (const float*)d_in[15];
  const float* bn2b = (const float*)d_in[16];
  const float* m2w1 = (const float*)d_in[17];
  const float* m2bng = (const float*)d_in[19];
  const float* m2bnb = (const float*)d_in[20];
  const float* m2w2  = (const float*)d_in[21];
  const float* m2b2  = (const float*)d_in[22];

  char* ws = (char*)d_ws;
  float*    x1a   = (float*)(ws + 0);
  float*    x1bn  = (float*)(ws + 1572864);
  float*    x2bn  = (float*)(ws + 3145728);
  float*    x2f   = (float*)(ws + 4718592);
  float*    sqv   = (float*)(ws + 6291456);
  unsigned* nbr   = (unsigned*)(ws + 6316032);
  float*    stats = (float*)(ws + 6512640);
  float*    dbins = (float*)(ws + 6515712);
  u64*      parts = (u64*)(ws + 6581248);
  // overlays (disjoint lifetimes):
  float*    A2    = (float*)(ws + 0);            // over x1a (dead after bn1 apply)
  float*    Qm    = (float*)(ws + 3145728);      // over x2bn slot (written later)
  float*    P1    = (float*)(ws + 3145728);      // edge1 phase only
  float*    P2    = (float*)(ws + 4718592);
  // CSR scratch + EAc overlay the parts region (dead before k_knn writes parts)
  unsigned* rcnt  = (unsigned*)(ws + 6581248);
  unsigned* rptr  = rcnt + 6400;
  unsigned* rcur  = rptr + 6400;
  unsigned* rlist = rcur + 6400;
  float*    EAc   = (float*)(ws + 6581248 + 4194304);   // ends at ws+23358464
  float *g1sum = stats,     *g1ss = stats+64;
  float *g2sum = stats+256, *g2ss = stats+320;
  float *dsc = stats+512, *dsh = stats+640;
  float* outp = (float*)d_out;

  int CH = 96;   // 24x96 = 2304 blocks: measured-best knn occupancy (174us)
  if (ws_size < 6581248ull + (size_t)NN*96*64 + 3145728ull + 20480ull) CH = 48;
  if (ws_size < 6581248ull + (size_t)NN*48*64 + 3145728ull + 20480ull) CH = 24;
  size_t parts2_off = 6581248ull + (size_t)CH*NN*64;
  size_t wpre_off = parts2_off + 3145728ull;
  if (wpre_off < 23358464ull) wpre_off = 23358464ull;   // keep clear of EAc
  u64* parts2 = (u64*)(ws + parts2_off);
  unsigned short* Wpre  = (unsigned short*)(ws + wpre_off);
  unsigned short* W2Tp  = (unsigned short*)(ws + wpre_off + 16384);

  k_init<<<64,256,0,stream>>>(dbins, stats);
  k_prep_w<<<9,256,0,stream>>>(m2w1, m2w2, Wpre, W2Tp);
  k_root<<<1536,256,0,stream>>>(x, efwr, x1a);
  k_eac<<<3072,256,0,stream>>>(ea, efw1, EAc);
  k_zero_cnt<<<24,256,0,stream>>>(rcnt);
  k_cnt_dst<<<192,256,0,stream>>>(ei, rcnt);
  k_scan<<<1,256,0,stream>>>(rcnt, rptr, rcur);
  k_fill_dst<<<192,256,0,stream>>>(ei, rcur, rlist);
  k_p12<<<384,256,0,stream>>>(x, efw1, efb1, P1, P2);
  k_node1<<<384,256,0,stream>>>(P1, P2, EAc, ei, rptr, rlist, efw2, efb2, x1a);
  k_bn_stats<<<96,256,0,stream>>>(x1a, g1sum, g1ss);
  k_apply_bn1_sq<<<1536,256,0,stream>>>(x1a, g1sum, g1ss, bn1g, bn1b, x1bn, sqv);
  dim3 kg(24, CH);
  k_knn<<<kg,128,0,stream>>>(x1bn, sqv, parts, CH);
  k_knn_merge1<<<192,256,0,stream>>>(parts, CH/8, parts2);
  k_knn_merge2<<<24,256,0,stream>>>(parts2, nbr);
  k_zero_cnt<<<24,256,0,stream>>>(rcnt);
  k_rev_cnt<<<192,256,0,stream>>>(nbr, rcnt);
  k_scan<<<1,256,0,stream>>>(rcnt, rptr, rcur);
  k_rev_fill<<<192,256,0,stream>>>(nbr, rcur, rlist);
  k_pq<<<384,256,0,stream>>>(x1bn, ecw1, ecb1, A2, Qm);
  k_edge2max<<<384,256,0,stream>>>(A2, Qm, nbr, rptr, rlist, ecw2, ecb2, x2f);
  k_bn_stats<<<96,256,0,stream>>>(x2f, g2sum, g2ss);
  k_apply_bn2f<<<1536,256,0,stream>>>(x2f, g2sum, g2ss, bn2g, bn2b, x2bn);
  k_d_stats<<<6144,256,0,stream>>>(x2bn, Wpre, dbins);
  k_d_fin<<<1,128,0,stream>>>(dbins, m2bng, m2bnb, dsc, dsh);
  k_d_main<<<6144,256,0,stream>>>(x2bn, Wpre, W2Tp, m2b2, dsc, dsh, outp);
}